// Round 11
// baseline (212.619 us; speedup 1.0000x reference)
//
#include <hip/hip_runtime.h>
#include <math.h>

// PhaseMultiHeadDecoder: B=4, S=1024, E=1024, H=16, hd=64, V=256
// Full fp16 pipeline. attn: TQ=64, dbuf LDS + reg-prefetch + raw barriers
// (T14/T4), 32-key fused softmax, defer-max (T13), setprio (T5).
// FF/RO fp16 GEMM (K=2048) K-split.
#define B_ 4
#define S_ 1024
#define E_ 1024
#define H_ 16
#define V_ 256

typedef _Float16 h8 __attribute__((ext_vector_type(8)));
typedef _Float16 h4 __attribute__((ext_vector_type(4)));
typedef float f4x __attribute__((ext_vector_type(4)));

__device__ __forceinline__ void gload16(const void* g, void* l) {
  __builtin_amdgcn_global_load_lds((const __attribute__((address_space(1))) void*)g,
                                   (__attribute__((address_space(3))) void*)l, 16, 0, 0);
}

#define MFMA32F16(a, b, c) __builtin_amdgcn_mfma_f32_16x16x32_f16(a, b, c, 0, 0, 0)

#if defined(__has_builtin)
#if __has_builtin(__builtin_amdgcn_mfma_f32_16x16x16f16)
#define MFMA16F16(a, b, c) __builtin_amdgcn_mfma_f32_16x16x16f16(a, b, c, 0, 0, 0)
#endif
#endif
#ifndef MFMA16F16
__device__ __forceinline__ f4x mfma16f16_asm(h4 a, h4 b, f4x c) {
  asm volatile("v_mfma_f32_16x16x16_f16 %0, %1, %2, %0" : "+v"(c) : "v"(a), "v"(b));
  return c;
}
#define MFMA16F16(a, b, c) mfma16f16_asm(a, b, c)
#endif

// ---------------- rotation cos/sin tables: tabs[3][2][1024] ----------------
__global__ void rot_kernel(const float* __restrict__ qr, const float* __restrict__ kr,
                           const float* __restrict__ vr, float* __restrict__ tabs) {
  int i = blockIdx.x * blockDim.x + threadIdx.x;
  if (i >= 3 * 1024) return;
  int which = i >> 10;
  int j = i & 1023;
  const float* src = which == 0 ? qr : (which == 1 ? kr : vr);
  float s, c;
  sincosf(src[j], &s, &c);
  tabs[which * 2048 + j] = c;
  tabs[which * 2048 + 1024 + j] = s;
}

// ---------------- fused embed + K'/V' prep (fp16) ----------------
__global__ __launch_bounds__(256) void embed_qkv_kernel(
    const int* __restrict__ x, const float* __restrict__ te,
    const float* __restrict__ pp, const float* __restrict__ tabs,
    float* __restrict__ sr, float* __restrict__ si,
    unsigned short* __restrict__ Kd, unsigned short* __restrict__ Vd) {
  __shared__ unsigned short Kl2[4096];
  __shared__ unsigned short Vl2[4096];
  const int kt2 = blockIdx.x;          // 32-row group, 0..31
  const int bh = blockIdx.y;           // 0..63
  const int b = bh >> 4, h = bh & 15;
  const int tid = threadIdx.x;
  const float* qc = tabs + h * 64;
  const float* qs = tabs + 1024 + h * 64;
  const float* kc = tabs + 2048 + h * 64;
  const float* ks = tabs + 3072 + h * 64;
  #pragma unroll
  for (int p = 0; p < 8; ++p) {
    int id = p * 256 + tid;            // 2048 items = 32 rows x 64 dims
    int sl = id >> 6;
    int dd = id & 63;
    int s = kt2 * 32 + sl;
    int e = h * 64 + dd;
    int tok = x[b * 1024 + s];
    float mm = tanhf(te[tok * 1024 + e]);
    float sn, cs;
    sincosf(pp[s * 1024 + e], &sn, &cs);
    float re = mm * cs, im = mm * sn;
    size_t g = ((size_t)(b * 1024 + s)) * 1024 + e;
    sr[g] = re;
    si[g] = im;
    float cq = qc[dd], sq = qs[dd], ck = kc[dd], sk = ks[dd];
    float cd = cq * ck + sq * sk;      // cos(thq - thk)
    float sd = sq * ck - cq * sk;      // sin(thq - thk)
    float kr = re * cd + im * sd;      // k-state rotated by -delta
    float ki = im * cd - re * sd;
    int t = sl >> 4, key = sl & 15;
    int c0 = dd, c1 = 64 + dd;
    #define KOFF(c) (t * 2048 + ((((c) >> 5) * 4 + (((c) >> 3) & 3)) * 16 + key) * 8 + ((c) & 7))
    *(_Float16*)&Kl2[KOFF(c0)] = (_Float16)kr;
    *(_Float16*)&Kl2[KOFF(c1)] = (_Float16)ki;
    #undef KOFF
    int kgk = key >> 2, jk = key & 3;
    #define VOFF(d) (t * 2048 + ((((d) >> 4) * 4 + kgk) * 16 + ((d) & 15)) * 4 + jk)
    *(_Float16*)&Vl2[VOFF(dd)] = (_Float16)re;
    *(_Float16*)&Vl2[VOFF(64 + dd)] = (_Float16)im;
    #undef VOFF
  }
  __syncthreads();
  unsigned short* kdst = Kd + ((size_t)(bh * 64 + kt2 * 2)) * 2048;
  unsigned short* vdst = Vd + ((size_t)(bh * 64 + kt2 * 2)) * 2048;
  #pragma unroll
  for (int p = 0; p < 2; ++p) {
    int c = p * 256 + tid;
    ((int4*)kdst)[c] = ((const int4*)Kl2)[c];
    ((int4*)vdst)[c] = ((const int4*)Vl2)[c];
  }
}

// ---------------- fp16 MFMA flash attention, TQ=64, dbuf + reg-prefetch ------
// grid 1024: flat -> low=flat&7 (XCD=bh&7), qt=(flat>>3)>>3, bh=((flat>>3)&7)<<3|low
__global__ __launch_bounds__(256, 4) void attn_mfma_kernel(
    const float* __restrict__ sr, const float* __restrict__ si,
    const unsigned short* __restrict__ Kd, const unsigned short* __restrict__ Vd,
    const float* __restrict__ tabs,
    unsigned short* __restrict__ Af) {
  __shared__ __align__(16) unsigned short Klds[2][4096];
  __shared__ __align__(16) unsigned short Vlds[2][4096];
  const int flat = blockIdx.x;
  const int low = flat & 7, rest = flat >> 3;
  const int qt = rest >> 3;            // 0..15
  const int bh = ((rest & 7) << 3) | low;
  const int b = bh >> 4, h = bh & 15;
  const int tid = threadIdx.x, lane = tid & 63, wid = tid >> 6;
  const int cl = lane & 15, kg = lane >> 4;
  const int q0 = qt * 64, qw0 = q0 + wid * 16;

  // Q^T b-frag (fp16), this wave's 16 q-rows
  h8 qf[4];
  {
    int q = qw0 + cl;
    const float* srow = sr + ((size_t)(b * 1024 + q)) * 1024 + h * 64;
    const float* irow = si + ((size_t)(b * 1024 + q)) * 1024 + h * 64;
    #pragma unroll
    for (int ksx = 0; ksx < 4; ++ksx) {
      int f0 = ksx * 32 + kg * 8;
      const float* src = (f0 < 64) ? (srow + f0) : (irow + (f0 - 64));
      float4 v0 = *(const float4*)src;
      float4 v1 = *(const float4*)(src + 4);
      qf[ksx][0] = (_Float16)v0.x; qf[ksx][1] = (_Float16)v0.y;
      qf[ksx][2] = (_Float16)v0.z; qf[ksx][3] = (_Float16)v0.w;
      qf[ksx][4] = (_Float16)v1.x; qf[ksx][5] = (_Float16)v1.y;
      qf[ksx][6] = (_Float16)v1.z; qf[ksx][7] = (_Float16)v1.w;
    }
  }

  f4x acc[8] = {};                     // out^T: [mt], d = mt*16+kg*4+r (mt<4 re, >=4 im)
  float m_ = -1e30f, l_ = 0.f;
  const int np = qt * 2 + 2;           // 32-key pairs
  const int wqmax = qw0 + 15;
  const int qcol = qw0 + cl;

  // pair P = int4 range [P*512, P*512+512) of this bh's K/V streams
  const int4* kgbase = (const int4*)(Kd + ((size_t)(bh * 64)) * 2048);
  const int4* vgbase = (const int4*)(Vd + ((size_t)(bh * 64)) * 2048);
  int4 kreg[2], vreg[2];

  // prologue: pair 0 -> buf0; issue pair-1 loads (stay in flight across barrier)
  #pragma unroll
  for (int j = 0; j < 2; ++j) {
    kreg[j] = kgbase[tid + 256 * j];
    vreg[j] = vgbase[tid + 256 * j];
  }
  #pragma unroll
  for (int j = 0; j < 2; ++j) {
    ((int4*)Klds[0])[tid + 256 * j] = kreg[j];
    ((int4*)Vlds[0])[tid + 256 * j] = vreg[j];
  }
  if (np > 1) {
    #pragma unroll
    for (int j = 0; j < 2; ++j) {
      kreg[j] = kgbase[512 + tid + 256 * j];
      vreg[j] = vgbase[512 + tid + 256 * j];
    }
  }
  asm volatile("s_waitcnt lgkmcnt(0)" ::: "memory");
  __builtin_amdgcn_s_barrier();

  for (int p = 0; p < np; ++p) {
    const int cur = p & 1;
    const int k0a = p * 32;
    if (k0a <= wqmax) {                // wave-uniform causal skip
      // scores^T for 32 keys (two 16-key tiles)
      __builtin_amdgcn_s_setprio(1);
      f4x sca = {}, scb = {};
      #pragma unroll
      for (int ksx = 0; ksx < 4; ++ksx) {
        h8 ka = *(const h8*)&Klds[cur][ksx * 512 + lane * 8];
        sca = MFMA32F16(ka, qf[ksx], sca);
      }
      #pragma unroll
      for (int ksx = 0; ksx < 4; ++ksx) {
        h8 kb = *(const h8*)&Klds[cur][2048 + ksx * 512 + lane * 8];
        scb = MFMA32F16(kb, qf[ksx], scb);
      }
      __builtin_amdgcn_s_setprio(0);
      if (k0a + 31 > qw0) {            // causal mask (boundary pairs only)
        #pragma unroll
        for (int r = 0; r < 4; ++r) {
          if (k0a + kg * 4 + r > qcol)      sca[r] = -1e30f;
          if (k0a + 16 + kg * 4 + r > qcol) scb[r] = -1e30f;
        }
      }
      // fused 32-key online softmax with defer-max (THR=8)
      float mx = fmaxf(fmaxf(fmaxf(sca[0], sca[1]), fmaxf(sca[2], sca[3])),
                       fmaxf(fmaxf(scb[0], scb[1]), fmaxf(scb[2], scb[3])));
      mx = fmaxf(mx, __shfl_xor(mx, 16, 64));
      mx = fmaxf(mx, __shfl_xor(mx, 32, 64));
      if (!__all(mx <= m_ + 8.0f)) {
        float mn = fmaxf(m_, mx);
        float corr = __expf(m_ - mn);
        #pragma unroll
        for (int mt = 0; mt < 8; ++mt) acc[mt] *= corr;
        l_ *= corr;
        m_ = mn;
      }
      float pa0 = __expf(sca[0] - m_), pa1 = __expf(sca[1] - m_);
      float pa2 = __expf(sca[2] - m_), pa3 = __expf(sca[3] - m_);
      float pb0 = __expf(scb[0] - m_), pb1 = __expf(scb[1] - m_);
      float pb2 = __expf(scb[2] - m_), pb3 = __expf(scb[3] - m_);
      float s0 = ((pa0 + pa1) + (pa2 + pa3)) + ((pb0 + pb1) + (pb2 + pb3));
      s0 += __shfl_xor(s0, 16, 64);
      s0 += __shfl_xor(s0, 32, 64);
      l_ += s0;
      h4 pba, pbb;
      pba[0] = (_Float16)pa0; pba[1] = (_Float16)pa1;
      pba[2] = (_Float16)pa2; pba[3] = (_Float16)pa3;
      pbb[0] = (_Float16)pb0; pbb[1] = (_Float16)pb1;
      pbb[2] = (_Float16)pb2; pbb[3] = (_Float16)pb3;
      __builtin_amdgcn_s_setprio(1);
      #pragma unroll
      for (int mt = 0; mt < 8; ++mt) {
        h4 va = *(const h4*)&Vlds[cur][mt * 256 + lane * 4];
        acc[mt] = MFMA16F16(va, pba, acc[mt]);
      }
      #pragma unroll
      for (int mt = 0; mt < 8; ++mt) {
        h4 vb = *(const h4*)&Vlds[cur][2048 + mt * 256 + lane * 4];
        acc[mt] = MFMA16F16(vb, pbb, acc[mt]);
      }
      __builtin_amdgcn_s_setprio(0);
    }
    if (p + 1 < np) {
      // write prefetched pair p+1 into the other buffer (vmcnt wait is automatic)
      #pragma unroll
      for (int j = 0; j < 2; ++j) {
        ((int4*)Klds[cur ^ 1])[tid + 256 * j] = kreg[j];
        ((int4*)Vlds[cur ^ 1])[tid + 256 * j] = vreg[j];
      }
      if (p + 2 < np) {                // issue pair p+2 loads; left in flight
        #pragma unroll
        for (int j = 0; j < 2; ++j) {
          kreg[j] = kgbase[(size_t)(p + 2) * 512 + tid + 256 * j];
          vreg[j] = vgbase[(size_t)(p + 2) * 512 + tid + 256 * j];
        }
      }
      asm volatile("s_waitcnt lgkmcnt(0)" ::: "memory");
      __builtin_amdgcn_s_barrier();    // raw barrier: no vmcnt drain
    }
  }
  // epilogue: /l, rotate by exp(i*thv), add state, fp16 -> Af[4096][re1024|im1024]
  {
    float linv = 1.0f / l_;
    int q = qw0 + cl;
    size_t mrow = (size_t)(b * 1024 + q);
    size_t obase = mrow * 1024 + h * 64;
    size_t abase = mrow * 2048 + h * 64;
    #pragma unroll
    for (int mt = 0; mt < 4; ++mt) {
      int d0 = mt * 16 + kg * 4;
      float4 s_r = *(const float4*)&sr[obase + d0];
      float4 s_i = *(const float4*)&si[obase + d0];
      float srv[4] = {s_r.x, s_r.y, s_r.z, s_r.w};
      float siv[4] = {s_i.x, s_i.y, s_i.z, s_i.w};
      h4 hr, hi;
      #pragma unroll
      for (int r = 0; r < 4; ++r) {
        int d = d0 + r;
        float orv = acc[mt][r] * linv;
        float oiv = acc[mt + 4][r] * linv;
        float c = tabs[4096 + h * 64 + d], s = tabs[5120 + h * 64 + d];
        hr[r] = (_Float16)(orv * c - oiv * s + srv[r]);
        hi[r] = (_Float16)(orv * s + oiv * c + siv[r]);
      }
      *(h4*)&Af[abase + d0]        = hr;   // real
      *(h4*)&Af[abase + 1024 + d0] = hi;   // imag
    }
  }
}

// ---------------- transpose FF weight -> fp16: Bt[2048][2048] ----------------
__global__ void split_b_kernel(const float* __restrict__ fr, const float* __restrict__ fi,
                               unsigned short* __restrict__ Bt) {
  __shared__ float tile[32][33];
  const int k0 = blockIdx.x * 32, n0 = blockIdx.y * 32;
  const int tid = threadIdx.x;
  #pragma unroll
  for (int p = 0; p < 4; ++p) {
    int e = p * 256 + tid;
    int kk = e >> 5, nn = e & 31;
    int k = k0 + kk, n = n0 + nn;
    float v;
    if (n < 1024) v = (k < 1024) ? fr[(size_t)k * 1024 + n] : -fi[(size_t)(k - 1024) * 1024 + n];
    else          v = (k < 1024) ? fi[(size_t)k * 1024 + (n - 1024)]
                                 : fr[(size_t)(k - 1024) * 1024 + (n - 1024)];
    tile[kk][nn] = v;
  }
  __syncthreads();
  #pragma unroll
  for (int p = 0; p < 4; ++p) {
    int e = p * 256 + tid;
    int nn = e >> 5, kk = e & 31;
    *(_Float16*)&Bt[(size_t)(n0 + nn) * 2048 + (k0 + kk)] = (_Float16)tile[kk][nn];
  }
}

// ---------------- readout weight fp16: Wt[256][wr1024|wi1024] ----------------
__global__ void split_w_kernel(const float* __restrict__ wr, const float* __restrict__ wi,
                               unsigned short* __restrict__ Wt) {
  int idx = blockIdx.x * 256 + threadIdx.x;        // 256*512
  int v = idx >> 9;
  int k4 = (idx & 511) * 4;
  float4 a = (k4 < 1024) ? *(const float4*)&wr[(size_t)v * 1024 + k4]
                         : *(const float4*)&wi[(size_t)v * 1024 + k4 - 1024];
  h4 h;
  h[0] = (_Float16)a.x; h[1] = (_Float16)a.y;
  h[2] = (_Float16)a.z; h[3] = (_Float16)a.w;
  *(h4*)&Wt[(size_t)v * 2048 + k4] = h;
}

// ---------------- FF GEMM: fp16, 128x128 tile, BK=64, K=2048, K-split x2 ------
__global__ __launch_bounds__(256, 4) void gemm_ff(
    const unsigned short* __restrict__ A,   // [4096][2048] fp16 bits
    const unsigned short* __restrict__ Bt,  // [2048][2048]
    float* __restrict__ pr0, float* __restrict__ pi0,
    float* __restrict__ pr1, float* __restrict__ pi1) {
  __shared__ short As[128 * 64];
  __shared__ short Bs[128 * 64];
  const int tid = threadIdx.x;
  const int lane = tid & 63, wid = tid >> 6;
  const int m0 = blockIdx.x * 128, n0 = blockIdx.y * 128;
  const int z = blockIdx.z;
  const int wr = wid >> 1, wc = wid & 1;
  const int cl = lane & 15, rg = lane >> 4;

  f4x acc[4][4] = {};
  const int cbase = wid * 256;

  for (int kt = z * 16; kt < z * 16 + 16; ++kt) {
    const int k0 = kt * 64;
    #pragma unroll
    for (int it = 0; it < 4; ++it) {
      int c = cbase + it * 64 + lane;
      gload16(A + (size_t)(m0 + (c >> 3)) * 2048 + k0 + (c & 7) * 8,
              As + (cbase + it * 64) * 8);
      gload16(Bt + (size_t)(n0 + (c >> 3)) * 2048 + k0 + (c & 7) * 8,
              Bs + (cbase + it * 64) * 8);
    }
    __syncthreads();
    #pragma unroll
    for (int ks = 0; ks < 2; ++ks) {
      h8 a[4], b[4];
      #pragma unroll
      for (int ms = 0; ms < 4; ++ms)
        a[ms] = *(const h8*)&As[(wr * 64 + ms * 16 + cl) * 64 + ks * 32 + rg * 8];
      #pragma unroll
      for (int ns = 0; ns < 4; ++ns)
        b[ns] = *(const h8*)&Bs[(wc * 64 + ns * 16 + cl) * 64 + ks * 32 + rg * 8];
      #pragma unroll
      for (int ms = 0; ms < 4; ++ms)
        #pragma unroll
        for (int ns = 0; ns < 4; ++ns)
          acc[ms][ns] = MFMA32F16(a[ms], b[ns], acc[ms][ns]);
    }
    __syncthreads();
  }

  const int colbase = n0 + wc * 64;
  float* o_r = z ? pr1 : pr0;
  float* o_i = z ? pi1 : pi0;
  float* dst = (colbase < 1024) ? o_r : o_i;
  const int cb = colbase & 1023;
  #pragma unroll
  for (int ms = 0; ms < 4; ++ms)
    #pragma unroll
    for (int r2 = 0; r2 < 4; ++r2) {
      const int grow = m0 + wr * 64 + ms * 16 + rg * 4 + r2;
      #pragma unroll
      for (int ns = 0; ns < 4; ++ns)
        dst[(size_t)grow * 1024 + cb + ns * 16 + cl] = acc[ms][ns][r2];
    }
}

// ---------------- RO GEMM: fp16, 128x128 tile, K=2048, K-split x8 ------------
__global__ __launch_bounds__(256, 4) void gemm_ro(
    const unsigned short* __restrict__ Z,   // [4096][2048] fp16 bits
    const unsigned short* __restrict__ Wt,  // [256][2048]
    float* __restrict__ part) {             // [8][4096][256]
  __shared__ short As[128 * 64];
  __shared__ short Bs[128 * 64];
  const int tid = threadIdx.x;
  const int lane = tid & 63, wid = tid >> 6;
  const int m0 = blockIdx.x * 128, n0 = blockIdx.y * 128;
  const int z = blockIdx.z;
  const int wr = wid >> 1, wc = wid & 1;
  const int cl = lane & 15, rg = lane >> 4;

  f4x acc[4][4] = {};
  const int cbase = wid * 256;

  for (int kt = z * 4; kt < z * 4 + 4; ++kt) {
    const int k0 = kt * 64;
    #pragma unroll
    for (int it = 0; it < 4; ++it) {
      int c = cbase + it * 64 + lane;
      gload16(Z + (size_t)(m0 + (c >> 3)) * 2048 + k0 + (c & 7) * 8,
              As + (cbase + it * 64) * 8);
      gload16(Wt + (size_t)(n0 + (c >> 3)) * 2048 + k0 + (c & 7) * 8,
              Bs + (cbase + it * 64) * 8);
    }
    __syncthreads();
    #pragma unroll
    for (int ks = 0; ks < 2; ++ks) {
      h8 a[4], b[4];
      #pragma unroll
      for (int ms = 0; ms < 4; ++ms)
        a[ms] = *(const h8*)&As[(wr * 64 + ms * 16 + cl) * 64 + ks * 32 + rg * 8];
      #pragma unroll
      for (int ns = 0; ns < 4; ++ns)
        b[ns] = *(const h8*)&Bs[(wc * 64 + ns * 16 + cl) * 64 + ks * 32 + rg * 8];
      #pragma unroll
      for (int ms = 0; ms < 4; ++ms)
        #pragma unroll
        for (int ns = 0; ns < 4; ++ns)
          acc[ms][ns] = MFMA32F16(a[ms], b[ns], acc[ms][ns]);
    }
    __syncthreads();
  }

  float* dst = part + (size_t)z * 4096 * 256;
  const int colbase = n0 + wc * 64;
  #pragma unroll
  for (int ms = 0; ms < 4; ++ms)
    #pragma unroll
    for (int r2 = 0; r2 < 4; ++r2) {
      const int grow = m0 + wr * 64 + ms * 16 + rg * 4 + r2;
      #pragma unroll
      for (int ns = 0; ns < 4; ++ns)
        dst[(size_t)grow * 256 + colbase + ns * 16 + cl] = acc[ms][ns][r2];
    }
}

// ---------------- complex_norm over FF partial sums -> fp16 Z ----------------
__global__ __launch_bounds__(256) void norm_split_kernel(
    const float* __restrict__ pr0, const float* __restrict__ pi0,
    const float* __restrict__ pr1, const float* __restrict__ pi1,
    unsigned short* __restrict__ Z) {
  const int row = blockIdx.x, tid = threadIdx.x;
  const int base = row * E_ + tid * 4;
  float4 r0 = *(const float4*)&pr0[base];
  float4 r1 = *(const float4*)&pr1[base];
  float4 i0 = *(const float4*)&pi0[base];
  float4 i1 = *(const float4*)&pi1[base];
  float4 zr = make_float4(r0.x + r1.x, r0.y + r1.y, r0.z + r1.z, r0.w + r1.w);
  float4 zi = make_float4(i0.x + i1.x, i0.y + i1.y, i0.z + i1.z, i0.w + i1.w);
  float mg[4];
  mg[0] = sqrtf(zr.x * zr.x + zi.x * zi.x);
  mg[1] = sqrtf(zr.y * zr.y + zi.y * zi.y);
  mg[2] = sqrtf(zr.z * zr.z + zi.z * zi.z);
  mg[3] = sqrtf(zr.w * zr.w + zi.w * zi.w);
  float s1 = mg[0] + mg[1] + mg[2] + mg[3];
  float s2 = mg[0]*mg[0] + mg[1]*mg[1] + mg[2]*mg[2] + mg[3]*mg[3];
  #pragma unroll
  for (int off = 1; off < 64; off <<= 1) {
    s1 += __shfl_xor(s1, off, 64);
    s2 += __shfl_xor(s2, off, 64);
  }
  __shared__ float ws1[4], ws2[4];
  if ((tid & 63) == 0) { ws1[tid >> 6] = s1; ws2[tid >> 6] = s2; }
  __syncthreads();
  s1 = ws1[0] + ws1[1] + ws1[2] + ws1[3];
  s2 = ws2[0] + ws2[1] + ws2[2] + ws2[3];
  float mean = s1 * (1.0f / 1024.0f);
  float var = (s2 - 1024.0f * mean * mean) * (1.0f / 1023.0f);  // ddof=1
  var = fmaxf(var, 0.0f);
  float inv_sd = 1.0f / (sqrtf(var) + 1e-5f);
  float sc[4];
  #pragma unroll
  for (int t = 0; t < 4; ++t)
    sc[t] = tanhf((mg[t] - mean) * inv_sd) / (mg[t] + 1e-5f);
  h4 hr, hi;
  hr[0] = (_Float16)(zr.x * sc[0]); hr[1] = (_Float16)(zr.y * sc[1]);
  hr[2] = (_Float16)(zr.z * sc[2]); hr[3] = (_Float16)(zr.w * sc[3]);
  hi[0] = (_Float16)(zi.x * sc[0]); hi[1] = (_Float16)(zi.y * sc[1]);
  hi[2] = (_Float16)(zi.z * sc[2]); hi[3] = (_Float16)(zi.w * sc[3]);
  const size_t zb = (size_t)row * 2048 + tid * 4;
  *(h4*)&Z[zb]        = hr;
  *(h4*)&Z[zb + 1024] = hi;
}

// ---------------- reduce RO partials + biases -> out ----------------
__global__ void reduce_bias_kernel(const float* __restrict__ part,
                                   const float* __restrict__ rb,
                                   const float* __restrict__ ib,
                                   float* __restrict__ out) {
  int i4 = (blockIdx.x * 256 + threadIdx.x) * 4;   // < 4096*256
  int col = i4 & 255;
  float4 s = *(const float4*)&part[i4];
  #pragma unroll
  for (int z = 1; z < 8; ++z) {
    float4 v = *(const float4*)&part[(size_t)z * 1048576 + i4];
    s.x += v.x; s.y += v.y; s.z += v.z; s.w += v.w;
  }
  s.x += rb[col + 0] + ib[col + 0];
  s.y += rb[col + 1] + ib[col + 1];
  s.z += rb[col + 2] + ib[col + 2];
  s.w += rb[col + 3] + ib[col + 3];
  *(float4*)&out[i4] = s;
}

extern "C" void kernel_launch(void* const* d_in, const int* in_sizes, int n_in,
                              void* d_out, int out_size, void* d_ws, size_t ws_size,
                              hipStream_t stream) {
  const int*   x    = (const int*)d_in[0];
  const float* te   = (const float*)d_in[1];
  const float* pp   = (const float*)d_in[2];
  const float* qr   = (const float*)d_in[3];
  const float* kr   = (const float*)d_in[4];
  const float* vr   = (const float*)d_in[5];
  const float* ffr  = (const float*)d_in[6];
  const float* ffi  = (const float*)d_in[7];
  const float* rorw = (const float*)d_in[8];
  const float* rorb = (const float*)d_in[9];
  const float* roiw = (const float*)d_in[10];
  const float* roib = (const float*)d_in[11];
  float* out = (float*)d_out;

  char* W = (char*)d_ws;
  const size_t MiB = 1 << 20;
  // [0,16) sr -> pr0 | [16,32) si -> pi0
  // [32,48) Af -> Zhl
  // [48,64) Kd -> Bt[48,56) + Wt[56,57)   (after attn)
  // [64,80) Vd -> pr1 ┐
  // [80,96) pi1       ┴-> ro_part [64,96)  (after norm)
  // [96,+24K) tabs
  float* sr  = (float*)W;
  float* si  = (float*)(W + 16 * MiB);
  unsigned short* Af = (unsigned short*)(W + 32 * MiB);
  unsigned short* Kd = (unsigned short*)(W + 48 * MiB);
  unsigned short* Vd = (unsigned short*)(W + 64 * MiB);
  unsigned short* Bt = (unsigned short*)(W + 48 * MiB);
  unsigned short* Wt = (unsigned short*)(W + 56 * MiB);
  float* tabs = (float*)(W + 96 * MiB);
  float* pr0 = sr;
  float* pi0 = si;
  float* pr1 = (float*)(W + 64 * MiB);
  float* pi1 = (float*)(W + 80 * MiB);
  unsigned short* Zhl = Af;
  float* ro_part = (float*)(W + 64 * MiB);   // 8 x 4 MiB

  rot_kernel<<<12, 256, 0, stream>>>(qr, kr, vr, tabs);
  embed_qkv_kernel<<<dim3(32, 64), 256, 0, stream>>>(x, te, pp, tabs, sr, si, Kd, Vd);
  attn_mfma_kernel<<<1024, 256, 0, stream>>>(sr, si, Kd, Vd, tabs, Af);
  split_b_kernel<<<dim3(64, 64), 256, 0, stream>>>(ffr, ffi, Bt);
  split_w_kernel<<<512, 256, 0, stream>>>(rorw, roiw, Wt);
  gemm_ff<<<dim3(32, 16, 2), 256, 0, stream>>>(Af, Bt, pr0, pi0, pr1, pi1);
  norm_split_kernel<<<B_ * S_, 256, 0, stream>>>(pr0, pi0, pr1, pi1, Zhl);
  gemm_ro<<<dim3(32, 2, 8), 256, 0, stream>>>(Zhl, Wt, ro_part);
  reduce_bias_kernel<<<1024, 256, 0, stream>>>(ro_part, rorb, roib, out);
}

// Round 12
// 161.311 us; speedup vs baseline: 1.3181x; 1.3181x over previous
//
#include <hip/hip_runtime.h>
#include <math.h>

// PhaseMultiHeadDecoder: B=4, S=1024, E=1024, H=16, hd=64, V=256
// Full fp16 pipeline. attn: TQ=64, gload_lds DOUBLE-BUFFER 2-phase pipeline
// (stage next pair during compute), fused 32-key softmax, defer-max, setprio.
// FF/RO fp16 GEMM (K=2048) K-split.
#define B_ 4
#define S_ 1024
#define E_ 1024
#define H_ 16
#define V_ 256

typedef _Float16 h8 __attribute__((ext_vector_type(8)));
typedef _Float16 h4 __attribute__((ext_vector_type(4)));
typedef float f4x __attribute__((ext_vector_type(4)));

__device__ __forceinline__ void gload16(const void* g, void* l) {
  __builtin_amdgcn_global_load_lds((const __attribute__((address_space(1))) void*)g,
                                   (__attribute__((address_space(3))) void*)l, 16, 0, 0);
}

#define MFMA32F16(a, b, c) __builtin_amdgcn_mfma_f32_16x16x32_f16(a, b, c, 0, 0, 0)

#if defined(__has_builtin)
#if __has_builtin(__builtin_amdgcn_mfma_f32_16x16x16f16)
#define MFMA16F16(a, b, c) __builtin_amdgcn_mfma_f32_16x16x16f16(a, b, c, 0, 0, 0)
#endif
#endif
#ifndef MFMA16F16
__device__ __forceinline__ f4x mfma16f16_asm(h4 a, h4 b, f4x c) {
  asm volatile("v_mfma_f32_16x16x16_f16 %0, %1, %2, %0" : "+v"(c) : "v"(a), "v"(b));
  return c;
}
#define MFMA16F16(a, b, c) mfma16f16_asm(a, b, c)
#endif

// ---------------- rotation cos/sin tables: tabs[3][2][1024] ----------------
__global__ void rot_kernel(const float* __restrict__ qr, const float* __restrict__ kr,
                           const float* __restrict__ vr, float* __restrict__ tabs) {
  int i = blockIdx.x * blockDim.x + threadIdx.x;
  if (i >= 3 * 1024) return;
  int which = i >> 10;
  int j = i & 1023;
  const float* src = which == 0 ? qr : (which == 1 ? kr : vr);
  float s, c;
  sincosf(src[j], &s, &c);
  tabs[which * 2048 + j] = c;
  tabs[which * 2048 + 1024 + j] = s;
}

// ---------------- fused embed + K'/V' prep (fp16) ----------------
__global__ __launch_bounds__(256) void embed_qkv_kernel(
    const int* __restrict__ x, const float* __restrict__ te,
    const float* __restrict__ pp, const float* __restrict__ tabs,
    float* __restrict__ sr, float* __restrict__ si,
    unsigned short* __restrict__ Kd, unsigned short* __restrict__ Vd) {
  __shared__ unsigned short Kl2[4096];
  __shared__ unsigned short Vl2[4096];
  const int kt2 = blockIdx.x;          // 32-row group, 0..31
  const int bh = blockIdx.y;           // 0..63
  const int b = bh >> 4, h = bh & 15;
  const int tid = threadIdx.x;
  const float* qc = tabs + h * 64;
  const float* qs = tabs + 1024 + h * 64;
  const float* kc = tabs + 2048 + h * 64;
  const float* ks = tabs + 3072 + h * 64;
  #pragma unroll
  for (int p = 0; p < 8; ++p) {
    int id = p * 256 + tid;            // 2048 items = 32 rows x 64 dims
    int sl = id >> 6;
    int dd = id & 63;
    int s = kt2 * 32 + sl;
    int e = h * 64 + dd;
    int tok = x[b * 1024 + s];
    float mm = tanhf(te[tok * 1024 + e]);
    float sn, cs;
    sincosf(pp[s * 1024 + e], &sn, &cs);
    float re = mm * cs, im = mm * sn;
    size_t g = ((size_t)(b * 1024 + s)) * 1024 + e;
    sr[g] = re;
    si[g] = im;
    float cq = qc[dd], sq = qs[dd], ck = kc[dd], sk = ks[dd];
    float cd = cq * ck + sq * sk;      // cos(thq - thk)
    float sd = sq * ck - cq * sk;      // sin(thq - thk)
    float kr = re * cd + im * sd;      // k-state rotated by -delta
    float ki = im * cd - re * sd;
    int t = sl >> 4, key = sl & 15;
    int c0 = dd, c1 = 64 + dd;
    #define KOFF(c) (t * 2048 + ((((c) >> 5) * 4 + (((c) >> 3) & 3)) * 16 + key) * 8 + ((c) & 7))
    *(_Float16*)&Kl2[KOFF(c0)] = (_Float16)kr;
    *(_Float16*)&Kl2[KOFF(c1)] = (_Float16)ki;
    #undef KOFF
    int kgk = key >> 2, jk = key & 3;
    #define VOFF(d) (t * 2048 + ((((d) >> 4) * 4 + kgk) * 16 + ((d) & 15)) * 4 + jk)
    *(_Float16*)&Vl2[VOFF(dd)] = (_Float16)re;
    *(_Float16*)&Vl2[VOFF(64 + dd)] = (_Float16)im;
    #undef VOFF
  }
  __syncthreads();
  unsigned short* kdst = Kd + ((size_t)(bh * 64 + kt2 * 2)) * 2048;
  unsigned short* vdst = Vd + ((size_t)(bh * 64 + kt2 * 2)) * 2048;
  #pragma unroll
  for (int p = 0; p < 2; ++p) {
    int c = p * 256 + tid;
    ((int4*)kdst)[c] = ((const int4*)Kl2)[c];
    ((int4*)vdst)[c] = ((const int4*)Vl2)[c];
  }
}

// ---------------- fp16 MFMA flash attention, TQ=64, gload_lds dbuf ----------
// grid 1024: flat -> low=flat&7 (XCD=bh&7), qt=(flat>>3)>>3, bh=((flat>>3)&7)<<3|low
__global__ __launch_bounds__(256, 4) void attn_mfma_kernel(
    const float* __restrict__ sr, const float* __restrict__ si,
    const unsigned short* __restrict__ Kd, const unsigned short* __restrict__ Vd,
    const float* __restrict__ tabs,
    unsigned short* __restrict__ Af) {
  __shared__ __align__(16) unsigned short Klds[2][4096];
  __shared__ __align__(16) unsigned short Vlds[2][4096];
  const int flat = blockIdx.x;
  const int low = flat & 7, rest = flat >> 3;
  const int qt = rest >> 3;            // 0..15
  const int bh = ((rest & 7) << 3) | low;
  const int b = bh >> 4, h = bh & 15;
  const int tid = threadIdx.x, lane = tid & 63, wid = tid >> 6;
  const int cl = lane & 15, kg = lane >> 4;
  const int q0 = qt * 64, qw0 = q0 + wid * 16;

  // Q^T b-frag (fp16), this wave's 16 q-rows
  h8 qf[4];
  {
    int q = qw0 + cl;
    const float* srow = sr + ((size_t)(b * 1024 + q)) * 1024 + h * 64;
    const float* irow = si + ((size_t)(b * 1024 + q)) * 1024 + h * 64;
    #pragma unroll
    for (int ksx = 0; ksx < 4; ++ksx) {
      int f0 = ksx * 32 + kg * 8;
      const float* src = (f0 < 64) ? (srow + f0) : (irow + (f0 - 64));
      float4 v0 = *(const float4*)src;
      float4 v1 = *(const float4*)(src + 4);
      qf[ksx][0] = (_Float16)v0.x; qf[ksx][1] = (_Float16)v0.y;
      qf[ksx][2] = (_Float16)v0.z; qf[ksx][3] = (_Float16)v0.w;
      qf[ksx][4] = (_Float16)v1.x; qf[ksx][5] = (_Float16)v1.y;
      qf[ksx][6] = (_Float16)v1.z; qf[ksx][7] = (_Float16)v1.w;
    }
  }

  f4x acc[8] = {};                     // out^T: [mt], d = mt*16+kg*4+r (mt<4 re, >=4 im)
  float m_ = -1e30f, l_ = 0.f;
  const int np = qt * 2 + 2;           // 32-key pairs
  const int wqmax = qw0 + 15;
  const int qcol = qw0 + cl;

  const unsigned short* kstream = Kd + ((size_t)(bh * 64)) * 2048;
  const unsigned short* vstream = Vd + ((size_t)(bh * 64)) * 2048;

  // stage 32-key pair P (8KB K + 8KB V) into buffer `buf` via global_load_lds:
  // LDS dest = wave-uniform base + lane*16 (linear); zero VGPR cost.
  #define STAGE_PAIR(buf, P)                                                    \
    {                                                                           \
      const unsigned short* kb = kstream + (size_t)(P) * 4096;                  \
      const unsigned short* vb = vstream + (size_t)(P) * 4096;                  \
      _Pragma("unroll")                                                         \
      for (int r = 0; r < 2; ++r) {                                             \
        int off = r * 256 + wid * 64;                                           \
        gload16(kb + (size_t)(off + lane) * 8, &Klds[buf][off * 8]);            \
        gload16(vb + (size_t)(off + lane) * 8, &Vlds[buf][off * 8]);            \
      }                                                                         \
    }

  STAGE_PAIR(0, 0)
  __syncthreads();                     // pair 0 landed

  for (int p = 0; p < np; ++p) {
    const int cur = p & 1;
    if (p + 1 < np) STAGE_PAIR(cur ^ 1, p + 1)   // async: in flight during compute
    const int k0a = p * 32;
    if (k0a <= wqmax) {                // wave-uniform causal skip
      // scores^T for 32 keys (two 16-key tiles)
      __builtin_amdgcn_s_setprio(1);
      f4x sca = {}, scb = {};
      #pragma unroll
      for (int ksx = 0; ksx < 4; ++ksx) {
        h8 ka = *(const h8*)&Klds[cur][ksx * 512 + lane * 8];
        sca = MFMA32F16(ka, qf[ksx], sca);
      }
      #pragma unroll
      for (int ksx = 0; ksx < 4; ++ksx) {
        h8 kb = *(const h8*)&Klds[cur][2048 + ksx * 512 + lane * 8];
        scb = MFMA32F16(kb, qf[ksx], scb);
      }
      __builtin_amdgcn_s_setprio(0);
      if (k0a + 31 > qw0) {            // causal mask (boundary pairs only)
        #pragma unroll
        for (int r = 0; r < 4; ++r) {
          if (k0a + kg * 4 + r > qcol)      sca[r] = -1e30f;
          if (k0a + 16 + kg * 4 + r > qcol) scb[r] = -1e30f;
        }
      }
      // fused 32-key online softmax with defer-max (THR=8)
      float mx = fmaxf(fmaxf(fmaxf(sca[0], sca[1]), fmaxf(sca[2], sca[3])),
                       fmaxf(fmaxf(scb[0], scb[1]), fmaxf(scb[2], scb[3])));
      mx = fmaxf(mx, __shfl_xor(mx, 16, 64));
      mx = fmaxf(mx, __shfl_xor(mx, 32, 64));
      if (!__all(mx <= m_ + 8.0f)) {
        float mn = fmaxf(m_, mx);
        float corr = __expf(m_ - mn);
        #pragma unroll
        for (int mt = 0; mt < 8; ++mt) acc[mt] *= corr;
        l_ *= corr;
        m_ = mn;
      }
      float pa0 = __expf(sca[0] - m_), pa1 = __expf(sca[1] - m_);
      float pa2 = __expf(sca[2] - m_), pa3 = __expf(sca[3] - m_);
      float pb0 = __expf(scb[0] - m_), pb1 = __expf(scb[1] - m_);
      float pb2 = __expf(scb[2] - m_), pb3 = __expf(scb[3] - m_);
      float s0 = ((pa0 + pa1) + (pa2 + pa3)) + ((pb0 + pb1) + (pb2 + pb3));
      s0 += __shfl_xor(s0, 16, 64);
      s0 += __shfl_xor(s0, 32, 64);
      l_ += s0;
      h4 pba, pbb;
      pba[0] = (_Float16)pa0; pba[1] = (_Float16)pa1;
      pba[2] = (_Float16)pa2; pba[3] = (_Float16)pa3;
      pbb[0] = (_Float16)pb0; pbb[1] = (_Float16)pb1;
      pbb[2] = (_Float16)pb2; pbb[3] = (_Float16)pb3;
      __builtin_amdgcn_s_setprio(1);
      #pragma unroll
      for (int mt = 0; mt < 8; ++mt) {
        h4 va = *(const h4*)&Vlds[cur][mt * 256 + lane * 4];
        acc[mt] = MFMA16F16(va, pba, acc[mt]);
      }
      #pragma unroll
      for (int mt = 0; mt < 8; ++mt) {
        h4 vb = *(const h4*)&Vlds[cur][2048 + mt * 256 + lane * 4];
        acc[mt] = MFMA16F16(vb, pbb, acc[mt]);
      }
      __builtin_amdgcn_s_setprio(0);
    }
    // drains vmcnt (staged pair p+1 landed) + all waves done reading buf[cur]
    __syncthreads();
  }
  #undef STAGE_PAIR
  // epilogue: /l, rotate by exp(i*thv), add state, fp16 -> Af[4096][re1024|im1024]
  {
    float linv = 1.0f / l_;
    int q = qw0 + cl;
    size_t mrow = (size_t)(b * 1024 + q);
    size_t obase = mrow * 1024 + h * 64;
    size_t abase = mrow * 2048 + h * 64;
    #pragma unroll
    for (int mt = 0; mt < 4; ++mt) {
      int d0 = mt * 16 + kg * 4;
      float4 s_r = *(const float4*)&sr[obase + d0];
      float4 s_i = *(const float4*)&si[obase + d0];
      float srv[4] = {s_r.x, s_r.y, s_r.z, s_r.w};
      float siv[4] = {s_i.x, s_i.y, s_i.z, s_i.w};
      h4 hr, hi;
      #pragma unroll
      for (int r = 0; r < 4; ++r) {
        int d = d0 + r;
        float orv = acc[mt][r] * linv;
        float oiv = acc[mt + 4][r] * linv;
        float c = tabs[4096 + h * 64 + d], s = tabs[5120 + h * 64 + d];
        hr[r] = (_Float16)(orv * c - oiv * s + srv[r]);
        hi[r] = (_Float16)(orv * s + oiv * c + siv[r]);
      }
      *(h4*)&Af[abase + d0]        = hr;   // real
      *(h4*)&Af[abase + 1024 + d0] = hi;   // imag
    }
  }
}

// ---------------- transpose FF weight -> fp16: Bt[2048][2048] ----------------
__global__ void split_b_kernel(const float* __restrict__ fr, const float* __restrict__ fi,
                               unsigned short* __restrict__ Bt) {
  __shared__ float tile[32][33];
  const int k0 = blockIdx.x * 32, n0 = blockIdx.y * 32;
  const int tid = threadIdx.x;
  #pragma unroll
  for (int p = 0; p < 4; ++p) {
    int e = p * 256 + tid;
    int kk = e >> 5, nn = e & 31;
    int k = k0 + kk, n = n0 + nn;
    float v;
    if (n < 1024) v = (k < 1024) ? fr[(size_t)k * 1024 + n] : -fi[(size_t)(k - 1024) * 1024 + n];
    else          v = (k < 1024) ? fi[(size_t)k * 1024 + (n - 1024)]
                                 : fr[(size_t)(k - 1024) * 1024 + (n - 1024)];
    tile[kk][nn] = v;
  }
  __syncthreads();
  #pragma unroll
  for (int p = 0; p < 4; ++p) {
    int e = p * 256 + tid;
    int nn = e >> 5, kk = e & 31;
    *(_Float16*)&Bt[(size_t)(n0 + nn) * 2048 + (k0 + kk)] = (_Float16)tile[kk][nn];
  }
}

// ---------------- readout weight fp16: Wt[256][wr1024|wi1024] ----------------
__global__ void split_w_kernel(const float* __restrict__ wr, const float* __restrict__ wi,
                               unsigned short* __restrict__ Wt) {
  int idx = blockIdx.x * 256 + threadIdx.x;        // 256*512
  int v = idx >> 9;
  int k4 = (idx & 511) * 4;
  float4 a = (k4 < 1024) ? *(const float4*)&wr[(size_t)v * 1024 + k4]
                         : *(const float4*)&wi[(size_t)v * 1024 + k4 - 1024];
  h4 h;
  h[0] = (_Float16)a.x; h[1] = (_Float16)a.y;
  h[2] = (_Float16)a.z; h[3] = (_Float16)a.w;
  *(h4*)&Wt[(size_t)v * 2048 + k4] = h;
}

// ---------------- FF GEMM: fp16, 128x128 tile, BK=64, K=2048, K-split x2 ------
__global__ __launch_bounds__(256, 4) void gemm_ff(
    const unsigned short* __restrict__ A,   // [4096][2048] fp16 bits
    const unsigned short* __restrict__ Bt,  // [2048][2048]
    float* __restrict__ pr0, float* __restrict__ pi0,
    float* __restrict__ pr1, float* __restrict__ pi1) {
  __shared__ short As[128 * 64];
  __shared__ short Bs[128 * 64];
  const int tid = threadIdx.x;
  const int lane = tid & 63, wid = tid >> 6;
  const int m0 = blockIdx.x * 128, n0 = blockIdx.y * 128;
  const int z = blockIdx.z;
  const int wr = wid >> 1, wc = wid & 1;
  const int cl = lane & 15, rg = lane >> 4;

  f4x acc[4][4] = {};
  const int cbase = wid * 256;

  for (int kt = z * 16; kt < z * 16 + 16; ++kt) {
    const int k0 = kt * 64;
    #pragma unroll
    for (int it = 0; it < 4; ++it) {
      int c = cbase + it * 64 + lane;
      gload16(A + (size_t)(m0 + (c >> 3)) * 2048 + k0 + (c & 7) * 8,
              As + (cbase + it * 64) * 8);
      gload16(Bt + (size_t)(n0 + (c >> 3)) * 2048 + k0 + (c & 7) * 8,
              Bs + (cbase + it * 64) * 8);
    }
    __syncthreads();
    #pragma unroll
    for (int ks = 0; ks < 2; ++ks) {
      h8 a[4], b[4];
      #pragma unroll
      for (int ms = 0; ms < 4; ++ms)
        a[ms] = *(const h8*)&As[(wr * 64 + ms * 16 + cl) * 64 + ks * 32 + rg * 8];
      #pragma unroll
      for (int ns = 0; ns < 4; ++ns)
        b[ns] = *(const h8*)&Bs[(wc * 64 + ns * 16 + cl) * 64 + ks * 32 + rg * 8];
      #pragma unroll
      for (int ms = 0; ms < 4; ++ms)
        #pragma unroll
        for (int ns = 0; ns < 4; ++ns)
          acc[ms][ns] = MFMA32F16(a[ms], b[ns], acc[ms][ns]);
    }
    __syncthreads();
  }

  const int colbase = n0 + wc * 64;
  float* o_r = z ? pr1 : pr0;
  float* o_i = z ? pi1 : pi0;
  float* dst = (colbase < 1024) ? o_r : o_i;
  const int cb = colbase & 1023;
  #pragma unroll
  for (int ms = 0; ms < 4; ++ms)
    #pragma unroll
    for (int r2 = 0; r2 < 4; ++r2) {
      const int grow = m0 + wr * 64 + ms * 16 + rg * 4 + r2;
      #pragma unroll
      for (int ns = 0; ns < 4; ++ns)
        dst[(size_t)grow * 1024 + cb + ns * 16 + cl] = acc[ms][ns][r2];
    }
}

// ---------------- RO GEMM: fp16, 128x128 tile, K=2048, K-split x8 ------------
__global__ __launch_bounds__(256, 4) void gemm_ro(
    const unsigned short* __restrict__ Z,   // [4096][2048] fp16 bits
    const unsigned short* __restrict__ Wt,  // [256][2048]
    float* __restrict__ part) {             // [8][4096][256]
  __shared__ short As[128 * 64];
  __shared__ short Bs[128 * 64];
  const int tid = threadIdx.x;
  const int lane = tid & 63, wid = tid >> 6;
  const int m0 = blockIdx.x * 128, n0 = blockIdx.y * 128;
  const int z = blockIdx.z;
  const int wr = wid >> 1, wc = wid & 1;
  const int cl = lane & 15, rg = lane >> 4;

  f4x acc[4][4] = {};
  const int cbase = wid * 256;

  for (int kt = z * 4; kt < z * 4 + 4; ++kt) {
    const int k0 = kt * 64;
    #pragma unroll
    for (int it = 0; it < 4; ++it) {
      int c = cbase + it * 64 + lane;
      gload16(Z + (size_t)(m0 + (c >> 3)) * 2048 + k0 + (c & 7) * 8,
              As + (cbase + it * 64) * 8);
      gload16(Wt + (size_t)(n0 + (c >> 3)) * 2048 + k0 + (c & 7) * 8,
              Bs + (cbase + it * 64) * 8);
    }
    __syncthreads();
    #pragma unroll
    for (int ks = 0; ks < 2; ++ks) {
      h8 a[4], b[4];
      #pragma unroll
      for (int ms = 0; ms < 4; ++ms)
        a[ms] = *(const h8*)&As[(wr * 64 + ms * 16 + cl) * 64 + ks * 32 + rg * 8];
      #pragma unroll
      for (int ns = 0; ns < 4; ++ns)
        b[ns] = *(const h8*)&Bs[(wc * 64 + ns * 16 + cl) * 64 + ks * 32 + rg * 8];
      #pragma unroll
      for (int ms = 0; ms < 4; ++ms)
        #pragma unroll
        for (int ns = 0; ns < 4; ++ns)
          acc[ms][ns] = MFMA32F16(a[ms], b[ns], acc[ms][ns]);
    }
    __syncthreads();
  }

  float* dst = part + (size_t)z * 4096 * 256;
  const int colbase = n0 + wc * 64;
  #pragma unroll
  for (int ms = 0; ms < 4; ++ms)
    #pragma unroll
    for (int r2 = 0; r2 < 4; ++r2) {
      const int grow = m0 + wr * 64 + ms * 16 + rg * 4 + r2;
      #pragma unroll
      for (int ns = 0; ns < 4; ++ns)
        dst[(size_t)grow * 256 + colbase + ns * 16 + cl] = acc[ms][ns][r2];
    }
}

// ---------------- complex_norm over FF partial sums -> fp16 Z ----------------
__global__ __launch_bounds__(256) void norm_split_kernel(
    const float* __restrict__ pr0, const float* __restrict__ pi0,
    const float* __restrict__ pr1, const float* __restrict__ pi1,
    unsigned short* __restrict__ Z) {
  const int row = blockIdx.x, tid = threadIdx.x;
  const int base = row * E_ + tid * 4;
  float4 r0 = *(const float4*)&pr0[base];
  float4 r1 = *(const float4*)&pr1[base];
  float4 i0 = *(const float4*)&pi0[base];
  float4 i1 = *(const float4*)&pi1[base];
  float4 zr = make_float4(r0.x + r1.x, r0.y + r1.y, r0.z + r1.z, r0.w + r1.w);
  float4 zi = make_float4(i0.x + i1.x, i0.y + i1.y, i0.z + i1.z, i0.w + i1.w);
  float mg[4];
  mg[0] = sqrtf(zr.x * zr.x + zi.x * zi.x);
  mg[1] = sqrtf(zr.y * zr.y + zi.y * zi.y);
  mg[2] = sqrtf(zr.z * zr.z + zi.z * zi.z);
  mg[3] = sqrtf(zr.w * zr.w + zi.w * zi.w);
  float s1 = mg[0] + mg[1] + mg[2] + mg[3];
  float s2 = mg[0]*mg[0] + mg[1]*mg[1] + mg[2]*mg[2] + mg[3]*mg[3];
  #pragma unroll
  for (int off = 1; off < 64; off <<= 1) {
    s1 += __shfl_xor(s1, off, 64);
    s2 += __shfl_xor(s2, off, 64);
  }
  __shared__ float ws1[4], ws2[4];
  if ((tid & 63) == 0) { ws1[tid >> 6] = s1; ws2[tid >> 6] = s2; }
  __syncthreads();
  s1 = ws1[0] + ws1[1] + ws1[2] + ws1[3];
  s2 = ws2[0] + ws2[1] + ws2[2] + ws2[3];
  float mean = s1 * (1.0f / 1024.0f);
  float var = (s2 - 1024.0f * mean * mean) * (1.0f / 1023.0f);  // ddof=1
  var = fmaxf(var, 0.0f);
  float inv_sd = 1.0f / (sqrtf(var) + 1e-5f);
  float sc[4];
  #pragma unroll
  for (int t = 0; t < 4; ++t)
    sc[t] = tanhf((mg[t] - mean) * inv_sd) / (mg[t] + 1e-5f);
  h4 hr, hi;
  hr[0] = (_Float16)(zr.x * sc[0]); hr[1] = (_Float16)(zr.y * sc[1]);
  hr[2] = (_Float16)(zr.z * sc[2]); hr[3] = (_Float16)(zr.w * sc[3]);
  hi[0] = (_Float16)(zi.x * sc[0]); hi[1] = (_Float16)(zi.y * sc[1]);
  hi[2] = (_Float16)(zi.z * sc[2]); hi[3] = (_Float16)(zi.w * sc[3]);
  const size_t zb = (size_t)row * 2048 + tid * 4;
  *(h4*)&Z[zb]        = hr;
  *(h4*)&Z[zb + 1024] = hi;
}

// ---------------- reduce RO partials + biases -> out ----------------
__global__ void reduce_bias_kernel(const float* __restrict__ part,
                                   const float* __restrict__ rb,
                                   const float* __restrict__ ib,
                                   float* __restrict__ out) {
  int i4 = (blockIdx.x * 256 + threadIdx.x) * 4;   // < 4096*256
  int col = i4 & 255;
  float4 s = *(const float4*)&part[i4];
  #pragma unroll
  for (int z = 1; z < 8; ++z) {
    float4 v = *(const float4*)&part[(size_t)z * 1048576 + i4];
    s.x += v.x; s.y += v.y; s.z += v.z; s.w += v.w;
  }
  s.x += rb[col + 0] + ib[col + 0];
  s.y += rb[col + 1] + ib[col + 1];
  s.z += rb[col + 2] + ib[col + 2];
  s.w += rb[col + 3] + ib[col + 3];
  *(float4*)&out[i4] = s;
}

extern "C" void kernel_launch(void* const* d_in, const int* in_sizes, int n_in,
                              void* d_out, int out_size, void* d_ws, size_t ws_size,
                              hipStream_t stream) {
  const int*   x    = (const int*)d_in[0];
  const float* te   = (const float*)d_in[1];
  const float* pp   = (const float*)d_in[2];
  const float* qr   = (const float*)d_in[3];
  const float* kr   = (const float*)d_in[4];
  const float* vr   = (const float*)d_in[5];
  const float* ffr  = (const float*)d_in[6];
  const float* ffi  = (const float*)d_in[7];
  const float* rorw = (const float*)d_in[8];
  const float* rorb = (const float*)d_in[9];
  const float* roiw = (const float*)d_in[10];
  const float* roib = (const float*)d_in[11];
  float* out = (float*)d_out;

  char* W = (char*)d_ws;
  const size_t MiB = 1 << 20;
  // [0,16) sr -> pr0 | [16,32) si -> pi0
  // [32,48) Af -> Zhl
  // [48,64) Kd -> Bt[48,56) + Wt[56,57)   (after attn)
  // [64,80) Vd -> pr1 ┐
  // [80,96) pi1       ┴-> ro_part [64,96)  (after norm)
  // [96,+24K) tabs
  float* sr  = (float*)W;
  float* si  = (float*)(W + 16 * MiB);
  unsigned short* Af = (unsigned short*)(W + 32 * MiB);
  unsigned short* Kd = (unsigned short*)(W + 48 * MiB);
  unsigned short* Vd = (unsigned short*)(W + 64 * MiB);
  unsigned short* Bt = (unsigned short*)(W + 48 * MiB);
  unsigned short* Wt = (unsigned short*)(W + 56 * MiB);
  float* tabs = (float*)(W + 96 * MiB);
  float* pr0 = sr;
  float* pi0 = si;
  float* pr1 = (float*)(W + 64 * MiB);
  float* pi1 = (float*)(W + 80 * MiB);
  unsigned short* Zhl = Af;
  float* ro_part = (float*)(W + 64 * MiB);   // 8 x 4 MiB

  rot_kernel<<<12, 256, 0, stream>>>(qr, kr, vr, tabs);
  embed_qkv_kernel<<<dim3(32, 64), 256, 0, stream>>>(x, te, pp, tabs, sr, si, Kd, Vd);
  attn_mfma_kernel<<<1024, 256, 0, stream>>>(sr, si, Kd, Vd, tabs, Af);
  split_b_kernel<<<dim3(64, 64), 256, 0, stream>>>(ffr, ffi, Bt);
  split_w_kernel<<<512, 256, 0, stream>>>(rorw, roiw, Wt);
  gemm_ff<<<dim3(32, 16, 2), 256, 0, stream>>>(Af, Bt, pr0, pi0, pr1, pi1);
  norm_split_kernel<<<B_ * S_, 256, 0, stream>>>(pr0, pi0, pr1, pi1, Zhl);
  gemm_ro<<<dim3(32, 2, 8), 256, 0, stream>>>(Zhl, Wt, ro_part);
  reduce_bias_kernel<<<1024, 256, 0, stream>>>(ro_part, rorb, roib, out);
}

// Round 13
// 156.030 us; speedup vs baseline: 1.3627x; 1.0338x over previous
//
#include <hip/hip_runtime.h>
#include <math.h>

// PhaseMultiHeadDecoder: B=4, S=1024, E=1024, H=16, hd=64, V=256
// Full fp16 pipeline. attn: balanced block pairing {a, 31-a} (const 66
// wave-pairs/block), gload_lds dbuf 2-phase pipeline, fused 32-key softmax,
// defer-max, setprio. FF/RO fp16 GEMM (K=2048) K-split.
#define B_ 4
#define S_ 1024
#define E_ 1024
#define H_ 16
#define V_ 256

typedef _Float16 h8 __attribute__((ext_vector_type(8)));
typedef _Float16 h4 __attribute__((ext_vector_type(4)));
typedef float f4x __attribute__((ext_vector_type(4)));

__device__ __forceinline__ void gload16(const void* g, void* l) {
  __builtin_amdgcn_global_load_lds((const __attribute__((address_space(1))) void*)g,
                                   (__attribute__((address_space(3))) void*)l, 16, 0, 0);
}

#define MFMA32F16(a, b, c) __builtin_amdgcn_mfma_f32_16x16x32_f16(a, b, c, 0, 0, 0)

#if defined(__has_builtin)
#if __has_builtin(__builtin_amdgcn_mfma_f32_16x16x16f16)
#define MFMA16F16(a, b, c) __builtin_amdgcn_mfma_f32_16x16x16f16(a, b, c, 0, 0, 0)
#endif
#endif
#ifndef MFMA16F16
__device__ __forceinline__ f4x mfma16f16_asm(h4 a, h4 b, f4x c) {
  asm volatile("v_mfma_f32_16x16x16_f16 %0, %1, %2, %0" : "+v"(c) : "v"(a), "v"(b));
  return c;
}
#define MFMA16F16(a, b, c) mfma16f16_asm(a, b, c)
#endif

// ---------------- rotation cos/sin tables: tabs[3][2][1024] ----------------
__global__ void rot_kernel(const float* __restrict__ qr, const float* __restrict__ kr,
                           const float* __restrict__ vr, float* __restrict__ tabs) {
  int i = blockIdx.x * blockDim.x + threadIdx.x;
  if (i >= 3 * 1024) return;
  int which = i >> 10;
  int j = i & 1023;
  const float* src = which == 0 ? qr : (which == 1 ? kr : vr);
  float s, c;
  sincosf(src[j], &s, &c);
  tabs[which * 2048 + j] = c;
  tabs[which * 2048 + 1024 + j] = s;
}

// ---------------- fused embed + K'/V' prep (fp16) ----------------
__global__ __launch_bounds__(256) void embed_qkv_kernel(
    const int* __restrict__ x, const float* __restrict__ te,
    const float* __restrict__ pp, const float* __restrict__ tabs,
    float* __restrict__ sr, float* __restrict__ si,
    unsigned short* __restrict__ Kd, unsigned short* __restrict__ Vd) {
  __shared__ unsigned short Kl2[4096];
  __shared__ unsigned short Vl2[4096];
  const int kt2 = blockIdx.x;          // 32-row group, 0..31
  const int bh = blockIdx.y;           // 0..63
  const int b = bh >> 4, h = bh & 15;
  const int tid = threadIdx.x;
  const float* qc = tabs + h * 64;
  const float* qs = tabs + 1024 + h * 64;
  const float* kc = tabs + 2048 + h * 64;
  const float* ks = tabs + 3072 + h * 64;
  #pragma unroll
  for (int p = 0; p < 8; ++p) {
    int id = p * 256 + tid;            // 2048 items = 32 rows x 64 dims
    int sl = id >> 6;
    int dd = id & 63;
    int s = kt2 * 32 + sl;
    int e = h * 64 + dd;
    int tok = x[b * 1024 + s];
    float mm = tanhf(te[tok * 1024 + e]);
    float sn, cs;
    sincosf(pp[s * 1024 + e], &sn, &cs);
    float re = mm * cs, im = mm * sn;
    size_t g = ((size_t)(b * 1024 + s)) * 1024 + e;
    sr[g] = re;
    si[g] = im;
    float cq = qc[dd], sq = qs[dd], ck = kc[dd], sk = ks[dd];
    float cd = cq * ck + sq * sk;      // cos(thq - thk)
    float sd = sq * ck - cq * sk;      // sin(thq - thk)
    float kr = re * cd + im * sd;      // k-state rotated by -delta
    float ki = im * cd - re * sd;
    int t = sl >> 4, key = sl & 15;
    int c0 = dd, c1 = 64 + dd;
    #define KOFF(c) (t * 2048 + ((((c) >> 5) * 4 + (((c) >> 3) & 3)) * 16 + key) * 8 + ((c) & 7))
    *(_Float16*)&Kl2[KOFF(c0)] = (_Float16)kr;
    *(_Float16*)&Kl2[KOFF(c1)] = (_Float16)ki;
    #undef KOFF
    int kgk = key >> 2, jk = key & 3;
    #define VOFF(d) (t * 2048 + ((((d) >> 4) * 4 + kgk) * 16 + ((d) & 15)) * 4 + jk)
    *(_Float16*)&Vl2[VOFF(dd)] = (_Float16)re;
    *(_Float16*)&Vl2[VOFF(64 + dd)] = (_Float16)im;
    #undef VOFF
  }
  __syncthreads();
  unsigned short* kdst = Kd + ((size_t)(bh * 64 + kt2 * 2)) * 2048;
  unsigned short* vdst = Vd + ((size_t)(bh * 64 + kt2 * 2)) * 2048;
  #pragma unroll
  for (int p = 0; p < 2; ++p) {
    int c = p * 256 + tid;
    ((int4*)kdst)[c] = ((const int4*)Kl2)[c];
    ((int4*)vdst)[c] = ((const int4*)Vl2)[c];
  }
}

// ---------------- fp16 MFMA flash attention, balanced pairing ----------------
// grid 1024: flat -> low=flat&7 (XCD=bh&7), a=(flat>>3)>>3 in 0..15,
// bh=((flat>>3)&7)<<3|low. Waves 0-1: rows 32a..32a+31; waves 2-3: rows
// 32(31-a)..+31. Per-block work = 2(a+1)+2(32-a) = 66 wave-pairs (constant).
__global__ __launch_bounds__(256, 4) void attn_mfma_kernel(
    const float* __restrict__ sr, const float* __restrict__ si,
    const unsigned short* __restrict__ Kd, const unsigned short* __restrict__ Vd,
    const float* __restrict__ tabs,
    unsigned short* __restrict__ Af) {
  __shared__ __align__(16) unsigned short Klds[2][4096];
  __shared__ __align__(16) unsigned short Vlds[2][4096];
  const int flat = blockIdx.x;
  const int low = flat & 7, rest = flat >> 3;
  const int a = rest >> 3;             // 0..15 (pair index)
  const int bh = ((rest & 7) << 3) | low;
  const int b = bh >> 4, h = bh & 15;
  const int tid = threadIdx.x, lane = tid & 63, wid = tid >> 6;
  const int cl = lane & 15, kg = lane >> 4;
  const int atile = (wid >> 1) ? (31 - a) : a;      // 32-row half-tile
  const int qw0 = atile * 32 + (wid & 1) * 16;      // this wave's 16 q-rows

  // Q^T b-frag (fp16), this wave's 16 q-rows
  h8 qf[4];
  {
    int q = qw0 + cl;
    const float* srow = sr + ((size_t)(b * 1024 + q)) * 1024 + h * 64;
    const float* irow = si + ((size_t)(b * 1024 + q)) * 1024 + h * 64;
    #pragma unroll
    for (int ksx = 0; ksx < 4; ++ksx) {
      int f0 = ksx * 32 + kg * 8;
      const float* src = (f0 < 64) ? (srow + f0) : (irow + (f0 - 64));
      float4 v0 = *(const float4*)src;
      float4 v1 = *(const float4*)(src + 4);
      qf[ksx][0] = (_Float16)v0.x; qf[ksx][1] = (_Float16)v0.y;
      qf[ksx][2] = (_Float16)v0.z; qf[ksx][3] = (_Float16)v0.w;
      qf[ksx][4] = (_Float16)v1.x; qf[ksx][5] = (_Float16)v1.y;
      qf[ksx][6] = (_Float16)v1.z; qf[ksx][7] = (_Float16)v1.w;
    }
  }

  f4x acc[8] = {};                     // out^T: [mt], d = mt*16+kg*4+r (mt<4 re, >=4 im)
  float m_ = -1e30f, l_ = 0.f;
  const int np = 32 - a;               // staged 32-key pairs (covers high tile)
  const int wqmax = qw0 + 15;
  const int qcol = qw0 + cl;

  const unsigned short* kstream = Kd + ((size_t)(bh * 64)) * 2048;
  const unsigned short* vstream = Vd + ((size_t)(bh * 64)) * 2048;

  // stage 32-key pair P (8KB K + 8KB V) into buffer `buf` via global_load_lds
  #define STAGE_PAIR(buf, P)                                                    \
    {                                                                           \
      const unsigned short* kb = kstream + (size_t)(P) * 4096;                  \
      const unsigned short* vb = vstream + (size_t)(P) * 4096;                  \
      _Pragma("unroll")                                                         \
      for (int r = 0; r < 2; ++r) {                                             \
        int off = r * 256 + wid * 64;                                           \
        gload16(kb + (size_t)(off + lane) * 8, &Klds[buf][off * 8]);            \
        gload16(vb + (size_t)(off + lane) * 8, &Vlds[buf][off * 8]);            \
      }                                                                         \
    }

  STAGE_PAIR(0, 0)
  __syncthreads();                     // pair 0 landed

  for (int p = 0; p < np; ++p) {
    const int cur = p & 1;
    if (p + 1 < np) STAGE_PAIR(cur ^ 1, p + 1)   // async: in flight during compute
    const int k0a = p * 32;
    if (k0a <= wqmax) {                // wave-uniform causal skip
      // scores^T for 32 keys (two 16-key tiles)
      __builtin_amdgcn_s_setprio(1);
      f4x sca = {}, scb = {};
      #pragma unroll
      for (int ksx = 0; ksx < 4; ++ksx) {
        h8 ka = *(const h8*)&Klds[cur][ksx * 512 + lane * 8];
        sca = MFMA32F16(ka, qf[ksx], sca);
      }
      #pragma unroll
      for (int ksx = 0; ksx < 4; ++ksx) {
        h8 kb = *(const h8*)&Klds[cur][2048 + ksx * 512 + lane * 8];
        scb = MFMA32F16(kb, qf[ksx], scb);
      }
      __builtin_amdgcn_s_setprio(0);
      if (k0a + 31 > qw0) {            // causal mask (boundary pairs only)
        #pragma unroll
        for (int r = 0; r < 4; ++r) {
          if (k0a + kg * 4 + r > qcol)      sca[r] = -1e30f;
          if (k0a + 16 + kg * 4 + r > qcol) scb[r] = -1e30f;
        }
      }
      // fused 32-key online softmax with defer-max (THR=8)
      float mx = fmaxf(fmaxf(fmaxf(sca[0], sca[1]), fmaxf(sca[2], sca[3])),
                       fmaxf(fmaxf(scb[0], scb[1]), fmaxf(scb[2], scb[3])));
      mx = fmaxf(mx, __shfl_xor(mx, 16, 64));
      mx = fmaxf(mx, __shfl_xor(mx, 32, 64));
      if (!__all(mx <= m_ + 8.0f)) {
        float mn = fmaxf(m_, mx);
        float corr = __expf(m_ - mn);
        #pragma unroll
        for (int mt = 0; mt < 8; ++mt) acc[mt] *= corr;
        l_ *= corr;
        m_ = mn;
      }
      float pa0 = __expf(sca[0] - m_), pa1 = __expf(sca[1] - m_);
      float pa2 = __expf(sca[2] - m_), pa3 = __expf(sca[3] - m_);
      float pb0 = __expf(scb[0] - m_), pb1 = __expf(scb[1] - m_);
      float pb2 = __expf(scb[2] - m_), pb3 = __expf(scb[3] - m_);
      float s0 = ((pa0 + pa1) + (pa2 + pa3)) + ((pb0 + pb1) + (pb2 + pb3));
      s0 += __shfl_xor(s0, 16, 64);
      s0 += __shfl_xor(s0, 32, 64);
      l_ += s0;
      h4 pba, pbb;
      pba[0] = (_Float16)pa0; pba[1] = (_Float16)pa1;
      pba[2] = (_Float16)pa2; pba[3] = (_Float16)pa3;
      pbb[0] = (_Float16)pb0; pbb[1] = (_Float16)pb1;
      pbb[2] = (_Float16)pb2; pbb[3] = (_Float16)pb3;
      __builtin_amdgcn_s_setprio(1);
      #pragma unroll
      for (int mt = 0; mt < 8; ++mt) {
        h4 va = *(const h4*)&Vlds[cur][mt * 256 + lane * 4];
        acc[mt] = MFMA16F16(va, pba, acc[mt]);
      }
      #pragma unroll
      for (int mt = 0; mt < 8; ++mt) {
        h4 vb = *(const h4*)&Vlds[cur][2048 + mt * 256 + lane * 4];
        acc[mt] = MFMA16F16(vb, pbb, acc[mt]);
      }
      __builtin_amdgcn_s_setprio(0);
    }
    // drains vmcnt (staged pair p+1 landed) + all waves done reading buf[cur]
    __syncthreads();
  }
  #undef STAGE_PAIR
  // epilogue: /l, rotate by exp(i*thv), add state, fp16 -> Af[4096][re1024|im1024]
  {
    float linv = 1.0f / l_;
    int q = qw0 + cl;
    size_t mrow = (size_t)(b * 1024 + q);
    size_t obase = mrow * 1024 + h * 64;
    size_t abase = mrow * 2048 + h * 64;
    #pragma unroll
    for (int mt = 0; mt < 4; ++mt) {
      int d0 = mt * 16 + kg * 4;
      float4 s_r = *(const float4*)&sr[obase + d0];
      float4 s_i = *(const float4*)&si[obase + d0];
      float srv[4] = {s_r.x, s_r.y, s_r.z, s_r.w};
      float siv[4] = {s_i.x, s_i.y, s_i.z, s_i.w};
      h4 hr, hi;
      #pragma unroll
      for (int r = 0; r < 4; ++r) {
        int d = d0 + r;
        float orv = acc[mt][r] * linv;
        float oiv = acc[mt + 4][r] * linv;
        float c = tabs[4096 + h * 64 + d], s = tabs[5120 + h * 64 + d];
        hr[r] = (_Float16)(orv * c - oiv * s + srv[r]);
        hi[r] = (_Float16)(orv * s + oiv * c + siv[r]);
      }
      *(h4*)&Af[abase + d0]        = hr;   // real
      *(h4*)&Af[abase + 1024 + d0] = hi;   // imag
    }
  }
}

// ---------------- transpose FF weight -> fp16: Bt[2048][2048] ----------------
__global__ void split_b_kernel(const float* __restrict__ fr, const float* __restrict__ fi,
                               unsigned short* __restrict__ Bt) {
  __shared__ float tile[32][33];
  const int k0 = blockIdx.x * 32, n0 = blockIdx.y * 32;
  const int tid = threadIdx.x;
  #pragma unroll
  for (int p = 0; p < 4; ++p) {
    int e = p * 256 + tid;
    int kk = e >> 5, nn = e & 31;
    int k = k0 + kk, n = n0 + nn;
    float v;
    if (n < 1024) v = (k < 1024) ? fr[(size_t)k * 1024 + n] : -fi[(size_t)(k - 1024) * 1024 + n];
    else          v = (k < 1024) ? fi[(size_t)k * 1024 + (n - 1024)]
                                 : fr[(size_t)(k - 1024) * 1024 + (n - 1024)];
    tile[kk][nn] = v;
  }
  __syncthreads();
  #pragma unroll
  for (int p = 0; p < 4; ++p) {
    int e = p * 256 + tid;
    int nn = e >> 5, kk = e & 31;
    *(_Float16*)&Bt[(size_t)(n0 + nn) * 2048 + (k0 + kk)] = (_Float16)tile[kk][nn];
  }
}

// ---------------- readout weight fp16: Wt[256][wr1024|wi1024] ----------------
__global__ void split_w_kernel(const float* __restrict__ wr, const float* __restrict__ wi,
                               unsigned short* __restrict__ Wt) {
  int idx = blockIdx.x * 256 + threadIdx.x;        // 256*512
  int v = idx >> 9;
  int k4 = (idx & 511) * 4;
  float4 a = (k4 < 1024) ? *(const float4*)&wr[(size_t)v * 1024 + k4]
                         : *(const float4*)&wi[(size_t)v * 1024 + k4 - 1024];
  h4 h;
  h[0] = (_Float16)a.x; h[1] = (_Float16)a.y;
  h[2] = (_Float16)a.z; h[3] = (_Float16)a.w;
  *(h4*)&Wt[(size_t)v * 2048 + k4] = h;
}

// ---------------- FF GEMM: fp16, 128x128 tile, BK=64, K=2048, K-split x2 ------
__global__ __launch_bounds__(256, 4) void gemm_ff(
    const unsigned short* __restrict__ A,   // [4096][2048] fp16 bits
    const unsigned short* __restrict__ Bt,  // [2048][2048]
    float* __restrict__ pr0, float* __restrict__ pi0,
    float* __restrict__ pr1, float* __restrict__ pi1) {
  __shared__ short As[128 * 64];
  __shared__ short Bs[128 * 64];
  const int tid = threadIdx.x;
  const int lane = tid & 63, wid = tid >> 6;
  const int m0 = blockIdx.x * 128, n0 = blockIdx.y * 128;
  const int z = blockIdx.z;
  const int wr = wid >> 1, wc = wid & 1;
  const int cl = lane & 15, rg = lane >> 4;

  f4x acc[4][4] = {};
  const int cbase = wid * 256;

  for (int kt = z * 16; kt < z * 16 + 16; ++kt) {
    const int k0 = kt * 64;
    #pragma unroll
    for (int it = 0; it < 4; ++it) {
      int c = cbase + it * 64 + lane;
      gload16(A + (size_t)(m0 + (c >> 3)) * 2048 + k0 + (c & 7) * 8,
              As + (cbase + it * 64) * 8);
      gload16(Bt + (size_t)(n0 + (c >> 3)) * 2048 + k0 + (c & 7) * 8,
              Bs + (cbase + it * 64) * 8);
    }
    __syncthreads();
    #pragma unroll
    for (int ks = 0; ks < 2; ++ks) {
      h8 a[4], b[4];
      #pragma unroll
      for (int ms = 0; ms < 4; ++ms)
        a[ms] = *(const h8*)&As[(wr * 64 + ms * 16 + cl) * 64 + ks * 32 + rg * 8];
      #pragma unroll
      for (int ns = 0; ns < 4; ++ns)
        b[ns] = *(const h8*)&Bs[(wc * 64 + ns * 16 + cl) * 64 + ks * 32 + rg * 8];
      #pragma unroll
      for (int ms = 0; ms < 4; ++ms)
        #pragma unroll
        for (int ns = 0; ns < 4; ++ns)
          acc[ms][ns] = MFMA32F16(a[ms], b[ns], acc[ms][ns]);
    }
    __syncthreads();
  }

  const int colbase = n0 + wc * 64;
  float* o_r = z ? pr1 : pr0;
  float* o_i = z ? pi1 : pi0;
  float* dst = (colbase < 1024) ? o_r : o_i;
  const int cb = colbase & 1023;
  #pragma unroll
  for (int ms = 0; ms < 4; ++ms)
    #pragma unroll
    for (int r2 = 0; r2 < 4; ++r2) {
      const int grow = m0 + wr * 64 + ms * 16 + rg * 4 + r2;
      #pragma unroll
      for (int ns = 0; ns < 4; ++ns)
        dst[(size_t)grow * 1024 + cb + ns * 16 + cl] = acc[ms][ns][r2];
    }
}

// ---------------- RO GEMM: fp16, 128x128 tile, K=2048, K-split x8 ------------
__global__ __launch_bounds__(256, 4) void gemm_ro(
    const unsigned short* __restrict__ Z,   // [4096][2048] fp16 bits
    const unsigned short* __restrict__ Wt,  // [256][2048]
    float* __restrict__ part) {             // [8][4096][256]
  __shared__ short As[128 * 64];
  __shared__ short Bs[128 * 64];
  const int tid = threadIdx.x;
  const int lane = tid & 63, wid = tid >> 6;
  const int m0 = blockIdx.x * 128, n0 = blockIdx.y * 128;
  const int z = blockIdx.z;
  const int wr = wid >> 1, wc = wid & 1;
  const int cl = lane & 15, rg = lane >> 4;

  f4x acc[4][4] = {};
  const int cbase = wid * 256;

  for (int kt = z * 4; kt < z * 4 + 4; ++kt) {
    const int k0 = kt * 64;
    #pragma unroll
    for (int it = 0; it < 4; ++it) {
      int c = cbase + it * 64 + lane;
      gload16(Z + (size_t)(m0 + (c >> 3)) * 2048 + k0 + (c & 7) * 8,
              As + (cbase + it * 64) * 8);
      gload16(Wt + (size_t)(n0 + (c >> 3)) * 2048 + k0 + (c & 7) * 8,
              Bs + (cbase + it * 64) * 8);
    }
    __syncthreads();
    #pragma unroll
    for (int ks = 0; ks < 2; ++ks) {
      h8 a[4], b[4];
      #pragma unroll
      for (int ms = 0; ms < 4; ++ms)
        a[ms] = *(const h8*)&As[(wr * 64 + ms * 16 + cl) * 64 + ks * 32 + rg * 8];
      #pragma unroll
      for (int ns = 0; ns < 4; ++ns)
        b[ns] = *(const h8*)&Bs[(wc * 64 + ns * 16 + cl) * 64 + ks * 32 + rg * 8];
      #pragma unroll
      for (int ms = 0; ms < 4; ++ms)
        #pragma unroll
        for (int ns = 0; ns < 4; ++ns)
          acc[ms][ns] = MFMA32F16(a[ms], b[ns], acc[ms][ns]);
    }
    __syncthreads();
  }

  float* dst = part + (size_t)z * 4096 * 256;
  const int colbase = n0 + wc * 64;
  #pragma unroll
  for (int ms = 0; ms < 4; ++ms)
    #pragma unroll
    for (int r2 = 0; r2 < 4; ++r2) {
      const int grow = m0 + wr * 64 + ms * 16 + rg * 4 + r2;
      #pragma unroll
      for (int ns = 0; ns < 4; ++ns)
        dst[(size_t)grow * 256 + colbase + ns * 16 + cl] = acc[ms][ns][r2];
    }
}

// ---------------- complex_norm over FF partial sums -> fp16 Z ----------------
__global__ __launch_bounds__(256) void norm_split_kernel(
    const float* __restrict__ pr0, const float* __restrict__ pi0,
    const float* __restrict__ pr1, const float* __restrict__ pi1,
    unsigned short* __restrict__ Z) {
  const int row = blockIdx.x, tid = threadIdx.x;
  const int base = row * E_ + tid * 4;
  float4 r0 = *(const float4*)&pr0[base];
  float4 r1 = *(const float4*)&pr1[base];
  float4 i0 = *(const float4*)&pi0[base];
  float4 i1 = *(const float4*)&pi1[base];
  float4 zr = make_float4(r0.x + r1.x, r0.y + r1.y, r0.z + r1.z, r0.w + r1.w);
  float4 zi = make_float4(i0.x + i1.x, i0.y + i1.y, i0.z + i1.z, i0.w + i1.w);
  float mg[4];
  mg[0] = sqrtf(zr.x * zr.x + zi.x * zi.x);
  mg[1] = sqrtf(zr.y * zr.y + zi.y * zi.y);
  mg[2] = sqrtf(zr.z * zr.z + zi.z * zi.z);
  mg[3] = sqrtf(zr.w * zr.w + zi.w * zi.w);
  float s1 = mg[0] + mg[1] + mg[2] + mg[3];
  float s2 = mg[0]*mg[0] + mg[1]*mg[1] + mg[2]*mg[2] + mg[3]*mg[3];
  #pragma unroll
  for (int off = 1; off < 64; off <<= 1) {
    s1 += __shfl_xor(s1, off, 64);
    s2 += __shfl_xor(s2, off, 64);
  }
  __shared__ float ws1[4], ws2[4];
  if ((tid & 63) == 0) { ws1[tid >> 6] = s1; ws2[tid >> 6] = s2; }
  __syncthreads();
  s1 = ws1[0] + ws1[1] + ws1[2] + ws1[3];
  s2 = ws2[0] + ws2[1] + ws2[2] + ws2[3];
  float mean = s1 * (1.0f / 1024.0f);
  float var = (s2 - 1024.0f * mean * mean) * (1.0f / 1023.0f);  // ddof=1
  var = fmaxf(var, 0.0f);
  float inv_sd = 1.0f / (sqrtf(var) + 1e-5f);
  float sc[4];
  #pragma unroll
  for (int t = 0; t < 4; ++t)
    sc[t] = tanhf((mg[t] - mean) * inv_sd) / (mg[t] + 1e-5f);
  h4 hr, hi;
  hr[0] = (_Float16)(zr.x * sc[0]); hr[1] = (_Float16)(zr.y * sc[1]);
  hr[2] = (_Float16)(zr.z * sc[2]); hr[3] = (_Float16)(zr.w * sc[3]);
  hi[0] = (_Float16)(zi.x * sc[0]); hi[1] = (_Float16)(zi.y * sc[1]);
  hi[2] = (_Float16)(zi.z * sc[2]); hi[3] = (_Float16)(zi.w * sc[3]);
  const size_t zb = (size_t)row * 2048 + tid * 4;
  *(h4*)&Z[zb]        = hr;
  *(h4*)&Z[zb + 1024] = hi;
}

// ---------------- reduce RO partials + biases -> out ----------------
__global__ void reduce_bias_kernel(const float* __restrict__ part,
                                   const float* __restrict__ rb,
                                   const float* __restrict__ ib,
                                   float* __restrict__ out) {
  int i4 = (blockIdx.x * 256 + threadIdx.x) * 4;   // < 4096*256
  int col = i4 & 255;
  float4 s = *(const float4*)&part[i4];
  #pragma unroll
  for (int z = 1; z < 8; ++z) {
    float4 v = *(const float4*)&part[(size_t)z * 1048576 + i4];
    s.x += v.x; s.y += v.y; s.z += v.z; s.w += v.w;
  }
  s.x += rb[col + 0] + ib[col + 0];
  s.y += rb[col + 1] + ib[col + 1];
  s.z += rb[col + 2] + ib[col + 2];
  s.w += rb[col + 3] + ib[col + 3];
  *(float4*)&out[i4] = s;
}

extern "C" void kernel_launch(void* const* d_in, const int* in_sizes, int n_in,
                              void* d_out, int out_size, void* d_ws, size_t ws_size,
                              hipStream_t stream) {
  const int*   x    = (const int*)d_in[0];
  const float* te   = (const float*)d_in[1];
  const float* pp   = (const float*)d_in[2];
  const float* qr   = (const float*)d_in[3];
  const float* kr   = (const float*)d_in[4];
  const float* vr   = (const float*)d_in[5];
  const float* ffr  = (const float*)d_in[6];
  const float* ffi  = (const float*)d_in[7];
  const float* rorw = (const float*)d_in[8];
  const float* rorb = (const float*)d_in[9];
  const float* roiw = (const float*)d_in[10];
  const float* roib = (const float*)d_in[11];
  float* out = (float*)d_out;

  char* W = (char*)d_ws;
  const size_t MiB = 1 << 20;
  // [0,16) sr -> pr0 | [16,32) si -> pi0
  // [32,48) Af -> Zhl
  // [48,64) Kd -> Bt[48,56) + Wt[56,57)   (after attn)
  // [64,80) Vd -> pr1 ┐
  // [80,96) pi1       ┴-> ro_part [64,96)  (after norm)
  // [96,+24K) tabs
  float* sr  = (float*)W;
  float* si  = (float*)(W + 16 * MiB);
  unsigned short* Af = (unsigned short*)(W + 32 * MiB);
  unsigned short* Kd = (unsigned short*)(W + 48 * MiB);
  unsigned short* Vd = (unsigned short*)(W + 64 * MiB);
  unsigned short* Bt = (unsigned short*)(W + 48 * MiB);
  unsigned short* Wt = (unsigned short*)(W + 56 * MiB);
  float* tabs = (float*)(W + 96 * MiB);
  float* pr0 = sr;
  float* pi0 = si;
  float* pr1 = (float*)(W + 64 * MiB);
  float* pi1 = (float*)(W + 80 * MiB);
  unsigned short* Zhl = Af;
  float* ro_part = (float*)(W + 64 * MiB);   // 8 x 4 MiB

  rot_kernel<<<12, 256, 0, stream>>>(qr, kr, vr, tabs);
  embed_qkv_kernel<<<dim3(32, 64), 256, 0, stream>>>(x, te, pp, tabs, sr, si, Kd, Vd);
  attn_mfma_kernel<<<1024, 256, 0, stream>>>(sr, si, Kd, Vd, tabs, Af);
  split_b_kernel<<<dim3(64, 64), 256, 0, stream>>>(ffr, ffi, Bt);
  split_w_kernel<<<512, 256, 0, stream>>>(rorw, roiw, Wt);
  gemm_ff<<<dim3(32, 16, 2), 256, 0, stream>>>(Af, Bt, pr0, pi0, pr1, pi1);
  norm_split_kernel<<<B_ * S_, 256, 0, stream>>>(pr0, pi0, pr1, pi1, Zhl);
  gemm_ro<<<dim3(32, 2, 8), 256, 0, stream>>>(Zhl, Wt, ro_part);
  reduce_bias_kernel<<<1024, 256, 0, stream>>>(ro_part, rorb, roib, out);
}

// Round 16
// 148.540 us; speedup vs baseline: 1.4314x; 1.0504x over previous
//
#include <hip/hip_runtime.h>
#include <math.h>

// PhaseMultiHeadDecoder: B=4, S=1024, E=1024, H=16, hd=64, V=256
// Full fp16 pipeline. embed: fast v_sin/v_cos + exp-tanh, fp16 state.
// attn: balanced pairing, gload_lds dbuf, fused 32-key softmax, defer-max,
// setprio, pkrtz P-pack. FF/RO fp16 GEMM (K=2048) K-split + XCD swizzle.
#define B_ 4
#define S_ 1024
#define E_ 1024
#define H_ 16
#define V_ 256

typedef _Float16 h8 __attribute__((ext_vector_type(8)));
typedef _Float16 h4 __attribute__((ext_vector_type(4)));
typedef __fp16 f16x2 __attribute__((ext_vector_type(2)));   // cvt_pkrtz result type
typedef float f4x __attribute__((ext_vector_type(4)));

__device__ __forceinline__ void gload16(const void* g, void* l) {
  __builtin_amdgcn_global_load_lds((const __attribute__((address_space(1))) void*)g,
                                   (__attribute__((address_space(3))) void*)l, 16, 0, 0);
}

#define MFMA32F16(a, b, c) __builtin_amdgcn_mfma_f32_16x16x32_f16(a, b, c, 0, 0, 0)

#if defined(__has_builtin)
#if __has_builtin(__builtin_amdgcn_mfma_f32_16x16x16f16)
#define MFMA16F16(a, b, c) __builtin_amdgcn_mfma_f32_16x16x16f16(a, b, c, 0, 0, 0)
#endif
#endif
#ifndef MFMA16F16
__device__ __forceinline__ f4x mfma16f16_asm(h4 a, h4 b, f4x c) {
  asm volatile("v_mfma_f32_16x16x16_f16 %0, %1, %2, %0" : "+v"(c) : "v"(a), "v"(b));
  return c;
}
#define MFMA16F16(a, b, c) mfma16f16_asm(a, b, c)
#endif

// fast sincos: rev = fract(x/2pi); v_sin/v_cos take revolutions (ISA 3)
__device__ __forceinline__ void fast_sincos(float x, float* s, float* c) {
  float rev = x * 0.15915494309189535f;
  rev = rev - floorf(rev);
  float sv, cv;
  asm("v_sin_f32 %0, %1" : "=v"(sv) : "v"(rev));
  asm("v_cos_f32 %0, %1" : "=v"(cv) : "v"(rev));
  *s = sv; *c = cv;
}
__device__ __forceinline__ float fast_tanh(float x) {
  return 1.0f - 2.0f / (__expf(2.0f * x) + 1.0f);
}

// ---------------- rotation cos/sin tables: tabs[3][2][1024] ----------------
__global__ void rot_kernel(const float* __restrict__ qr, const float* __restrict__ kr,
                           const float* __restrict__ vr, float* __restrict__ tabs) {
  int i = blockIdx.x * blockDim.x + threadIdx.x;
  if (i >= 3 * 1024) return;
  int which = i >> 10;
  int j = i & 1023;
  const float* src = which == 0 ? qr : (which == 1 ? kr : vr);
  float s, c;
  sincosf(src[j], &s, &c);   // small args, exact path
  tabs[which * 2048 + j] = c;
  tabs[which * 2048 + 1024 + j] = s;
}

// ---------------- fused embed + K'/V' prep (fp16 state) ----------------
__global__ __launch_bounds__(256) void embed_qkv_kernel(
    const int* __restrict__ x, const float* __restrict__ te,
    const float* __restrict__ pp, const float* __restrict__ tabs,
    unsigned short* __restrict__ srh, unsigned short* __restrict__ sih,
    unsigned short* __restrict__ Kd, unsigned short* __restrict__ Vd) {
  __shared__ unsigned short Kl2[4096];
  __shared__ unsigned short Vl2[4096];
  const int kt2 = blockIdx.x;          // 32-row group, 0..31
  const int bh = blockIdx.y;           // 0..63
  const int b = bh >> 4, h = bh & 15;
  const int tid = threadIdx.x;
  const float* qc = tabs + h * 64;
  const float* qs = tabs + 1024 + h * 64;
  const float* kc = tabs + 2048 + h * 64;
  const float* ks = tabs + 3072 + h * 64;
  #pragma unroll
  for (int p = 0; p < 8; ++p) {
    int id = p * 256 + tid;            // 2048 items = 32 rows x 64 dims
    int sl = id >> 6;
    int dd = id & 63;
    int s = kt2 * 32 + sl;
    int e = h * 64 + dd;
    int tok = x[b * 1024 + s];
    float mm = fast_tanh(te[tok * 1024 + e]);
    float sn, cs;
    fast_sincos(pp[s * 1024 + e], &sn, &cs);
    float re = mm * cs, im = mm * sn;
    size_t g = ((size_t)(b * 1024 + s)) * 1024 + e;
    *(_Float16*)&srh[g] = (_Float16)re;
    *(_Float16*)&sih[g] = (_Float16)im;
    float cq = qc[dd], sq = qs[dd], ck = kc[dd], sk = ks[dd];
    float cd = cq * ck + sq * sk;      // cos(thq - thk)
    float sd = sq * ck - cq * sk;      // sin(thq - thk)
    float kr = re * cd + im * sd;      // k-state rotated by -delta
    float ki = im * cd - re * sd;
    int t = sl >> 4, key = sl & 15;
    int c0 = dd, c1 = 64 + dd;
    #define KOFF(c) (t * 2048 + ((((c) >> 5) * 4 + (((c) >> 3) & 3)) * 16 + key) * 8 + ((c) & 7))
    *(_Float16*)&Kl2[KOFF(c0)] = (_Float16)kr;
    *(_Float16*)&Kl2[KOFF(c1)] = (_Float16)ki;
    #undef KOFF
    int kgk = key >> 2, jk = key & 3;
    #define VOFF(d) (t * 2048 + ((((d) >> 4) * 4 + kgk) * 16 + ((d) & 15)) * 4 + jk)
    *(_Float16*)&Vl2[VOFF(dd)] = (_Float16)re;
    *(_Float16*)&Vl2[VOFF(64 + dd)] = (_Float16)im;
    #undef VOFF
  }
  __syncthreads();
  unsigned short* kdst = Kd + ((size_t)(bh * 64 + kt2 * 2)) * 2048;
  unsigned short* vdst = Vd + ((size_t)(bh * 64 + kt2 * 2)) * 2048;
  #pragma unroll
  for (int p = 0; p < 2; ++p) {
    int c = p * 256 + tid;
    ((int4*)kdst)[c] = ((const int4*)Kl2)[c];
    ((int4*)vdst)[c] = ((const int4*)Vl2)[c];
  }
}

// ---------------- fp16 MFMA flash attention, balanced pairing ----------------
// grid 1024: flat -> low=flat&7 (XCD=bh&7), a=(flat>>3)>>3 in 0..15,
// bh=((flat>>3)&7)<<3|low. Waves 0-1: rows 32a..; waves 2-3: rows 32(31-a)..
__global__ __launch_bounds__(256, 4) void attn_mfma_kernel(
    const unsigned short* __restrict__ srh, const unsigned short* __restrict__ sih,
    const unsigned short* __restrict__ Kd, const unsigned short* __restrict__ Vd,
    const float* __restrict__ tabs,
    unsigned short* __restrict__ Af) {
  __shared__ __align__(16) unsigned short Klds[2][4096];
  __shared__ __align__(16) unsigned short Vlds[2][4096];
  const int flat = blockIdx.x;
  const int low = flat & 7, rest = flat >> 3;
  const int a = rest >> 3;             // 0..15 (pair index)
  const int bh = ((rest & 7) << 3) | low;
  const int b = bh >> 4, h = bh & 15;
  const int tid = threadIdx.x, lane = tid & 63, wid = tid >> 6;
  const int cl = lane & 15, kg = lane >> 4;
  const int atile = (wid >> 1) ? (31 - a) : a;      // 32-row half-tile
  const int qw0 = atile * 32 + (wid & 1) * 16;      // this wave's 16 q-rows

  // Q^T b-frag: direct fp16 16B loads (state pre-formatted)
  h8 qf[4];
  {
    int q = qw0 + cl;
    const unsigned short* srow = srh + ((size_t)(b * 1024 + q)) * 1024 + h * 64;
    const unsigned short* irow = sih + ((size_t)(b * 1024 + q)) * 1024 + h * 64;
    #pragma unroll
    for (int ksx = 0; ksx < 4; ++ksx) {
      int f0 = ksx * 32 + kg * 8;
      qf[ksx] = (f0 < 64) ? *(const h8*)(srow + f0) : *(const h8*)(irow + (f0 - 64));
    }
  }

  f4x acc[8] = {};                     // out^T: [mt], d = mt*16+kg*4+r (mt<4 re, >=4 im)
  float m_ = -1e30f, l_ = 0.f;
  const int np = 32 - a;               // staged 32-key pairs (covers high tile)
  const int wqmax = qw0 + 15;
  const int qcol = qw0 + cl;

  const unsigned short* kstream = Kd + ((size_t)(bh * 64)) * 2048;
  const unsigned short* vstream = Vd + ((size_t)(bh * 64)) * 2048;

  #define STAGE_PAIR(buf, P)                                                    \
    {                                                                           \
      const unsigned short* kb = kstream + (size_t)(P) * 4096;                  \
      const unsigned short* vb = vstream + (size_t)(P) * 4096;                  \
      _Pragma("unroll")                                                         \
      for (int r = 0; r < 2; ++r) {                                             \
        int off = r * 256 + wid * 64;                                           \
        gload16(kb + (size_t)(off + lane) * 8, &Klds[buf][off * 8]);            \
        gload16(vb + (size_t)(off + lane) * 8, &Vlds[buf][off * 8]);            \
      }                                                                         \
    }

  STAGE_PAIR(0, 0)
  __syncthreads();                     // pair 0 landed

  for (int p = 0; p < np; ++p) {
    const int cur = p & 1;
    if (p + 1 < np) STAGE_PAIR(cur ^ 1, p + 1)   // async: in flight during compute
    const int k0a = p * 32;
    if (k0a <= wqmax) {                // wave-uniform causal skip
      __builtin_amdgcn_s_setprio(1);
      f4x sca = {}, scb = {};
      #pragma unroll
      for (int ksx = 0; ksx < 4; ++ksx) {
        h8 ka = *(const h8*)&Klds[cur][ksx * 512 + lane * 8];
        sca = MFMA32F16(ka, qf[ksx], sca);
      }
      #pragma unroll
      for (int ksx = 0; ksx < 4; ++ksx) {
        h8 kb = *(const h8*)&Klds[cur][2048 + ksx * 512 + lane * 8];
        scb = MFMA32F16(kb, qf[ksx], scb);
      }
      __builtin_amdgcn_s_setprio(0);
      if (k0a + 31 > qw0) {            // causal mask (boundary pairs only)
        #pragma unroll
        for (int r = 0; r < 4; ++r) {
          if (k0a + kg * 4 + r > qcol)      sca[r] = -1e30f;
          if (k0a + 16 + kg * 4 + r > qcol) scb[r] = -1e30f;
        }
      }
      // fused 32-key online softmax with defer-max (THR=8)
      float mx = fmaxf(fmaxf(fmaxf(sca[0], sca[1]), fmaxf(sca[2], sca[3])),
                       fmaxf(fmaxf(scb[0], scb[1]), fmaxf(scb[2], scb[3])));
      mx = fmaxf(mx, __shfl_xor(mx, 16, 64));
      mx = fmaxf(mx, __shfl_xor(mx, 32, 64));
      if (!__all(mx <= m_ + 8.0f)) {
        float mn = fmaxf(m_, mx);
        float corr = __expf(m_ - mn);
        #pragma unroll
        for (int mt = 0; mt < 8; ++mt) acc[mt] *= corr;
        l_ *= corr;
        m_ = mn;
      }
      float pa0 = __expf(sca[0] - m_), pa1 = __expf(sca[1] - m_);
      float pa2 = __expf(sca[2] - m_), pa3 = __expf(sca[3] - m_);
      float pb0 = __expf(scb[0] - m_), pb1 = __expf(scb[1] - m_);
      float pb2 = __expf(scb[2] - m_), pb3 = __expf(scb[3] - m_);
      float s0 = ((pa0 + pa1) + (pa2 + pa3)) + ((pb0 + pb1) + (pb2 + pb3));
      s0 += __shfl_xor(s0, 16, 64);
      s0 += __shfl_xor(s0, 32, 64);
      l_ += s0;
      // pack P via cvt_pkrtz (1 op per 2 values); result type is __fp16x2
      f16x2 a01 = __builtin_amdgcn_cvt_pkrtz(pa0, pa1);
      f16x2 a23 = __builtin_amdgcn_cvt_pkrtz(pa2, pa3);
      f16x2 b01 = __builtin_amdgcn_cvt_pkrtz(pb0, pb1);
      f16x2 b23 = __builtin_amdgcn_cvt_pkrtz(pb2, pb3);
      h4 pba, pbb;
      pba[0] = (_Float16)a01[0]; pba[1] = (_Float16)a01[1];
      pba[2] = (_Float16)a23[0]; pba[3] = (_Float16)a23[1];
      pbb[0] = (_Float16)b01[0]; pbb[1] = (_Float16)b01[1];
      pbb[2] = (_Float16)b23[0]; pbb[3] = (_Float16)b23[1];
      __builtin_amdgcn_s_setprio(1);
      #pragma unroll
      for (int mt = 0; mt < 8; ++mt) {
        h4 va = *(const h4*)&Vlds[cur][mt * 256 + lane * 4];
        acc[mt] = MFMA16F16(va, pba, acc[mt]);
      }
      #pragma unroll
      for (int mt = 0; mt < 8; ++mt) {
        h4 vb = *(const h4*)&Vlds[cur][2048 + mt * 256 + lane * 4];
        acc[mt] = MFMA16F16(vb, pbb, acc[mt]);
      }
      __builtin_amdgcn_s_setprio(0);
    }
    __syncthreads();   // staged pair landed + readers done
  }
  #undef STAGE_PAIR
  // epilogue: /l, rotate by exp(i*thv), add fp16 state -> Af[4096][re1024|im1024]
  {
    float linv = 1.0f / l_;
    int q = qw0 + cl;
    size_t mrow = (size_t)(b * 1024 + q);
    size_t obase = mrow * 1024 + h * 64;
    size_t abase = mrow * 2048 + h * 64;
    #pragma unroll
    for (int mt = 0; mt < 4; ++mt) {
      int d0 = mt * 16 + kg * 4;
      h4 s_r = *(const h4*)&srh[obase + d0];
      h4 s_i = *(const h4*)&sih[obase + d0];
      h4 hr, hi;
      #pragma unroll
      for (int r = 0; r < 4; ++r) {
        int d = d0 + r;
        float orv = acc[mt][r] * linv;
        float oiv = acc[mt + 4][r] * linv;
        float c = tabs[4096 + h * 64 + d], s = tabs[5120 + h * 64 + d];
        hr[r] = (_Float16)(orv * c - oiv * s + (float)s_r[r]);
        hi[r] = (_Float16)(orv * s + oiv * c + (float)s_i[r]);
      }
      *(h4*)&Af[abase + d0]        = hr;   // real
      *(h4*)&Af[abase + 1024 + d0] = hi;   // imag
    }
  }
}

// ---------------- transpose FF weight -> fp16: Bt[2048][2048] ----------------
__global__ void split_b_kernel(const float* __restrict__ fr, const float* __restrict__ fi,
                               unsigned short* __restrict__ Bt) {
  __shared__ float tile[32][33];
  const int k0 = blockIdx.x * 32, n0 = blockIdx.y * 32;
  const int tid = threadIdx.x;
  #pragma unroll
  for (int p = 0; p < 4; ++p) {
    int e = p * 256 + tid;
    int kk = e >> 5, nn = e & 31;
    int k = k0 + kk, n = n0 + nn;
    float v;
    if (n < 1024) v = (k < 1024) ? fr[(size_t)k * 1024 + n] : -fi[(size_t)(k - 1024) * 1024 + n];
    else          v = (k < 1024) ? fi[(size_t)k * 1024 + (n - 1024)]
                                 : fr[(size_t)(k - 1024) * 1024 + (n - 1024)];
    tile[kk][nn] = v;
  }
  __syncthreads();
  #pragma unroll
  for (int p = 0; p < 4; ++p) {
    int e = p * 256 + tid;
    int nn = e >> 5, kk = e & 31;
    *(_Float16*)&Bt[(size_t)(n0 + nn) * 2048 + (k0 + kk)] = (_Float16)tile[kk][nn];
  }
}

// ---------------- readout weight fp16: Wt[256][wr1024|wi1024] ----------------
__global__ void split_w_kernel(const float* __restrict__ wr, const float* __restrict__ wi,
                               unsigned short* __restrict__ Wt) {
  int idx = blockIdx.x * 256 + threadIdx.x;        // 256*512
  int v = idx >> 9;
  int k4 = (idx & 511) * 4;
  float4 a = (k4 < 1024) ? *(const float4*)&wr[(size_t)v * 1024 + k4]
                         : *(const float4*)&wi[(size_t)v * 1024 + k4 - 1024];
  h4 h;
  h[0] = (_Float16)a.x; h[1] = (_Float16)a.y;
  h[2] = (_Float16)a.z; h[3] = (_Float16)a.w;
  *(h4*)&Wt[(size_t)v * 2048 + k4] = h;
}

// ---------------- FF GEMM: fp16, 128x128 tile, K-split x2, XCD-colocated -----
__global__ __launch_bounds__(256, 4) void gemm_ff(
    const unsigned short* __restrict__ A,   // [4096][2048] fp16 bits
    const unsigned short* __restrict__ Bt,  // [2048][2048]
    float* __restrict__ pr0, float* __restrict__ pi0,
    float* __restrict__ pr1, float* __restrict__ pi1) {
  __shared__ short As[128 * 64];
  __shared__ short Bs[128 * 64];
  const int tid = threadIdx.x;
  const int lane = tid & 63, wid = tid >> 6;
  // XCD swizzle: linear id l (z adds 512 = 0 mod 8); colocate 4 m-bands/XCD
  const int l = blockIdx.x + (blockIdx.y << 5);
  const int xcd = l & 7, j = l >> 3;
  const int m0 = ((xcd << 2) + (j & 3)) << 7;      // 32 m-tiles
  const int n0 = (j >> 2) << 7;                    // 16 n-tiles
  const int z = blockIdx.z;
  const int wr = wid >> 1, wc = wid & 1;
  const int cl = lane & 15, rg = lane >> 4;

  f4x acc[4][4] = {};
  const int cbase = wid * 256;

  for (int kt = z * 16; kt < z * 16 + 16; ++kt) {
    const int k0 = kt * 64;
    #pragma unroll
    for (int it = 0; it < 4; ++it) {
      int c = cbase + it * 64 + lane;
      gload16(A + (size_t)(m0 + (c >> 3)) * 2048 + k0 + (c & 7) * 8,
              As + (cbase + it * 64) * 8);
      gload16(Bt + (size_t)(n0 + (c >> 3)) * 2048 + k0 + (c & 7) * 8,
              Bs + (cbase + it * 64) * 8);
    }
    __syncthreads();
    #pragma unroll
    for (int ks = 0; ks < 2; ++ks) {
      h8 a[4], b[4];
      #pragma unroll
      for (int ms = 0; ms < 4; ++ms)
        a[ms] = *(const h8*)&As[(wr * 64 + ms * 16 + cl) * 64 + ks * 32 + rg * 8];
      #pragma unroll
      for (int ns = 0; ns < 4; ++ns)
        b[ns] = *(const h8*)&Bs[(wc * 64 + ns * 16 + cl) * 64 + ks * 32 + rg * 8];
      #pragma unroll
      for (int ms = 0; ms < 4; ++ms)
        #pragma unroll
        for (int ns = 0; ns < 4; ++ns)
          acc[ms][ns] = MFMA32F16(a[ms], b[ns], acc[ms][ns]);
    }
    __syncthreads();
  }

  const int colbase = n0 + wc * 64;
  float* o_r = z ? pr1 : pr0;
  float* o_i = z ? pi1 : pi0;
  float* dst = (colbase < 1024) ? o_r : o_i;
  const int cb = colbase & 1023;
  #pragma unroll
  for (int ms = 0; ms < 4; ++ms)
    #pragma unroll
    for (int r2 = 0; r2 < 4; ++r2) {
      const int grow = m0 + wr * 64 + ms * 16 + rg * 4 + r2;
      #pragma unroll
      for (int ns = 0; ns < 4; ++ns)
        dst[(size_t)grow * 1024 + cb + ns * 16 + cl] = acc[ms][ns][r2];
    }
}

// ---------------- RO GEMM: fp16, 128x128 tile, K-split x8, XCD-colocated -----
__global__ __launch_bounds__(256, 4) void gemm_ro(
    const unsigned short* __restrict__ Z,   // [4096][2048] fp16 bits
    const unsigned short* __restrict__ Wt,  // [256][2048]
    float* __restrict__ part) {             // [8][4096][256]
  __shared__ short As[128 * 64];
  __shared__ short Bs[128 * 64];
  const int tid = threadIdx.x;
  const int lane = tid & 63, wid = tid >> 6;
  const int l = blockIdx.x + (blockIdx.y << 5);   // 0..63 (z adds 64 = 0 mod 8)
  const int xcd = l & 7, j = l >> 3;
  const int m0 = ((xcd << 2) + (j & 3)) << 7;     // 32 m-tiles
  const int n0 = (j >> 2) << 7;                   // 2 n-tiles
  const int z = blockIdx.z;
  const int wr = wid >> 1, wc = wid & 1;
  const int cl = lane & 15, rg = lane >> 4;

  f4x acc[4][4] = {};
  const int cbase = wid * 256;

  for (int kt = z * 4; kt < z * 4 + 4; ++kt) {
    const int k0 = kt * 64;
    #pragma unroll
    for (int it = 0; it < 4; ++it) {
      int c = cbase + it * 64 + lane;
      gload16(Z + (size_t)(m0 + (c >> 3)) * 2048 + k0 + (c & 7) * 8,
              As + (cbase + it * 64) * 8);
      gload16(Wt + (size_t)(n0 + (c >> 3)) * 2048 + k0 + (c & 7) * 8,
              Bs + (cbase + it * 64) * 8);
    }
    __syncthreads();
    #pragma unroll
    for (int ks = 0; ks < 2; ++ks) {
      h8 a[4], b[4];
      #pragma unroll
      for (int ms = 0; ms < 4; ++ms)
        a[ms] = *(const h8*)&As[(wr * 64 + ms * 16 + cl) * 64 + ks * 32 + rg * 8];
      #pragma unroll
      for (int ns = 0; ns < 4; ++ns)
        b[ns] = *(const h8*)&Bs[(wc * 64 + ns * 16 + cl) * 64 + ks * 32 + rg * 8];
      #pragma unroll
      for (int ms = 0; ms < 4; ++ms)
        #pragma unroll
        for (int ns = 0; ns < 4; ++ns)
          acc[ms][ns] = MFMA32F16(a[ms], b[ns], acc[ms][ns]);
    }
    __syncthreads();
  }

  float* dst = part + (size_t)z * 4096 * 256;
  const int colbase = n0 + wc * 64;
  #pragma unroll
  for (int ms = 0; ms < 4; ++ms)
    #pragma unroll
    for (int r2 = 0; r2 < 4; ++r2) {
      const int grow = m0 + wr * 64 + ms * 16 + rg * 4 + r2;
      #pragma unroll
      for (int ns = 0; ns < 4; ++ns)
        dst[(size_t)grow * 256 + colbase + ns * 16 + cl] = acc[ms][ns][r2];
    }
}

// ---------------- complex_norm over FF partial sums -> fp16 Z ----------------
__global__ __launch_bounds__(256) void norm_split_kernel(
    const float* __restrict__ pr0, const float* __restrict__ pi0,
    const float* __restrict__ pr1, const float* __restrict__ pi1,
    unsigned short* __restrict__ Z) {
  const int row = blockIdx.x, tid = threadIdx.x;
  const int base = row * E_ + tid * 4;
  float4 r0 = *(const float4*)&pr0[base];
  float4 r1 = *(const float4*)&pr1[base];
  float4 i0 = *(const float4*)&pi0[base];
  float4 i1 = *(const float4*)&pi1[base];
  float4 zr = make_float4(r0.x + r1.x, r0.y + r1.y, r0.z + r1.z, r0.w + r1.w);
  float4 zi = make_float4(i0.x + i1.x, i0.y + i1.y, i0.z + i1.z, i0.w + i1.w);
  float mg[4];
  mg[0] = sqrtf(zr.x * zr.x + zi.x * zi.x);
  mg[1] = sqrtf(zr.y * zr.y + zi.y * zi.y);
  mg[2] = sqrtf(zr.z * zr.z + zi.z * zi.z);
  mg[3] = sqrtf(zr.w * zr.w + zi.w * zi.w);
  float s1 = mg[0] + mg[1] + mg[2] + mg[3];
  float s2 = mg[0]*mg[0] + mg[1]*mg[1] + mg[2]*mg[2] + mg[3]*mg[3];
  #pragma unroll
  for (int off = 1; off < 64; off <<= 1) {
    s1 += __shfl_xor(s1, off, 64);
    s2 += __shfl_xor(s2, off, 64);
  }
  __shared__ float ws1[4], ws2[4];
  if ((tid & 63) == 0) { ws1[tid >> 6] = s1; ws2[tid >> 6] = s2; }
  __syncthreads();
  s1 = ws1[0] + ws1[1] + ws1[2] + ws1[3];
  s2 = ws2[0] + ws2[1] + ws2[2] + ws2[3];
  float mean = s1 * (1.0f / 1024.0f);
  float var = (s2 - 1024.0f * mean * mean) * (1.0f / 1023.0f);  // ddof=1
  var = fmaxf(var, 0.0f);
  float inv_sd = 1.0f / (sqrtf(var) + 1e-5f);
  float sc[4];
  #pragma unroll
  for (int t = 0; t < 4; ++t)
    sc[t] = tanhf((mg[t] - mean) * inv_sd) / (mg[t] + 1e-5f);
  h4 hr, hi;
  hr[0] = (_Float16)(zr.x * sc[0]); hr[1] = (_Float16)(zr.y * sc[1]);
  hr[2] = (_Float16)(zr.z * sc[2]); hr[3] = (_Float16)(zr.w * sc[3]);
  hi[0] = (_Float16)(zi.x * sc[0]); hi[1] = (_Float16)(zi.y * sc[1]);
  hi[2] = (_Float16)(zi.z * sc[2]); hi[3] = (_Float16)(zi.w * sc[3]);
  const size_t zb = (size_t)row * 2048 + tid * 4;
  *(h4*)&Z[zb]        = hr;
  *(h4*)&Z[zb + 1024] = hi;
}

// ---------------- reduce RO partials + biases -> out ----------------
__global__ void reduce_bias_kernel(const float* __restrict__ part,
                                   const float* __restrict__ rb,
                                   const float* __restrict__ ib,
                                   float* __restrict__ out) {
  int i4 = (blockIdx.x * 256 + threadIdx.x) * 4;   // < 4096*256
  int col = i4 & 255;
  float4 s = *(const float4*)&part[i4];
  #pragma unroll
  for (int z = 1; z < 8; ++z) {
    float4 v = *(const float4*)&part[(size_t)z * 1048576 + i4];
    s.x += v.x; s.y += v.y; s.z += v.z; s.w += v.w;
  }
  s.x += rb[col + 0] + ib[col + 0];
  s.y += rb[col + 1] + ib[col + 1];
  s.z += rb[col + 2] + ib[col + 2];
  s.w += rb[col + 3] + ib[col + 3];
  *(float4*)&out[i4] = s;
}

extern "C" void kernel_launch(void* const* d_in, const int* in_sizes, int n_in,
                              void* d_out, int out_size, void* d_ws, size_t ws_size,
                              hipStream_t stream) {
  const int*   x    = (const int*)d_in[0];
  const float* te   = (const float*)d_in[1];
  const float* pp   = (const float*)d_in[2];
  const float* qr   = (const float*)d_in[3];
  const float* kr   = (const float*)d_in[4];
  const float* vr   = (const float*)d_in[5];
  const float* ffr  = (const float*)d_in[6];
  const float* ffi  = (const float*)d_in[7];
  const float* rorw = (const float*)d_in[8];
  const float* rorb = (const float*)d_in[9];
  const float* roiw = (const float*)d_in[10];
  const float* roib = (const float*)d_in[11];
  float* out = (float*)d_out;

  char* W = (char*)d_ws;
  const size_t MiB = 1 << 20;
  // [0,16) srh(8MB used) -> pr0(f32 16MB) | [16,32) sih -> pi0
  // [32,48) Af -> Zhl
  // [48,64) Kd -> Bt[48,56) + Wt[56,57)   (after attn)
  // [64,80) Vd -> pr1 ┐
  // [80,96) pi1       ┴-> ro_part [64,96)  (after norm)
  // [96,+24K) tabs
  unsigned short* srh = (unsigned short*)W;
  unsigned short* sih = (unsigned short*)(W + 16 * MiB);
  unsigned short* Af = (unsigned short*)(W + 32 * MiB);
  unsigned short* Kd = (unsigned short*)(W + 48 * MiB);
  unsigned short* Vd = (unsigned short*)(W + 64 * MiB);
  unsigned short* Bt = (unsigned short*)(W + 48 * MiB);
  unsigned short* Wt = (unsigned short*)(W + 56 * MiB);
  float* tabs = (float*)(W + 96 * MiB);
  float* pr0 = (float*)W;
  float* pi0 = (float*)(W + 16 * MiB);
  float* pr1 = (float*)(W + 64 * MiB);
  float* pi1 = (float*)(W + 80 * MiB);
  unsigned short* Zhl = Af;
  float* ro_part = (float*)(W + 64 * MiB);   // 8 x 4 MiB

  rot_kernel<<<12, 256, 0, stream>>>(qr, kr, vr, tabs);
  embed_qkv_kernel<<<dim3(32, 64), 256, 0, stream>>>(x, te, pp, tabs, srh, sih, Kd, Vd);
  attn_mfma_kernel<<<1024, 256, 0, stream>>>(srh, sih, Kd, Vd, tabs, Af);
  split_b_kernel<<<dim3(64, 64), 256, 0, stream>>>(ffr, ffi, Bt);
  split_w_kernel<<<512, 256, 0, stream>>>(rorw, roiw, Wt);
  gemm_ff<<<dim3(32, 16, 2), 256, 0, stream>>>(Af, Bt, pr0, pi0, pr1, pi1);
  norm_split_kernel<<<B_ * S_, 256, 0, stream>>>(pr0, pi0, pr1, pi1, Zhl);
  gemm_ro<<<dim3(32, 2, 8), 256, 0, stream>>>(Zhl, Wt, ro_part);
  reduce_bias_kernel<<<1024, 256, 0, stream>>>(ro_part, rorb, roib, out);
}

// Round 17
// 146.035 us; speedup vs baseline: 1.4559x; 1.0172x over previous
//
#include <hip/hip_runtime.h>
#include <math.h>

// PhaseMultiHeadDecoder: B=4, S=1024, E=1024, H=16, hd=64, V=256
// Full fp16 pipeline. embed: fast v_sin/v_cos + exp-tanh, fp16 state.
// attn: balanced pairing, gload_lds dbuf, exp2-domain fused 32-key softmax
// (deferred l-reduce, max3 tree), defer-max, setprio, pkrtz P-pack.
// FF/RO fp16 GEMM (K=2048) K-split + XCD swizzle.
#define B_ 4
#define S_ 1024
#define E_ 1024
#define H_ 16
#define V_ 256

typedef _Float16 h8 __attribute__((ext_vector_type(8)));
typedef _Float16 h4 __attribute__((ext_vector_type(4)));
typedef __fp16 f16x2 __attribute__((ext_vector_type(2)));   // cvt_pkrtz result type
typedef int i2 __attribute__((ext_vector_type(2)));
typedef float f4x __attribute__((ext_vector_type(4)));

__device__ __forceinline__ void gload16(const void* g, void* l) {
  __builtin_amdgcn_global_load_lds((const __attribute__((address_space(1))) void*)g,
                                   (__attribute__((address_space(3))) void*)l, 16, 0, 0);
}

#define MFMA32F16(a, b, c) __builtin_amdgcn_mfma_f32_16x16x32_f16(a, b, c, 0, 0, 0)

#if defined(__has_builtin)
#if __has_builtin(__builtin_amdgcn_mfma_f32_16x16x16f16)
#define MFMA16F16(a, b, c) __builtin_amdgcn_mfma_f32_16x16x16f16(a, b, c, 0, 0, 0)
#endif
#endif
#ifndef MFMA16F16
__device__ __forceinline__ f4x mfma16f16_asm(h4 a, h4 b, f4x c) {
  asm volatile("v_mfma_f32_16x16x16_f16 %0, %1, %2, %0" : "+v"(c) : "v"(a), "v"(b));
  return c;
}
#define MFMA16F16(a, b, c) mfma16f16_asm(a, b, c)
#endif

// fast sincos: rev = fract(x/2pi); v_sin/v_cos take revolutions (ISA 3)
__device__ __forceinline__ void fast_sincos(float x, float* s, float* c) {
  float rev = x * 0.15915494309189535f;
  rev = rev - floorf(rev);
  float sv, cv;
  asm("v_sin_f32 %0, %1" : "=v"(sv) : "v"(rev));
  asm("v_cos_f32 %0, %1" : "=v"(cv) : "v"(rev));
  *s = sv; *c = cv;
}
__device__ __forceinline__ float fast_tanh(float x) {
  return 1.0f - 2.0f / (__expf(2.0f * x) + 1.0f);
}
// raw 2^x (v_exp_f32 IS exp2)
__device__ __forceinline__ float fast_exp2(float x) {
  float r;
  asm("v_exp_f32 %0, %1" : "=v"(r) : "v"(x));
  return r;
}

// ---------------- rotation cos/sin tables: tabs[3][2][1024] ----------------
__global__ void rot_kernel(const float* __restrict__ qr, const float* __restrict__ kr,
                           const float* __restrict__ vr, float* __restrict__ tabs) {
  int i = blockIdx.x * blockDim.x + threadIdx.x;
  if (i >= 3 * 1024) return;
  int which = i >> 10;
  int j = i & 1023;
  const float* src = which == 0 ? qr : (which == 1 ? kr : vr);
  float s, c;
  sincosf(src[j], &s, &c);   // small args, exact path
  tabs[which * 2048 + j] = c;
  tabs[which * 2048 + 1024 + j] = s;
}

// ---------------- fused embed + K'/V' prep (fp16 state) ----------------
__global__ __launch_bounds__(256) void embed_qkv_kernel(
    const int* __restrict__ x, const float* __restrict__ te,
    const float* __restrict__ pp, const float* __restrict__ tabs,
    unsigned short* __restrict__ srh, unsigned short* __restrict__ sih,
    unsigned short* __restrict__ Kd, unsigned short* __restrict__ Vd) {
  __shared__ unsigned short Kl2[4096];
  __shared__ unsigned short Vl2[4096];
  const int kt2 = blockIdx.x;          // 32-row group, 0..31
  const int bh = blockIdx.y;           // 0..63
  const int b = bh >> 4, h = bh & 15;
  const int tid = threadIdx.x;
  const float* qc = tabs + h * 64;
  const float* qs = tabs + 1024 + h * 64;
  const float* kc = tabs + 2048 + h * 64;
  const float* ks = tabs + 3072 + h * 64;
  #pragma unroll
  for (int p = 0; p < 8; ++p) {
    int id = p * 256 + tid;            // 2048 items = 32 rows x 64 dims
    int sl = id >> 6;
    int dd = id & 63;
    int s = kt2 * 32 + sl;
    int e = h * 64 + dd;
    int tok = x[b * 1024 + s];
    float mm = fast_tanh(te[tok * 1024 + e]);
    float sn, cs;
    fast_sincos(pp[s * 1024 + e], &sn, &cs);
    float re = mm * cs, im = mm * sn;
    size_t g = ((size_t)(b * 1024 + s)) * 1024 + e;
    *(_Float16*)&srh[g] = (_Float16)re;
    *(_Float16*)&sih[g] = (_Float16)im;
    float cq = qc[dd], sq = qs[dd], ck = kc[dd], sk = ks[dd];
    float cd = cq * ck + sq * sk;      // cos(thq - thk)
    float sd = sq * ck - cq * sk;      // sin(thq - thk)
    float kr = re * cd + im * sd;      // k-state rotated by -delta
    float ki = im * cd - re * sd;
    int t = sl >> 4, key = sl & 15;
    int c0 = dd, c1 = 64 + dd;
    #define KOFF(c) (t * 2048 + ((((c) >> 5) * 4 + (((c) >> 3) & 3)) * 16 + key) * 8 + ((c) & 7))
    *(_Float16*)&Kl2[KOFF(c0)] = (_Float16)kr;
    *(_Float16*)&Kl2[KOFF(c1)] = (_Float16)ki;
    #undef KOFF
    int kgk = key >> 2, jk = key & 3;
    #define VOFF(d) (t * 2048 + ((((d) >> 4) * 4 + kgk) * 16 + ((d) & 15)) * 4 + jk)
    *(_Float16*)&Vl2[VOFF(dd)] = (_Float16)re;
    *(_Float16*)&Vl2[VOFF(64 + dd)] = (_Float16)im;
    #undef VOFF
  }
  __syncthreads();
  unsigned short* kdst = Kd + ((size_t)(bh * 64 + kt2 * 2)) * 2048;
  unsigned short* vdst = Vd + ((size_t)(bh * 64 + kt2 * 2)) * 2048;
  #pragma unroll
  for (int p = 0; p < 2; ++p) {
    int c = p * 256 + tid;
    ((int4*)kdst)[c] = ((const int4*)Kl2)[c];
    ((int4*)vdst)[c] = ((const int4*)Vl2)[c];
  }
}

// ---------------- fp16 MFMA flash attention, balanced pairing ----------------
// grid 1024: flat -> low=flat&7 (XCD=bh&7), a=(flat>>3)>>3 in 0..15,
// bh=((flat>>3)&7)<<3|low. Waves 0-1: rows 32a..; waves 2-3: rows 32(31-a)..
// Softmax runs in exp2 domain (Q pre-scaled by log2 e); l_ is a per-lane
// partial reduced once in the epilogue.
__global__ __launch_bounds__(256, 4) void attn_mfma_kernel(
    const unsigned short* __restrict__ srh, const unsigned short* __restrict__ sih,
    const unsigned short* __restrict__ Kd, const unsigned short* __restrict__ Vd,
    const float* __restrict__ tabs,
    unsigned short* __restrict__ Af) {
  __shared__ __align__(16) unsigned short Klds[2][4096];
  __shared__ __align__(16) unsigned short Vlds[2][4096];
  const int flat = blockIdx.x;
  const int low = flat & 7, rest = flat >> 3;
  const int a = rest >> 3;             // 0..15 (pair index)
  const int bh = ((rest & 7) << 3) | low;
  const int b = bh >> 4, h = bh & 15;
  const int tid = threadIdx.x, lane = tid & 63, wid = tid >> 6;
  const int cl = lane & 15, kg = lane >> 4;
  const int atile = (wid >> 1) ? (31 - a) : a;      // 32-row half-tile
  const int qw0 = atile * 32 + (wid & 1) * 16;      // this wave's 16 q-rows

  // Q^T b-frag: direct fp16 16B loads, pre-scaled by log2(e)
  h8 qf[4];
  {
    int q = qw0 + cl;
    const unsigned short* srow = srh + ((size_t)(b * 1024 + q)) * 1024 + h * 64;
    const unsigned short* irow = sih + ((size_t)(b * 1024 + q)) * 1024 + h * 64;
    #pragma unroll
    for (int ksx = 0; ksx < 4; ++ksx) {
      int f0 = ksx * 32 + kg * 8;
      qf[ksx] = (f0 < 64) ? *(const h8*)(srow + f0) : *(const h8*)(irow + (f0 - 64));
      qf[ksx] *= (_Float16)1.4426950408889634f;
    }
  }

  f4x acc[8] = {};                     // out^T: [mt], d = mt*16+kg*4+r (mt<4 re, >=4 im)
  float m_ = -1e30f, l_ = 0.f;         // m_ in log2 units; l_ per-lane partial
  const int np = 32 - a;               // staged 32-key pairs (covers high tile)
  const int wqmax = qw0 + 15;
  const int qcol = qw0 + cl;

  const unsigned short* kstream = Kd + ((size_t)(bh * 64)) * 2048;
  const unsigned short* vstream = Vd + ((size_t)(bh * 64)) * 2048;

  #define STAGE_PAIR(buf, P)                                                    \
    {                                                                           \
      const unsigned short* kb = kstream + (size_t)(P) * 4096;                  \
      const unsigned short* vb = vstream + (size_t)(P) * 4096;                  \
      _Pragma("unroll")                                                         \
      for (int r = 0; r < 2; ++r) {                                             \
        int off = r * 256 + wid * 64;                                           \
        gload16(kb + (size_t)(off + lane) * 8, &Klds[buf][off * 8]);            \
        gload16(vb + (size_t)(off + lane) * 8, &Vlds[buf][off * 8]);            \
      }                                                                         \
    }

  STAGE_PAIR(0, 0)
  __syncthreads();                     // pair 0 landed

  for (int p = 0; p < np; ++p) {
    const int cur = p & 1;
    if (p + 1 < np) STAGE_PAIR(cur ^ 1, p + 1)   // async: in flight during compute
    const int k0a = p * 32;
    if (k0a <= wqmax) {                // wave-uniform causal skip
      __builtin_amdgcn_s_setprio(1);
      f4x sca = {}, scb = {};
      #pragma unroll
      for (int ksx = 0; ksx < 4; ++ksx) {
        h8 ka = *(const h8*)&Klds[cur][ksx * 512 + lane * 8];
        sca = MFMA32F16(ka, qf[ksx], sca);
      }
      #pragma unroll
      for (int ksx = 0; ksx < 4; ++ksx) {
        h8 kb = *(const h8*)&Klds[cur][2048 + ksx * 512 + lane * 8];
        scb = MFMA32F16(kb, qf[ksx], scb);
      }
      __builtin_amdgcn_s_setprio(0);
      if (k0a + 31 > qw0) {            // causal mask (boundary pairs only)
        #pragma unroll
        for (int r = 0; r < 4; ++r) {
          if (k0a + kg * 4 + r > qcol)      sca[r] = -1e30f;
          if (k0a + 16 + kg * 4 + r > qcol) scb[r] = -1e30f;
        }
      }
      // fused 32-key online softmax (exp2 domain), defer-max THR = 8 nats
      float mA = fmaxf(fmaxf(sca[0], sca[1]), sca[2]);          // v_max3
      float mB = fmaxf(fmaxf(sca[3], scb[0]), scb[1]);          // v_max3
      float mC = fmaxf(fmaxf(scb[2], scb[3]), mA);              // v_max3
      float mx = fmaxf(mB, mC);
      mx = fmaxf(mx, __shfl_xor(mx, 16, 64));
      mx = fmaxf(mx, __shfl_xor(mx, 32, 64));
      if (!__all(mx <= m_ + 11.5416f)) {
        float mn = fmaxf(m_, mx);
        float corr = fast_exp2(m_ - mn);
        #pragma unroll
        for (int mt = 0; mt < 8; ++mt) acc[mt] *= corr;
        l_ *= corr;
        m_ = mn;
      }
      float pa0 = fast_exp2(sca[0] - m_), pa1 = fast_exp2(sca[1] - m_);
      float pa2 = fast_exp2(sca[2] - m_), pa3 = fast_exp2(sca[3] - m_);
      float pb0 = fast_exp2(scb[0] - m_), pb1 = fast_exp2(scb[1] - m_);
      float pb2 = fast_exp2(scb[2] - m_), pb3 = fast_exp2(scb[3] - m_);
      l_ += ((pa0 + pa1) + (pa2 + pa3)) + ((pb0 + pb1) + (pb2 + pb3));
      // pack P via cvt_pkrtz, assemble h4 via bitcast (no element moves)
      f16x2 a01 = __builtin_amdgcn_cvt_pkrtz(pa0, pa1);
      f16x2 a23 = __builtin_amdgcn_cvt_pkrtz(pa2, pa3);
      f16x2 b01 = __builtin_amdgcn_cvt_pkrtz(pb0, pb1);
      f16x2 b23 = __builtin_amdgcn_cvt_pkrtz(pb2, pb3);
      i2 ta, tb;
      ta[0] = __builtin_bit_cast(int, a01); ta[1] = __builtin_bit_cast(int, a23);
      tb[0] = __builtin_bit_cast(int, b01); tb[1] = __builtin_bit_cast(int, b23);
      h4 pba = __builtin_bit_cast(h4, ta);
      h4 pbb = __builtin_bit_cast(h4, tb);
      __builtin_amdgcn_s_setprio(1);
      #pragma unroll
      for (int mt = 0; mt < 8; ++mt) {
        h4 va = *(const h4*)&Vlds[cur][mt * 256 + lane * 4];
        acc[mt] = MFMA16F16(va, pba, acc[mt]);
      }
      #pragma unroll
      for (int mt = 0; mt < 8; ++mt) {
        h4 vb = *(const h4*)&Vlds[cur][2048 + mt * 256 + lane * 4];
        acc[mt] = MFMA16F16(vb, pbb, acc[mt]);
      }
      __builtin_amdgcn_s_setprio(0);
    }
    __syncthreads();   // staged pair landed + readers done
  }
  #undef STAGE_PAIR
  // epilogue: reduce l_ across kg lanes, /l, rotate by exp(i*thv), add state
  {
    l_ += __shfl_xor(l_, 16, 64);
    l_ += __shfl_xor(l_, 32, 64);
    float linv = 1.0f / l_;
    int q = qw0 + cl;
    size_t mrow = (size_t)(b * 1024 + q);
    size_t obase = mrow * 1024 + h * 64;
    size_t abase = mrow * 2048 + h * 64;
    #pragma unroll
    for (int mt = 0; mt < 4; ++mt) {
      int d0 = mt * 16 + kg * 4;
      h4 s_r = *(const h4*)&srh[obase + d0];
      h4 s_i = *(const h4*)&sih[obase + d0];
      h4 hr, hi;
      #pragma unroll
      for (int r = 0; r < 4; ++r) {
        int d = d0 + r;
        float orv = acc[mt][r] * linv;
        float oiv = acc[mt + 4][r] * linv;
        float c = tabs[4096 + h * 64 + d], s = tabs[5120 + h * 64 + d];
        hr[r] = (_Float16)(orv * c - oiv * s + (float)s_r[r]);
        hi[r] = (_Float16)(orv * s + oiv * c + (float)s_i[r]);
      }
      *(h4*)&Af[abase + d0]        = hr;   // real
      *(h4*)&Af[abase + 1024 + d0] = hi;   // imag
    }
  }
}

// ---------------- transpose FF weight -> fp16: Bt[2048][2048] ----------------
__global__ void split_b_kernel(const float* __restrict__ fr, const float* __restrict__ fi,
                               unsigned short* __restrict__ Bt) {
  __shared__ float tile[32][33];
  const int k0 = blockIdx.x * 32, n0 = blockIdx.y * 32;
  const int tid = threadIdx.x;
  #pragma unroll
  for (int p = 0; p < 4; ++p) {
    int e = p * 256 + tid;
    int kk = e >> 5, nn = e & 31;
    int k = k0 + kk, n = n0 + nn;
    float v;
    if (n < 1024) v = (k < 1024) ? fr[(size_t)k * 1024 + n] : -fi[(size_t)(k - 1024) * 1024 + n];
    else          v = (k < 1024) ? fi[(size_t)k * 1024 + (n - 1024)]
                                 : fr[(size_t)(k - 1024) * 1024 + (n - 1024)];
    tile[kk][nn] = v;
  }
  __syncthreads();
  #pragma unroll
  for (int p = 0; p < 4; ++p) {
    int e = p * 256 + tid;
    int nn = e >> 5, kk = e & 31;
    *(_Float16*)&Bt[(size_t)(n0 + nn) * 2048 + (k0 + kk)] = (_Float16)tile[kk][nn];
  }
}

// ---------------- readout weight fp16: Wt[256][wr1024|wi1024] ----------------
__global__ void split_w_kernel(const float* __restrict__ wr, const float* __restrict__ wi,
                               unsigned short* __restrict__ Wt) {
  int idx = blockIdx.x * 256 + threadIdx.x;        // 256*512
  int v = idx >> 9;
  int k4 = (idx & 511) * 4;
  float4 a = (k4 < 1024) ? *(const float4*)&wr[(size_t)v * 1024 + k4]
                         : *(const float4*)&wi[(size_t)v * 1024 + k4 - 1024];
  h4 h;
  h[0] = (_Float16)a.x; h[1] = (_Float16)a.y;
  h[2] = (_Float16)a.z; h[3] = (_Float16)a.w;
  *(h4*)&Wt[(size_t)v * 2048 + k4] = h;
}

// ---------------- FF GEMM: fp16, 128x128 tile, K-split x2, XCD-colocated -----
__global__ __launch_bounds__(256, 4) void gemm_ff(
    const unsigned short* __restrict__ A,   // [4096][2048] fp16 bits
    const unsigned short* __restrict__ Bt,  // [2048][2048]
    float* __restrict__ pr0, float* __restrict__ pi0,
    float* __restrict__ pr1, float* __restrict__ pi1) {
  __shared__ short As[128 * 64];
  __shared__ short Bs[128 * 64];
  const int tid = threadIdx.x;
  const int lane = tid & 63, wid = tid >> 6;
  // XCD swizzle: linear id l (z adds 512 = 0 mod 8); colocate 4 m-bands/XCD
  const int l = blockIdx.x + (blockIdx.y << 5);
  const int xcd = l & 7, j = l >> 3;
  const int m0 = ((xcd << 2) + (j & 3)) << 7;      // 32 m-tiles
  const int n0 = (j >> 2) << 7;                    // 16 n-tiles
  const int z = blockIdx.z;
  const int wr = wid >> 1, wc = wid & 1;
  const int cl = lane & 15, rg = lane >> 4;

  f4x acc[4][4] = {};
  const int cbase = wid * 256;

  for (int kt = z * 16; kt < z * 16 + 16; ++kt) {
    const int k0 = kt * 64;
    #pragma unroll
    for (int it = 0; it < 4; ++it) {
      int c = cbase + it * 64 + lane;
      gload16(A + (size_t)(m0 + (c >> 3)) * 2048 + k0 + (c & 7) * 8,
              As + (cbase + it * 64) * 8);
      gload16(Bt + (size_t)(n0 + (c >> 3)) * 2048 + k0 + (c & 7) * 8,
              Bs + (cbase + it * 64) * 8);
    }
    __syncthreads();
    #pragma unroll
    for (int ks = 0; ks < 2; ++ks) {
      h8 a[4], b[4];
      #pragma unroll
      for (int ms = 0; ms < 4; ++ms)
        a[ms] = *(const h8*)&As[(wr * 64 + ms * 16 + cl) * 64 + ks * 32 + rg * 8];
      #pragma unroll
      for (int ns = 0; ns < 4; ++ns)
        b[ns] = *(const h8*)&Bs[(wc * 64 + ns * 16 + cl) * 64 + ks * 32 + rg * 8];
      #pragma unroll
      for (int ms = 0; ms < 4; ++ms)
        #pragma unroll
        for (int ns = 0; ns < 4; ++ns)
          acc[ms][ns] = MFMA32F16(a[ms], b[ns], acc[ms][ns]);
    }
    __syncthreads();
  }

  const int colbase = n0 + wc * 64;
  float* o_r = z ? pr1 : pr0;
  float* o_i = z ? pi1 : pi0;
  float* dst = (colbase < 1024) ? o_r : o_i;
  const int cb = colbase & 1023;
  #pragma unroll
  for (int ms = 0; ms < 4; ++ms)
    #pragma unroll
    for (int r2 = 0; r2 < 4; ++r2) {
      const int grow = m0 + wr * 64 + ms * 16 + rg * 4 + r2;
      #pragma unroll
      for (int ns = 0; ns < 4; ++ns)
        dst[(size_t)grow * 1024 + cb + ns * 16 + cl] = acc[ms][ns][r2];
    }
}

// ---------------- RO GEMM: fp16, 128x128 tile, K-split x8, XCD-colocated -----
__global__ __launch_bounds__(256, 4) void gemm_ro(
    const unsigned short* __restrict__ Z,   // [4096][2048] fp16 bits
    const unsigned short* __restrict__ Wt,  // [256][2048]
    float* __restrict__ part) {             // [8][4096][256]
  __shared__ short As[128 * 64];
  __shared__ short Bs[128 * 64];
  const int tid = threadIdx.x;
  const int lane = tid & 63, wid = tid >> 6;
  const int l = blockIdx.x + (blockIdx.y << 5);   // 0..63 (z adds 64 = 0 mod 8)
  const int xcd = l & 7, j = l >> 3;
  const int m0 = ((xcd << 2) + (j & 3)) << 7;     // 32 m-tiles
  const int n0 = (j >> 2) << 7;                   // 2 n-tiles
  const int z = blockIdx.z;
  const int wr = wid >> 1, wc = wid & 1;
  const int cl = lane & 15, rg = lane >> 4;

  f4x acc[4][4] = {};
  const int cbase = wid * 256;

  for (int kt = z * 4; kt < z * 4 + 4; ++kt) {
    const int k0 = kt * 64;
    #pragma unroll
    for (int it = 0; it < 4; ++it) {
      int c = cbase + it * 64 + lane;
      gload16(Z + (size_t)(m0 + (c >> 3)) * 2048 + k0 + (c & 7) * 8,
              As + (cbase + it * 64) * 8);
      gload16(Wt + (size_t)(n0 + (c >> 3)) * 2048 + k0 + (c & 7) * 8,
              Bs + (cbase + it * 64) * 8);
    }
    __syncthreads();
    #pragma unroll
    for (int ks = 0; ks < 2; ++ks) {
      h8 a[4], b[4];
      #pragma unroll
      for (int ms = 0; ms < 4; ++ms)
        a[ms] = *(const h8*)&As[(wr * 64 + ms * 16 + cl) * 64 + ks * 32 + rg * 8];
      #pragma unroll
      for (int ns = 0; ns < 4; ++ns)
        b[ns] = *(const h8*)&Bs[(wc * 64 + ns * 16 + cl) * 64 + ks * 32 + rg * 8];
      #pragma unroll
      for (int ms = 0; ms < 4; ++ms)
        #pragma unroll
        for (int ns = 0; ns < 4; ++ns)
          acc[ms][ns] = MFMA32F16(a[ms], b[ns], acc[ms][ns]);
    }
    __syncthreads();
  }

  float* dst = part + (size_t)z * 4096 * 256;
  const int colbase = n0 + wc * 64;
  #pragma unroll
  for (int ms = 0; ms < 4; ++ms)
    #pragma unroll
    for (int r2 = 0; r2 < 4; ++r2) {
      const int grow = m0 + wr * 64 + ms * 16 + rg * 4 + r2;
      #pragma unroll
      for (int ns = 0; ns < 4; ++ns)
        dst[(size_t)grow * 256 + colbase + ns * 16 + cl] = acc[ms][ns][r2];
    }
}

// ---------------- complex_norm over FF partial sums -> fp16 Z ----------------
__global__ __launch_bounds__(256) void norm_split_kernel(
    const float* __restrict__ pr0, const float* __restrict__ pi0,
    const float* __restrict__ pr1, const float* __restrict__ pi1,
    unsigned short* __restrict__ Z) {
  const int row = blockIdx.x, tid = threadIdx.x;
  const int base = row * E_ + tid * 4;
  float4 r0 = *(const float4*)&pr0[base];
  float4 r1 = *(const float4*)&pr1[base];
  float4 i0 = *(const float4*)&pi0[base];
  float4 i1 = *(const float4*)&pi1[base];
  float4 zr = make_float4(r0.x + r1.x, r0.y + r1.y, r0.z + r1.z, r0.w + r1.w);
  float4 zi = make_float4(i0.x + i1.x, i0.y + i1.y, i0.z + i1.z, i0.w + i1.w);
  float mg[4];
  mg[0] = sqrtf(zr.x * zr.x + zi.x * zi.x);
  mg[1] = sqrtf(zr.y * zr.y + zi.y * zi.y);
  mg[2] = sqrtf(zr.z * zr.z + zi.z * zi.z);
  mg[3] = sqrtf(zr.w * zr.w + zi.w * zi.w);
  float s1 = mg[0] + mg[1] + mg[2] + mg[3];
  float s2 = mg[0]*mg[0] + mg[1]*mg[1] + mg[2]*mg[2] + mg[3]*mg[3];
  #pragma unroll
  for (int off = 1; off < 64; off <<= 1) {
    s1 += __shfl_xor(s1, off, 64);
    s2 += __shfl_xor(s2, off, 64);
  }
  __shared__ float ws1[4], ws2[4];
  if ((tid & 63) == 0) { ws1[tid >> 6] = s1; ws2[tid >> 6] = s2; }
  __syncthreads();
  s1 = ws1[0] + ws1[1] + ws1[2] + ws1[3];
  s2 = ws2[0] + ws2[1] + ws2[2] + ws2[3];
  float mean = s1 * (1.0f / 1024.0f);
  float var = (s2 - 1024.0f * mean * mean) * (1.0f / 1023.0f);  // ddof=1
  var = fmaxf(var, 0.0f);
  float inv_sd = 1.0f / (sqrtf(var) + 1e-5f);
  float sc[4];
  #pragma unroll
  for (int t = 0; t < 4; ++t)
    sc[t] = tanhf((mg[t] - mean) * inv_sd) / (mg[t] + 1e-5f);
  h4 hr, hi;
  hr[0] = (_Float16)(zr.x * sc[0]); hr[1] = (_Float16)(zr.y * sc[1]);
  hr[2] = (_Float16)(zr.z * sc[2]); hr[3] = (_Float16)(zr.w * sc[3]);
  hi[0] = (_Float16)(zi.x * sc[0]); hi[1] = (_Float16)(zi.y * sc[1]);
  hi[2] = (_Float16)(zi.z * sc[2]); hi[3] = (_Float16)(zi.w * sc[3]);
  const size_t zb = (size_t)row * 2048 + tid * 4;
  *(h4*)&Z[zb]        = hr;
  *(h4*)&Z[zb + 1024] = hi;
}

// ---------------- reduce RO partials + biases -> out ----------------
__global__ void reduce_bias_kernel(const float* __restrict__ part,
                                   const float* __restrict__ rb,
                                   const float* __restrict__ ib,
                                   float* __restrict__ out) {
  int i4 = (blockIdx.x * 256 + threadIdx.x) * 4;   // < 4096*256
  int col = i4 & 255;
  float4 s = *(const float4*)&part[i4];
  #pragma unroll
  for (int z = 1; z < 8; ++z) {
    float4 v = *(const float4*)&part[(size_t)z * 1048576 + i4];
    s.x += v.x; s.y += v.y; s.z += v.z; s.w += v.w;
  }
  s.x += rb[col + 0] + ib[col + 0];
  s.y += rb[col + 1] + ib[col + 1];
  s.z += rb[col + 2] + ib[col + 2];
  s.w += rb[col + 3] + ib[col + 3];
  *(float4*)&out[i4] = s;
}

extern "C" void kernel_launch(void* const* d_in, const int* in_sizes, int n_in,
                              void* d_out, int out_size, void* d_ws, size_t ws_size,
                              hipStream_t stream) {
  const int*   x    = (const int*)d_in[0];
  const float* te   = (const float*)d_in[1];
  const float* pp   = (const float*)d_in[2];
  const float* qr   = (const float*)d_in[3];
  const float* kr   = (const float*)d_in[4];
  const float* vr   = (const float*)d_in[5];
  const float* ffr  = (const float*)d_in[6];
  const float* ffi  = (const float*)d_in[7];
  const float* rorw = (const float*)d_in[8];
  const float* rorb = (const float*)d_in[9];
  const float* roiw = (const float*)d_in[10];
  const float* roib = (const float*)d_in[11];
  float* out = (float*)d_out;

  char* W = (char*)d_ws;
  const size_t MiB = 1 << 20;
  // [0,16) srh(8MB used) -> pr0(f32 16MB) | [16,32) sih -> pi0
  // [32,48) Af -> Zhl
  // [48,64) Kd -> Bt[48,56) + Wt[56,57)   (after attn)
  // [64,80) Vd -> pr1 ┐
  // [80,96) pi1       ┴-> ro_part [64,96)  (after norm)
  // [96,+24K) tabs
  unsigned short* srh = (unsigned short*)W;
  unsigned short* sih = (unsigned short*)(W + 16 * MiB);
  unsigned short* Af = (unsigned short*)(W + 32 * MiB);
  unsigned short* Kd = (unsigned short*)(W + 48 * MiB);
  unsigned short* Vd = (unsigned short*)(W + 64 * MiB);
  unsigned short* Bt = (unsigned short*)(W + 48 * MiB);
  unsigned short* Wt = (unsigned short*)(W + 56 * MiB);
  float* tabs = (float*)(W + 96 * MiB);
  float* pr0 = (float*)W;
  float* pi0 = (float*)(W + 16 * MiB);
  float* pr1 = (float*)(W + 64 * MiB);
  float* pi1 = (float*)(W + 80 * MiB);
  unsigned short* Zhl = Af;
  float* ro_part = (float*)(W + 64 * MiB);   // 8 x 4 MiB

  rot_kernel<<<12, 256, 0, stream>>>(qr, kr, vr, tabs);
  embed_qkv_kernel<<<dim3(32, 64), 256, 0, stream>>>(x, te, pp, tabs, srh, sih, Kd, Vd);
  attn_mfma_kernel<<<1024, 256, 0, stream>>>(srh, sih, Kd, Vd, tabs, Af);
  split_b_kernel<<<dim3(64, 64), 256, 0, stream>>>(ffr, ffi, Bt);
  split_w_kernel<<<512, 256, 0, stream>>>(rorw, roiw, Wt);
  gemm_ff<<<dim3(32, 16, 2), 256, 0, stream>>>(Af, Bt, pr0, pi0, pr1, pi1);
  norm_split_kernel<<<B_ * S_, 256, 0, stream>>>(pr0, pi0, pr1, pi1, Zhl);
  gemm_ro<<<dim3(32, 2, 8), 256, 0, stream>>>(Zhl, Wt, ro_part);
  reduce_bias_kernel<<<1024, 256, 0, stream>>>(ro_part, rorb, roib, out);
}

// Round 19
// 145.927 us; speedup vs baseline: 1.4570x; 1.0007x over previous
//
#include <hip/hip_runtime.h>
#include <math.h>

// PhaseMultiHeadDecoder: B=4, S=1024, E=1024, H=16, hd=64, V=256
// Full fp16 pipeline. embed: fast v_sin/v_cos + exp-tanh, fp16 state.
// attn: balanced pairing, gload_lds dbuf, exp2-domain fused 32-key softmax
// (deferred l-reduce, max3 tree), defer-max, setprio, pkrtz P-pack.
// FF GEMM: 4-mult complex (K=2048) K-split x2. RO GEMM: K-split x4.
// XCD-colocated swizzles. (Karatsuba reverted: fp16 3-mult = ~3x imag error.)
#define B_ 4
#define S_ 1024
#define E_ 1024
#define H_ 16
#define V_ 256

typedef _Float16 h8 __attribute__((ext_vector_type(8)));
typedef _Float16 h4 __attribute__((ext_vector_type(4)));
typedef __fp16 f16x2 __attribute__((ext_vector_type(2)));   // cvt_pkrtz result type
typedef int i2 __attribute__((ext_vector_type(2)));
typedef float f4x __attribute__((ext_vector_type(4)));

__device__ __forceinline__ void gload16(const void* g, void* l) {
  __builtin_amdgcn_global_load_lds((const __attribute__((address_space(1))) void*)g,
                                   (__attribute__((address_space(3))) void*)l, 16, 0, 0);
}

#define MFMA32F16(a, b, c) __builtin_amdgcn_mfma_f32_16x16x32_f16(a, b, c, 0, 0, 0)

#if defined(__has_builtin)
#if __has_builtin(__builtin_amdgcn_mfma_f32_16x16x16f16)
#define MFMA16F16(a, b, c) __builtin_amdgcn_mfma_f32_16x16x16f16(a, b, c, 0, 0, 0)
#endif
#endif
#ifndef MFMA16F16
__device__ __forceinline__ f4x mfma16f16_asm(h4 a, h4 b, f4x c) {
  asm volatile("v_mfma_f32_16x16x16_f16 %0, %1, %2, %0" : "+v"(c) : "v"(a), "v"(b));
  return c;
}
#define MFMA16F16(a, b, c) mfma16f16_asm(a, b, c)
#endif

// fast sincos: rev = fract(x/2pi); v_sin/v_cos take revolutions (ISA 3)
__device__ __forceinline__ void fast_sincos(float x, float* s, float* c) {
  float rev = x * 0.15915494309189535f;
  rev = rev - floorf(rev);
  float sv, cv;
  asm("v_sin_f32 %0, %1" : "=v"(sv) : "v"(rev));
  asm("v_cos_f32 %0, %1" : "=v"(cv) : "v"(rev));
  *s = sv; *c = cv;
}
__device__ __forceinline__ float fast_tanh(float x) {
  return 1.0f - 2.0f / (__expf(2.0f * x) + 1.0f);
}
// raw 2^x (v_exp_f32 IS exp2)
__device__ __forceinline__ float fast_exp2(float x) {
  float r;
  asm("v_exp_f32 %0, %1" : "=v"(r) : "v"(x));
  return r;
}

// ---------------- rotation cos/sin tables: tabs[3][2][1024] ----------------
__global__ void rot_kernel(const float* __restrict__ qr, const float* __restrict__ kr,
                           const float* __restrict__ vr, float* __restrict__ tabs) {
  int i = blockIdx.x * blockDim.x + threadIdx.x;
  if (i >= 3 * 1024) return;
  int which = i >> 10;
  int j = i & 1023;
  const float* src = which == 0 ? qr : (which == 1 ? kr : vr);
  float s, c;
  sincosf(src[j], &s, &c);   // small args, exact path
  tabs[which * 2048 + j] = c;
  tabs[which * 2048 + 1024 + j] = s;
}

// ---------------- fused embed + K'/V' prep (fp16 state) ----------------
__global__ __launch_bounds__(256) void embed_qkv_kernel(
    const int* __restrict__ x, const float* __restrict__ te,
    const float* __restrict__ pp, const float* __restrict__ tabs,
    unsigned short* __restrict__ srh, unsigned short* __restrict__ sih,
    unsigned short* __restrict__ Kd, unsigned short* __restrict__ Vd) {
  __shared__ unsigned short Kl2[4096];
  __shared__ unsigned short Vl2[4096];
  const int kt2 = blockIdx.x;          // 32-row group, 0..31
  const int bh = blockIdx.y;           // 0..63
  const int b = bh >> 4, h = bh & 15;
  const int tid = threadIdx.x;
  const float* qc = tabs + h * 64;
  const float* qs = tabs + 1024 + h * 64;
  const float* kc = tabs + 2048 + h * 64;
  const float* ks = tabs + 3072 + h * 64;
  #pragma unroll
  for (int p = 0; p < 8; ++p) {
    int id = p * 256 + tid;            // 2048 items = 32 rows x 64 dims
    int sl = id >> 6;
    int dd = id & 63;
    int s = kt2 * 32 + sl;
    int e = h * 64 + dd;
    int tok = x[b * 1024 + s];
    float mm = fast_tanh(te[tok * 1024 + e]);
    float sn, cs;
    fast_sincos(pp[s * 1024 + e], &sn, &cs);
    float re = mm * cs, im = mm * sn;
    size_t g = ((size_t)(b * 1024 + s)) * 1024 + e;
    *(_Float16*)&srh[g] = (_Float16)re;
    *(_Float16*)&sih[g] = (_Float16)im;
    float cq = qc[dd], sq = qs[dd], ck = kc[dd], sk = ks[dd];
    float cd = cq * ck + sq * sk;      // cos(thq - thk)
    float sd = sq * ck - cq * sk;      // sin(thq - thk)
    float kr = re * cd + im * sd;      // k-state rotated by -delta
    float ki = im * cd - re * sd;
    int t = sl >> 4, key = sl & 15;
    int c0 = dd, c1 = 64 + dd;
    #define KOFF(c) (t * 2048 + ((((c) >> 5) * 4 + (((c) >> 3) & 3)) * 16 + key) * 8 + ((c) & 7))
    *(_Float16*)&Kl2[KOFF(c0)] = (_Float16)kr;
    *(_Float16*)&Kl2[KOFF(c1)] = (_Float16)ki;
    #undef KOFF
    int kgk = key >> 2, jk = key & 3;
    #define VOFF(d) (t * 2048 + ((((d) >> 4) * 4 + kgk) * 16 + ((d) & 15)) * 4 + jk)
    *(_Float16*)&Vl2[VOFF(dd)] = (_Float16)re;
    *(_Float16*)&Vl2[VOFF(64 + dd)] = (_Float16)im;
    #undef VOFF
  }
  __syncthreads();
  unsigned short* kdst = Kd + ((size_t)(bh * 64 + kt2 * 2)) * 2048;
  unsigned short* vdst = Vd + ((size_t)(bh * 64 + kt2 * 2)) * 2048;
  #pragma unroll
  for (int p = 0; p < 2; ++p) {
    int c = p * 256 + tid;
    ((int4*)kdst)[c] = ((const int4*)Kl2)[c];
    ((int4*)vdst)[c] = ((const int4*)Vl2)[c];
  }
}

// ---------------- fp16 MFMA flash attention, balanced pairing ----------------
// grid 1024: flat -> low=flat&7 (XCD=bh&7), a=(flat>>3)>>3 in 0..15,
// bh=((flat>>3)&7)<<3|low. Waves 0-1: rows 32a..; waves 2-3: rows 32(31-a)..
// Softmax runs in exp2 domain (Q pre-scaled by log2 e); l_ is a per-lane
// partial reduced once in the epilogue.
__global__ __launch_bounds__(256, 4) void attn_mfma_kernel(
    const unsigned short* __restrict__ srh, const unsigned short* __restrict__ sih,
    const unsigned short* __restrict__ Kd, const unsigned short* __restrict__ Vd,
    const float* __restrict__ tabs,
    unsigned short* __restrict__ Af) {
  __shared__ __align__(16) unsigned short Klds[2][4096];
  __shared__ __align__(16) unsigned short Vlds[2][4096];
  const int flat = blockIdx.x;
  const int low = flat & 7, rest = flat >> 3;
  const int a = rest >> 3;             // 0..15 (pair index)
  const int bh = ((rest & 7) << 3) | low;
  const int b = bh >> 4, h = bh & 15;
  const int tid = threadIdx.x, lane = tid & 63, wid = tid >> 6;
  const int cl = lane & 15, kg = lane >> 4;
  const int atile = (wid >> 1) ? (31 - a) : a;      // 32-row half-tile
  const int qw0 = atile * 32 + (wid & 1) * 16;      // this wave's 16 q-rows

  // Q^T b-frag: direct fp16 16B loads, pre-scaled by log2(e)
  h8 qf[4];
  {
    int q = qw0 + cl;
    const unsigned short* srow = srh + ((size_t)(b * 1024 + q)) * 1024 + h * 64;
    const unsigned short* irow = sih + ((size_t)(b * 1024 + q)) * 1024 + h * 64;
    #pragma unroll
    for (int ksx = 0; ksx < 4; ++ksx) {
      int f0 = ksx * 32 + kg * 8;
      qf[ksx] = (f0 < 64) ? *(const h8*)(srow + f0) : *(const h8*)(irow + (f0 - 64));
      qf[ksx] *= (_Float16)1.4426950408889634f;
    }
  }

  f4x acc[8] = {};                     // out^T: [mt], d = mt*16+kg*4+r (mt<4 re, >=4 im)
  float m_ = -1e30f, l_ = 0.f;         // m_ in log2 units; l_ per-lane partial
  const int np = 32 - a;               // staged 32-key pairs (covers high tile)
  const int wqmax = qw0 + 15;
  const int qcol = qw0 + cl;

  const unsigned short* kstream = Kd + ((size_t)(bh * 64)) * 2048;
  const unsigned short* vstream = Vd + ((size_t)(bh * 64)) * 2048;

  #define STAGE_PAIR(buf, P)                                                    \
    {                                                                           \
      const unsigned short* kb = kstream + (size_t)(P) * 4096;                  \
      const unsigned short* vb = vstream + (size_t)(P) * 4096;                  \
      _Pragma("unroll")                                                         \
      for (int r = 0; r < 2; ++r) {                                             \
        int off = r * 256 + wid * 64;                                           \
        gload16(kb + (size_t)(off + lane) * 8, &Klds[buf][off * 8]);            \
        gload16(vb + (size_t)(off + lane) * 8, &Vlds[buf][off * 8]);            \
      }                                                                         \
    }

  STAGE_PAIR(0, 0)
  __syncthreads();                     // pair 0 landed

  for (int p = 0; p < np; ++p) {
    const int cur = p & 1;
    if (p + 1 < np) STAGE_PAIR(cur ^ 1, p + 1)   // async: in flight during compute
    const int k0a = p * 32;
    if (k0a <= wqmax) {                // wave-uniform causal skip
      __builtin_amdgcn_s_setprio(1);
      f4x sca = {}, scb = {};
      #pragma unroll
      for (int ksx = 0; ksx < 4; ++ksx) {
        h8 ka = *(const h8*)&Klds[cur][ksx * 512 + lane * 8];
        sca = MFMA32F16(ka, qf[ksx], sca);
      }
      #pragma unroll
      for (int ksx = 0; ksx < 4; ++ksx) {
        h8 kb = *(const h8*)&Klds[cur][2048 + ksx * 512 + lane * 8];
        scb = MFMA32F16(kb, qf[ksx], scb);
      }
      __builtin_amdgcn_s_setprio(0);
      if (k0a + 31 > qw0) {            // causal mask (boundary pairs only)
        #pragma unroll
        for (int r = 0; r < 4; ++r) {
          if (k0a + kg * 4 + r > qcol)      sca[r] = -1e30f;
          if (k0a + 16 + kg * 4 + r > qcol) scb[r] = -1e30f;
        }
      }
      // fused 32-key online softmax (exp2 domain), defer-max THR = 8 nats
      float mA = fmaxf(fmaxf(sca[0], sca[1]), sca[2]);          // v_max3
      float mB = fmaxf(fmaxf(sca[3], scb[0]), scb[1]);          // v_max3
      float mC = fmaxf(fmaxf(scb[2], scb[3]), mA);              // v_max3
      float mx = fmaxf(mB, mC);
      mx = fmaxf(mx, __shfl_xor(mx, 16, 64));
      mx = fmaxf(mx, __shfl_xor(mx, 32, 64));
      if (!__all(mx <= m_ + 11.5416f)) {
        float mn = fmaxf(m_, mx);
        float corr = fast_exp2(m_ - mn);
        #pragma unroll
        for (int mt = 0; mt < 8; ++mt) acc[mt] *= corr;
        l_ *= corr;
        m_ = mn;
      }
      float pa0 = fast_exp2(sca[0] - m_), pa1 = fast_exp2(sca[1] - m_);
      float pa2 = fast_exp2(sca[2] - m_), pa3 = fast_exp2(sca[3] - m_);
      float pb0 = fast_exp2(scb[0] - m_), pb1 = fast_exp2(scb[1] - m_);
      float pb2 = fast_exp2(scb[2] - m_), pb3 = fast_exp2(scb[3] - m_);
      l_ += ((pa0 + pa1) + (pa2 + pa3)) + ((pb0 + pb1) + (pb2 + pb3));
      // pack P via cvt_pkrtz, assemble h4 via bitcast (no element moves)
      f16x2 a01 = __builtin_amdgcn_cvt_pkrtz(pa0, pa1);
      f16x2 a23 = __builtin_amdgcn_cvt_pkrtz(pa2, pa3);
      f16x2 b01 = __builtin_amdgcn_cvt_pkrtz(pb0, pb1);
      f16x2 b23 = __builtin_amdgcn_cvt_pkrtz(pb2, pb3);
      i2 ta, tb;
      ta[0] = __builtin_bit_cast(int, a01); ta[1] = __builtin_bit_cast(int, a23);
      tb[0] = __builtin_bit_cast(int, b01); tb[1] = __builtin_bit_cast(int, b23);
      h4 pba = __builtin_bit_cast(h4, ta);
      h4 pbb = __builtin_bit_cast(h4, tb);
      __builtin_amdgcn_s_setprio(1);
      #pragma unroll
      for (int mt = 0; mt < 8; ++mt) {
        h4 va = *(const h4*)&Vlds[cur][mt * 256 + lane * 4];
        acc[mt] = MFMA16F16(va, pba, acc[mt]);
      }
      #pragma unroll
      for (int mt = 0; mt < 8; ++mt) {
        h4 vb = *(const h4*)&Vlds[cur][2048 + mt * 256 + lane * 4];
        acc[mt] = MFMA16F16(vb, pbb, acc[mt]);
      }
      __builtin_amdgcn_s_setprio(0);
    }
    __syncthreads();   // staged pair landed + readers done
  }
  #undef STAGE_PAIR
  // epilogue: reduce l_ across kg lanes, /l, rotate by exp(i*thv), add state
  {
    l_ += __shfl_xor(l_, 16, 64);
    l_ += __shfl_xor(l_, 32, 64);
    float linv = 1.0f / l_;
    int q = qw0 + cl;
    size_t mrow = (size_t)(b * 1024 + q);
    size_t obase = mrow * 1024 + h * 64;
    size_t abase = mrow * 2048 + h * 64;
    #pragma unroll
    for (int mt = 0; mt < 4; ++mt) {
      int d0 = mt * 16 + kg * 4;
      h4 s_r = *(const h4*)&srh[obase + d0];
      h4 s_i = *(const h4*)&sih[obase + d0];
      h4 hr, hi;
      #pragma unroll
      for (int r = 0; r < 4; ++r) {
        int d = d0 + r;
        float orv = acc[mt][r] * linv;
        float oiv = acc[mt + 4][r] * linv;
        float c = tabs[4096 + h * 64 + d], s = tabs[5120 + h * 64 + d];
        hr[r] = (_Float16)(orv * c - oiv * s + (float)s_r[r]);
        hi[r] = (_Float16)(orv * s + oiv * c + (float)s_i[r]);
      }
      *(h4*)&Af[abase + d0]        = hr;   // real
      *(h4*)&Af[abase + 1024 + d0] = hi;   // imag
    }
  }
}

// ---------------- transpose FF weight -> fp16: Bt[2048][2048] ----------------
__global__ void split_b_kernel(const float* __restrict__ fr, const float* __restrict__ fi,
                               unsigned short* __restrict__ Bt) {
  __shared__ float tile[32][33];
  const int k0 = blockIdx.x * 32, n0 = blockIdx.y * 32;
  const int tid = threadIdx.x;
  #pragma unroll
  for (int p = 0; p < 4; ++p) {
    int e = p * 256 + tid;
    int kk = e >> 5, nn = e & 31;
    int k = k0 + kk, n = n0 + nn;
    float v;
    if (n < 1024) v = (k < 1024) ? fr[(size_t)k * 1024 + n] : -fi[(size_t)(k - 1024) * 1024 + n];
    else          v = (k < 1024) ? fi[(size_t)k * 1024 + (n - 1024)]
                                 : fr[(size_t)(k - 1024) * 1024 + (n - 1024)];
    tile[kk][nn] = v;
  }
  __syncthreads();
  #pragma unroll
  for (int p = 0; p < 4; ++p) {
    int e = p * 256 + tid;
    int nn = e >> 5, kk = e & 31;
    *(_Float16*)&Bt[(size_t)(n0 + nn) * 2048 + (k0 + kk)] = (_Float16)tile[kk][nn];
  }
}

// ---------------- readout weight fp16: Wt[256][wr1024|wi1024] ----------------
__global__ void split_w_kernel(const float* __restrict__ wr, const float* __restrict__ wi,
                               unsigned short* __restrict__ Wt) {
  int idx = blockIdx.x * 256 + threadIdx.x;        // 256*512
  int v = idx >> 9;
  int k4 = (idx & 511) * 4;
  float4 a = (k4 < 1024) ? *(const float4*)&wr[(size_t)v * 1024 + k4]
                         : *(const float4*)&wi[(size_t)v * 1024 + k4 - 1024];
  h4 h;
  h[0] = (_Float16)a.x; h[1] = (_Float16)a.y;
  h[2] = (_Float16)a.z; h[3] = (_Float16)a.w;
  *(h4*)&Wt[(size_t)v * 2048 + k4] = h;
}

// ---------------- FF GEMM: fp16, 128x128 tile, K-split x2, XCD-colocated -----
__global__ __launch_bounds__(256, 4) void gemm_ff(
    const unsigned short* __restrict__ A,   // [4096][2048] fp16 bits
    const unsigned short* __restrict__ Bt,  // [2048][2048]
    float* __restrict__ pr0, float* __restrict__ pi0,
    float* __restrict__ pr1, float* __restrict__ pi1) {
  __shared__ short As[128 * 64];
  __shared__ short Bs[128 * 64];
  const int tid = threadIdx.x;
  const int lane = tid & 63, wid = tid >> 6;
  // XCD swizzle: linear id l (z adds 512 = 0 mod 8); colocate 4 m-bands/XCD
  const int l = blockIdx.x + (blockIdx.y << 5);
  const int xcd = l & 7, j = l >> 3;
  const int m0 = ((xcd << 2) + (j & 3)) << 7;      // 32 m-tiles
  const int n0 = (j >> 2) << 7;                    // 16 n-tiles
  const int z = blockIdx.z;
  const int wr = wid >> 1, wc = wid & 1;
  const int cl = lane & 15, rg = lane >> 4;

  f4x acc[4][4] = {};
  const int cbase = wid * 256;

  for (int kt = z * 16; kt < z * 16 + 16; ++kt) {
    const int k0 = kt * 64;
    #pragma unroll
    for (int it = 0; it < 4; ++it) {
      int c = cbase + it * 64 + lane;
      gload16(A + (size_t)(m0 + (c >> 3)) * 2048 + k0 + (c & 7) * 8,
              As + (cbase + it * 64) * 8);
      gload16(Bt + (size_t)(n0 + (c >> 3)) * 2048 + k0 + (c & 7) * 8,
              Bs + (cbase + it * 64) * 8);
    }
    __syncthreads();
    #pragma unroll
    for (int ks = 0; ks < 2; ++ks) {
      h8 a[4], b[4];
      #pragma unroll
      for (int ms = 0; ms < 4; ++ms)
        a[ms] = *(const h8*)&As[(wr * 64 + ms * 16 + cl) * 64 + ks * 32 + rg * 8];
      #pragma unroll
      for (int ns = 0; ns < 4; ++ns)
        b[ns] = *(const h8*)&Bs[(wc * 64 + ns * 16 + cl) * 64 + ks * 32 + rg * 8];
      #pragma unroll
      for (int ms = 0; ms < 4; ++ms)
        #pragma unroll
        for (int ns = 0; ns < 4; ++ns)
          acc[ms][ns] = MFMA32F16(a[ms], b[ns], acc[ms][ns]);
    }
    __syncthreads();
  }

  const int colbase = n0 + wc * 64;
  float* o_r = z ? pr1 : pr0;
  float* o_i = z ? pi1 : pi0;
  float* dst = (colbase < 1024) ? o_r : o_i;
  const int cb = colbase & 1023;
  #pragma unroll
  for (int ms = 0; ms < 4; ++ms)
    #pragma unroll
    for (int r2 = 0; r2 < 4; ++r2) {
      const int grow = m0 + wr * 64 + ms * 16 + rg * 4 + r2;
      #pragma unroll
      for (int ns = 0; ns < 4; ++ns)
        dst[(size_t)grow * 1024 + cb + ns * 16 + cl] = acc[ms][ns][r2];
    }
}

// ---------------- RO GEMM: fp16, 128x128 tile, K=2048, K-split x4 ------------
__global__ __launch_bounds__(256, 4) void gemm_ro(
    const unsigned short* __restrict__ Z,   // [4096][2048] fp16 bits
    const unsigned short* __restrict__ Wt,  // [256][2048]
    float* __restrict__ part) {             // [4][4096][256]
  __shared__ short As[128 * 64];
  __shared__ short Bs[128 * 64];
  const int tid = threadIdx.x;
  const int lane = tid & 63, wid = tid >> 6;
  const int l = blockIdx.x + (blockIdx.y << 5);   // 0..63 (z adds 64 = 0 mod 8)
  const int xcd = l & 7, j = l >> 3;
  const int m0 = ((xcd << 2) + (j & 3)) << 7;     // 32 m-tiles
  const int n0 = (j >> 2) << 7;                   // 2 n-tiles
  const int z = blockIdx.z;
  const int wr = wid >> 1, wc = wid & 1;
  const int cl = lane & 15, rg = lane >> 4;

  f4x acc[4][4] = {};
  const int cbase = wid * 256;

  for (int kt = z * 8; kt < z * 8 + 8; ++kt) {
    const int k0 = kt * 64;
    #pragma unroll
    for (int it = 0; it < 4; ++it) {
      int c = cbase + it * 64 + lane;
      gload16(Z + (size_t)(m0 + (c >> 3)) * 2048 + k0 + (c & 7) * 8,
              As + (cbase + it * 64) * 8);
      gload16(Wt + (size_t)(n0 + (c >> 3)) * 2048 + k0 + (c & 7) * 8,
              Bs + (cbase + it * 64) * 8);
    }
    __syncthreads();
    #pragma unroll
    for (int ks = 0; ks < 2; ++ks) {
      h8 a[4], b[4];
      #pragma unroll
      for (int ms = 0; ms < 4; ++ms)
        a[ms] = *(const h8*)&As[(wr * 64 + ms * 16 + cl) * 64 + ks * 32 + rg * 8];
      #pragma unroll
      for (int ns = 0; ns < 4; ++ns)
        b[ns] = *(const h8*)&Bs[(wc * 64 + ns * 16 + cl) * 64 + ks * 32 + rg * 8];
      #pragma unroll
      for (int ms = 0; ms < 4; ++ms)
        #pragma unroll
        for (int ns = 0; ns < 4; ++ns)
          acc[ms][ns] = MFMA32F16(a[ms], b[ns], acc[ms][ns]);
    }
    __syncthreads();
  }

  float* dst = part + (size_t)z * 4096 * 256;
  const int colbase = n0 + wc * 64;
  #pragma unroll
  for (int ms = 0; ms < 4; ++ms)
    #pragma unroll
    for (int r2 = 0; r2 < 4; ++r2) {
      const int grow = m0 + wr * 64 + ms * 16 + rg * 4 + r2;
      #pragma unroll
      for (int ns = 0; ns < 4; ++ns)
        dst[(size_t)grow * 256 + colbase + ns * 16 + cl] = acc[ms][ns][r2];
    }
}

// ---------------- complex_norm over FF partial sums -> fp16 Z ----------------
__global__ __launch_bounds__(256) void norm_split_kernel(
    const float* __restrict__ pr0, const float* __restrict__ pi0,
    const float* __restrict__ pr1, const float* __restrict__ pi1,
    unsigned short* __restrict__ Z) {
  const int row = blockIdx.x, tid = threadIdx.x;
  const int base = row * E_ + tid * 4;
  float4 r0 = *(const float4*)&pr0[base];
  float4 r1 = *(const float4*)&pr1[base];
  float4 i0 = *(const float4*)&pi0[base];
  float4 i1 = *(const float4*)&pi1[base];
  float4 zr = make_float4(r0.x + r1.x, r0.y + r1.y, r0.z + r1.z, r0.w + r1.w);
  float4 zi = make_float4(i0.x + i1.x, i0.y + i1.y, i0.z + i1.z, i0.w + i1.w);
  float mg[4];
  mg[0] = sqrtf(zr.x * zr.x + zi.x * zi.x);
  mg[1] = sqrtf(zr.y * zr.y + zi.y * zi.y);
  mg[2] = sqrtf(zr.z * zr.z + zi.z * zi.z);
  mg[3] = sqrtf(zr.w * zr.w + zi.w * zi.w);
  float s1 = mg[0] + mg[1] + mg[2] + mg[3];
  float s2 = mg[0]*mg[0] + mg[1]*mg[1] + mg[2]*mg[2] + mg[3]*mg[3];
  #pragma unroll
  for (int off = 1; off < 64; off <<= 1) {
    s1 += __shfl_xor(s1, off, 64);
    s2 += __shfl_xor(s2, off, 64);
  }
  __shared__ float ws1[4], ws2[4];
  if ((tid & 63) == 0) { ws1[tid >> 6] = s1; ws2[tid >> 6] = s2; }
  __syncthreads();
  s1 = ws1[0] + ws1[1] + ws1[2] + ws1[3];
  s2 = ws2[0] + ws2[1] + ws2[2] + ws2[3];
  float mean = s1 * (1.0f / 1024.0f);
  float var = (s2 - 1024.0f * mean * mean) * (1.0f / 1023.0f);  // ddof=1
  var = fmaxf(var, 0.0f);
  float inv_sd = 1.0f / (sqrtf(var) + 1e-5f);
  float sc[4];
  #pragma unroll
  for (int t = 0; t < 4; ++t)
    sc[t] = tanhf((mg[t] - mean) * inv_sd) / (mg[t] + 1e-5f);
  h4 hr, hi;
  hr[0] = (_Float16)(zr.x * sc[0]); hr[1] = (_Float16)(zr.y * sc[1]);
  hr[2] = (_Float16)(zr.z * sc[2]); hr[3] = (_Float16)(zr.w * sc[3]);
  hi[0] = (_Float16)(zi.x * sc[0]); hi[1] = (_Float16)(zi.y * sc[1]);
  hi[2] = (_Float16)(zi.z * sc[2]); hi[3] = (_Float16)(zi.w * sc[3]);
  const size_t zb = (size_t)row * 2048 + tid * 4;
  *(h4*)&Z[zb]        = hr;
  *(h4*)&Z[zb + 1024] = hi;
}

// ---------------- reduce RO partials + biases -> out ----------------
__global__ void reduce_bias_kernel(const float* __restrict__ part,
                                   const float* __restrict__ rb,
                                   const float* __restrict__ ib,
                                   float* __restrict__ out) {
  int i4 = (blockIdx.x * 256 + threadIdx.x) * 4;   // < 4096*256
  int col = i4 & 255;
  float4 s = *(const float4*)&part[i4];
  #pragma unroll
  for (int z = 1; z < 4; ++z) {
    float4 v = *(const float4*)&part[(size_t)z * 1048576 + i4];
    s.x += v.x; s.y += v.y; s.z += v.z; s.w += v.w;
  }
  s.x += rb[col + 0] + ib[col + 0];
  s.y += rb[col + 1] + ib[col + 1];
  s.z += rb[col + 2] + ib[col + 2];
  s.w += rb[col + 3] + ib[col + 3];
  *(float4*)&out[i4] = s;
}

extern "C" void kernel_launch(void* const* d_in, const int* in_sizes, int n_in,
                              void* d_out, int out_size, void* d_ws, size_t ws_size,
                              hipStream_t stream) {
  const int*   x    = (const int*)d_in[0];
  const float* te   = (const float*)d_in[1];
  const float* pp   = (const float*)d_in[2];
  const float* qr   = (const float*)d_in[3];
  const float* kr   = (const float*)d_in[4];
  const float* vr   = (const float*)d_in[5];
  const float* ffr  = (const float*)d_in[6];
  const float* ffi  = (const float*)d_in[7];
  const float* rorw = (const float*)d_in[8];
  const float* rorb = (const float*)d_in[9];
  const float* roiw = (const float*)d_in[10];
  const float* roib = (const float*)d_in[11];
  float* out = (float*)d_out;

  char* W = (char*)d_ws;
  const size_t MiB = 1 << 20;
  // [0,16) srh(8MB used) -> pr0(f32 16MB) | [16,32) sih -> pi0
  // [32,48) Af -> Zhl
  // [48,64) Kd -> Bt[48,56) + Wt[56,57)   (after attn)
  // [64,80) Vd -> pr1 ┐
  // [80,96) pi1       ┴-> ro_part [64,80)  (after norm)
  // [96,+24K) tabs
  unsigned short* srh = (unsigned short*)W;
  unsigned short* sih = (unsigned short*)(W + 16 * MiB);
  unsigned short* Af = (unsigned short*)(W + 32 * MiB);
  unsigned short* Kd = (unsigned short*)(W + 48 * MiB);
  unsigned short* Vd = (unsigned short*)(W + 64 * MiB);
  unsigned short* Bt = (unsigned short*)(W + 48 * MiB);
  unsigned short* Wt = (unsigned short*)(W + 56 * MiB);
  float* tabs = (float*)(W + 96 * MiB);
  float* pr0 = (float*)W;
  float* pi0 = (float*)(W + 16 * MiB);
  float* pr1 = (float*)(W + 64 * MiB);
  float* pi1 = (float*)(W + 80 * MiB);
  unsigned short* Zhl = Af;
  float* ro_part = (float*)(W + 64 * MiB);   // 4 x 4 MiB

  rot_kernel<<<12, 256, 0, stream>>>(qr, kr, vr, tabs);
  embed_qkv_kernel<<<dim3(32, 64), 256, 0, stream>>>(x, te, pp, tabs, srh, sih, Kd, Vd);
  attn_mfma_kernel<<<1024, 256, 0, stream>>>(srh, sih, Kd, Vd, tabs, Af);
  split_b_kernel<<<dim3(64, 64), 256, 0, stream>>>(ffr, ffi, Bt);
  split_w_kernel<<<512, 256, 0, stream>>>(rorw, roiw, Wt);
  gemm_ff<<<dim3(32, 16, 2), 256, 0, stream>>>(Af, Bt, pr0, pi0, pr1, pi1);
  norm_split_kernel<<<B_ * S_, 256, 0, stream>>>(pr0, pi0, pr1, pi1, Zhl);
  gemm_ro<<<dim3(32, 2, 4), 256, 0, stream>>>(Zhl, Wt, ro_part);
  reduce_bias_kernel<<<1024, 256, 0, stream>>>(ro_part, rorb, roib, out);
}

// Round 20
// 143.138 us; speedup vs baseline: 1.4854x; 1.0195x over previous
//
#include <hip/hip_runtime.h>
#include <math.h>

// PhaseMultiHeadDecoder: B=4, S=1024, E=1024, H=16, hd=64, V=256
// Full fp16 pipeline. embed: fast v_sin/v_cos + exp-tanh, fp16 state.
// attn: balanced pairing, gload_lds dbuf, exp2-domain fused 32-key softmax.
// FF GEMM: 256x128 tile (8x4 frags/wave, 2 blocks/CU), K-split x2.
// RO GEMM: K-split x4. XCD-colocated swizzles.
#define B_ 4
#define S_ 1024
#define E_ 1024
#define H_ 16
#define V_ 256

typedef _Float16 h8 __attribute__((ext_vector_type(8)));
typedef _Float16 h4 __attribute__((ext_vector_type(4)));
typedef __fp16 f16x2 __attribute__((ext_vector_type(2)));   // cvt_pkrtz result type
typedef int i2 __attribute__((ext_vector_type(2)));
typedef float f4x __attribute__((ext_vector_type(4)));

__device__ __forceinline__ void gload16(const void* g, void* l) {
  __builtin_amdgcn_global_load_lds((const __attribute__((address_space(1))) void*)g,
                                   (__attribute__((address_space(3))) void*)l, 16, 0, 0);
}

#define MFMA32F16(a, b, c) __builtin_amdgcn_mfma_f32_16x16x32_f16(a, b, c, 0, 0, 0)

#if defined(__has_builtin)
#if __has_builtin(__builtin_amdgcn_mfma_f32_16x16x16f16)
#define MFMA16F16(a, b, c) __builtin_amdgcn_mfma_f32_16x16x16f16(a, b, c, 0, 0, 0)
#endif
#endif
#ifndef MFMA16F16
__device__ __forceinline__ f4x mfma16f16_asm(h4 a, h4 b, f4x c) {
  asm volatile("v_mfma_f32_16x16x16_f16 %0, %1, %2, %0" : "+v"(c) : "v"(a), "v"(b));
  return c;
}
#define MFMA16F16(a, b, c) mfma16f16_asm(a, b, c)
#endif

// fast sincos: rev = fract(x/2pi); v_sin/v_cos take revolutions (ISA 3)
__device__ __forceinline__ void fast_sincos(float x, float* s, float* c) {
  float rev = x * 0.15915494309189535f;
  rev = rev - floorf(rev);
  float sv, cv;
  asm("v_sin_f32 %0, %1" : "=v"(sv) : "v"(rev));
  asm("v_cos_f32 %0, %1" : "=v"(cv) : "v"(rev));
  *s = sv; *c = cv;
}
__device__ __forceinline__ float fast_tanh(float x) {
  return 1.0f - 2.0f / (__expf(2.0f * x) + 1.0f);
}
// raw 2^x (v_exp_f32 IS exp2)
__device__ __forceinline__ float fast_exp2(float x) {
  float r;
  asm("v_exp_f32 %0, %1" : "=v"(r) : "v"(x));
  return r;
}

// ---------------- rotation cos/sin tables: tabs[3][2][1024] ----------------
__global__ void rot_kernel(const float* __restrict__ qr, const float* __restrict__ kr,
                           const float* __restrict__ vr, float* __restrict__ tabs) {
  int i = blockIdx.x * blockDim.x + threadIdx.x;
  if (i >= 3 * 1024) return;
  int which = i >> 10;
  int j = i & 1023;
  const float* src = which == 0 ? qr : (which == 1 ? kr : vr);
  float s, c;
  sincosf(src[j], &s, &c);   // small args, exact path
  tabs[which * 2048 + j] = c;
  tabs[which * 2048 + 1024 + j] = s;
}

// ---------------- fused embed + K'/V' prep (fp16 state) ----------------
__global__ __launch_bounds__(256) void embed_qkv_kernel(
    const int* __restrict__ x, const float* __restrict__ te,
    const float* __restrict__ pp, const float* __restrict__ tabs,
    unsigned short* __restrict__ srh, unsigned short* __restrict__ sih,
    unsigned short* __restrict__ Kd, unsigned short* __restrict__ Vd) {
  __shared__ unsigned short Kl2[4096];
  __shared__ unsigned short Vl2[4096];
  const int kt2 = blockIdx.x;          // 32-row group, 0..31
  const int bh = blockIdx.y;           // 0..63
  const int b = bh >> 4, h = bh & 15;
  const int tid = threadIdx.x;
  const float* qc = tabs + h * 64;
  const float* qs = tabs + 1024 + h * 64;
  const float* kc = tabs + 2048 + h * 64;
  const float* ks = tabs + 3072 + h * 64;
  #pragma unroll
  for (int p = 0; p < 8; ++p) {
    int id = p * 256 + tid;            // 2048 items = 32 rows x 64 dims
    int sl = id >> 6;
    int dd = id & 63;
    int s = kt2 * 32 + sl;
    int e = h * 64 + dd;
    int tok = x[b * 1024 + s];
    float mm = fast_tanh(te[tok * 1024 + e]);
    float sn, cs;
    fast_sincos(pp[s * 1024 + e], &sn, &cs);
    float re = mm * cs, im = mm * sn;
    size_t g = ((size_t)(b * 1024 + s)) * 1024 + e;
    *(_Float16*)&srh[g] = (_Float16)re;
    *(_Float16*)&sih[g] = (_Float16)im;
    float cq = qc[dd], sq = qs[dd], ck = kc[dd], sk = ks[dd];
    float cd = cq * ck + sq * sk;      // cos(thq - thk)
    float sd = sq * ck - cq * sk;      // sin(thq - thk)
    float kr = re * cd + im * sd;      // k-state rotated by -delta
    float ki = im * cd - re * sd;
    int t = sl >> 4, key = sl & 15;
    int c0 = dd, c1 = 64 + dd;
    #define KOFF(c) (t * 2048 + ((((c) >> 5) * 4 + (((c) >> 3) & 3)) * 16 + key) * 8 + ((c) & 7))
    *(_Float16*)&Kl2[KOFF(c0)] = (_Float16)kr;
    *(_Float16*)&Kl2[KOFF(c1)] = (_Float16)ki;
    #undef KOFF
    int kgk = key >> 2, jk = key & 3;
    #define VOFF(d) (t * 2048 + ((((d) >> 4) * 4 + kgk) * 16 + ((d) & 15)) * 4 + jk)
    *(_Float16*)&Vl2[VOFF(dd)] = (_Float16)re;
    *(_Float16*)&Vl2[VOFF(64 + dd)] = (_Float16)im;
    #undef VOFF
  }
  __syncthreads();
  unsigned short* kdst = Kd + ((size_t)(bh * 64 + kt2 * 2)) * 2048;
  unsigned short* vdst = Vd + ((size_t)(bh * 64 + kt2 * 2)) * 2048;
  #pragma unroll
  for (int p = 0; p < 2; ++p) {
    int c = p * 256 + tid;
    ((int4*)kdst)[c] = ((const int4*)Kl2)[c];
    ((int4*)vdst)[c] = ((const int4*)Vl2)[c];
  }
}

// ---------------- fp16 MFMA flash attention, balanced pairing ----------------
// grid 1024: flat -> low=flat&7 (XCD=bh&7), a=(flat>>3)>>3 in 0..15,
// bh=((flat>>3)&7)<<3|low. Waves 0-1: rows 32a..; waves 2-3: rows 32(31-a)..
__global__ __launch_bounds__(256, 4) void attn_mfma_kernel(
    const unsigned short* __restrict__ srh, const unsigned short* __restrict__ sih,
    const unsigned short* __restrict__ Kd, const unsigned short* __restrict__ Vd,
    const float* __restrict__ tabs,
    unsigned short* __restrict__ Af) {
  __shared__ __align__(16) unsigned short Klds[2][4096];
  __shared__ __align__(16) unsigned short Vlds[2][4096];
  const int flat = blockIdx.x;
  const int low = flat & 7, rest = flat >> 3;
  const int a = rest >> 3;             // 0..15 (pair index)
  const int bh = ((rest & 7) << 3) | low;
  const int b = bh >> 4, h = bh & 15;
  const int tid = threadIdx.x, lane = tid & 63, wid = tid >> 6;
  const int cl = lane & 15, kg = lane >> 4;
  const int atile = (wid >> 1) ? (31 - a) : a;      // 32-row half-tile
  const int qw0 = atile * 32 + (wid & 1) * 16;      // this wave's 16 q-rows

  // Q^T b-frag: direct fp16 16B loads, pre-scaled by log2(e)
  h8 qf[4];
  {
    int q = qw0 + cl;
    const unsigned short* srow = srh + ((size_t)(b * 1024 + q)) * 1024 + h * 64;
    const unsigned short* irow = sih + ((size_t)(b * 1024 + q)) * 1024 + h * 64;
    #pragma unroll
    for (int ksx = 0; ksx < 4; ++ksx) {
      int f0 = ksx * 32 + kg * 8;
      qf[ksx] = (f0 < 64) ? *(const h8*)(srow + f0) : *(const h8*)(irow + (f0 - 64));
      qf[ksx] *= (_Float16)1.4426950408889634f;
    }
  }

  f4x acc[8] = {};                     // out^T: [mt], d = mt*16+kg*4+r (mt<4 re, >=4 im)
  float m_ = -1e30f, l_ = 0.f;         // m_ in log2 units; l_ per-lane partial
  const int np = 32 - a;               // staged 32-key pairs (covers high tile)
  const int wqmax = qw0 + 15;
  const int qcol = qw0 + cl;

  const unsigned short* kstream = Kd + ((size_t)(bh * 64)) * 2048;
  const unsigned short* vstream = Vd + ((size_t)(bh * 64)) * 2048;

  #define STAGE_PAIR(buf, P)                                                    \
    {                                                                           \
      const unsigned short* kb = kstream + (size_t)(P) * 4096;                  \
      const unsigned short* vb = vstream + (size_t)(P) * 4096;                  \
      _Pragma("unroll")                                                         \
      for (int r = 0; r < 2; ++r) {                                             \
        int off = r * 256 + wid * 64;                                           \
        gload16(kb + (size_t)(off + lane) * 8, &Klds[buf][off * 8]);            \
        gload16(vb + (size_t)(off + lane) * 8, &Vlds[buf][off * 8]);            \
      }                                                                         \
    }

  STAGE_PAIR(0, 0)
  __syncthreads();                     // pair 0 landed

  for (int p = 0; p < np; ++p) {
    const int cur = p & 1;
    if (p + 1 < np) STAGE_PAIR(cur ^ 1, p + 1)   // async: in flight during compute
    const int k0a = p * 32;
    if (k0a <= wqmax) {                // wave-uniform causal skip
      __builtin_amdgcn_s_setprio(1);
      f4x sca = {}, scb = {};
      #pragma unroll
      for (int ksx = 0; ksx < 4; ++ksx) {
        h8 ka = *(const h8*)&Klds[cur][ksx * 512 + lane * 8];
        sca = MFMA32F16(ka, qf[ksx], sca);
      }
      #pragma unroll
      for (int ksx = 0; ksx < 4; ++ksx) {
        h8 kb = *(const h8*)&Klds[cur][2048 + ksx * 512 + lane * 8];
        scb = MFMA32F16(kb, qf[ksx], scb);
      }
      __builtin_amdgcn_s_setprio(0);
      if (k0a + 31 > qw0) {            // causal mask (boundary pairs only)
        #pragma unroll
        for (int r = 0; r < 4; ++r) {
          if (k0a + kg * 4 + r > qcol)      sca[r] = -1e30f;
          if (k0a + 16 + kg * 4 + r > qcol) scb[r] = -1e30f;
        }
      }
      // fused 32-key online softmax (exp2 domain), defer-max
      float mA = fmaxf(fmaxf(sca[0], sca[1]), sca[2]);          // v_max3
      float mB = fmaxf(fmaxf(sca[3], scb[0]), scb[1]);          // v_max3
      float mC = fmaxf(fmaxf(scb[2], scb[3]), mA);              // v_max3
      float mx = fmaxf(mB, mC);
      mx = fmaxf(mx, __shfl_xor(mx, 16, 64));
      mx = fmaxf(mx, __shfl_xor(mx, 32, 64));
      if (!__all(mx <= m_ + 11.5416f)) {
        float mn = fmaxf(m_, mx);
        float corr = fast_exp2(m_ - mn);
        #pragma unroll
        for (int mt = 0; mt < 8; ++mt) acc[mt] *= corr;
        l_ *= corr;
        m_ = mn;
      }
      float pa0 = fast_exp2(sca[0] - m_), pa1 = fast_exp2(sca[1] - m_);
      float pa2 = fast_exp2(sca[2] - m_), pa3 = fast_exp2(sca[3] - m_);
      float pb0 = fast_exp2(scb[0] - m_), pb1 = fast_exp2(scb[1] - m_);
      float pb2 = fast_exp2(scb[2] - m_), pb3 = fast_exp2(scb[3] - m_);
      l_ += ((pa0 + pa1) + (pa2 + pa3)) + ((pb0 + pb1) + (pb2 + pb3));
      // pack P via cvt_pkrtz, assemble h4 via bitcast (no element moves)
      f16x2 a01 = __builtin_amdgcn_cvt_pkrtz(pa0, pa1);
      f16x2 a23 = __builtin_amdgcn_cvt_pkrtz(pa2, pa3);
      f16x2 b01 = __builtin_amdgcn_cvt_pkrtz(pb0, pb1);
      f16x2 b23 = __builtin_amdgcn_cvt_pkrtz(pb2, pb3);
      i2 ta, tb;
      ta[0] = __builtin_bit_cast(int, a01); ta[1] = __builtin_bit_cast(int, a23);
      tb[0] = __builtin_bit_cast(int, b01); tb[1] = __builtin_bit_cast(int, b23);
      h4 pba = __builtin_bit_cast(h4, ta);
      h4 pbb = __builtin_bit_cast(h4, tb);
      __builtin_amdgcn_s_setprio(1);
      #pragma unroll
      for (int mt = 0; mt < 8; ++mt) {
        h4 va = *(const h4*)&Vlds[cur][mt * 256 + lane * 4];
        acc[mt] = MFMA16F16(va, pba, acc[mt]);
      }
      #pragma unroll
      for (int mt = 0; mt < 8; ++mt) {
        h4 vb = *(const h4*)&Vlds[cur][2048 + mt * 256 + lane * 4];
        acc[mt] = MFMA16F16(vb, pbb, acc[mt]);
      }
      __builtin_amdgcn_s_setprio(0);
    }
    __syncthreads();   // staged pair landed + readers done
  }
  #undef STAGE_PAIR
  // epilogue: reduce l_ across kg lanes, /l, rotate by exp(i*thv), add state
  {
    l_ += __shfl_xor(l_, 16, 64);
    l_ += __shfl_xor(l_, 32, 64);
    float linv = 1.0f / l_;
    int q = qw0 + cl;
    size_t mrow = (size_t)(b * 1024 + q);
    size_t obase = mrow * 1024 + h * 64;
    size_t abase = mrow * 2048 + h * 64;
    #pragma unroll
    for (int mt = 0; mt < 4; ++mt) {
      int d0 = mt * 16 + kg * 4;
      h4 s_r = *(const h4*)&srh[obase + d0];
      h4 s_i = *(const h4*)&sih[obase + d0];
      h4 hr, hi;
      #pragma unroll
      for (int r = 0; r < 4; ++r) {
        int d = d0 + r;
        float orv = acc[mt][r] * linv;
        float oiv = acc[mt + 4][r] * linv;
        float c = tabs[4096 + h * 64 + d], s = tabs[5120 + h * 64 + d];
        hr[r] = (_Float16)(orv * c - oiv * s + (float)s_r[r]);
        hi[r] = (_Float16)(orv * s + oiv * c + (float)s_i[r]);
      }
      *(h4*)&Af[abase + d0]        = hr;   // real
      *(h4*)&Af[abase + 1024 + d0] = hi;   // imag
    }
  }
}

// ---------------- transpose FF weight -> fp16: Bt[2048][2048] ----------------
__global__ void split_b_kernel(const float* __restrict__ fr, const float* __restrict__ fi,
                               unsigned short* __restrict__ Bt) {
  __shared__ float tile[32][33];
  const int k0 = blockIdx.x * 32, n0 = blockIdx.y * 32;
  const int tid = threadIdx.x;
  #pragma unroll
  for (int p = 0; p < 4; ++p) {
    int e = p * 256 + tid;
    int kk = e >> 5, nn = e & 31;
    int k = k0 + kk, n = n0 + nn;
    float v;
    if (n < 1024) v = (k < 1024) ? fr[(size_t)k * 1024 + n] : -fi[(size_t)(k - 1024) * 1024 + n];
    else          v = (k < 1024) ? fi[(size_t)k * 1024 + (n - 1024)]
                                 : fr[(size_t)(k - 1024) * 1024 + (n - 1024)];
    tile[kk][nn] = v;
  }
  __syncthreads();
  #pragma unroll
  for (int p = 0; p < 4; ++p) {
    int e = p * 256 + tid;
    int nn = e >> 5, kk = e & 31;
    *(_Float16*)&Bt[(size_t)(n0 + nn) * 2048 + (k0 + kk)] = (_Float16)tile[kk][nn];
  }
}

// ---------------- readout weight fp16: Wt[256][wr1024|wi1024] ----------------
__global__ void split_w_kernel(const float* __restrict__ wr, const float* __restrict__ wi,
                               unsigned short* __restrict__ Wt) {
  int idx = blockIdx.x * 256 + threadIdx.x;        // 256*512
  int v = idx >> 9;
  int k4 = (idx & 511) * 4;
  float4 a = (k4 < 1024) ? *(const float4*)&wr[(size_t)v * 1024 + k4]
                         : *(const float4*)&wi[(size_t)v * 1024 + k4 - 1024];
  h4 h;
  h[0] = (_Float16)a.x; h[1] = (_Float16)a.y;
  h[2] = (_Float16)a.z; h[3] = (_Float16)a.w;
  *(h4*)&Wt[(size_t)v * 2048 + k4] = h;
}

// ---------------- FF GEMM: fp16, 256x128 tile, BK=64, K-split x2 -------------
// 4 waves (2x2); each wave owns 128x64 (8x4 frags). 2 blocks/CU.
__global__ __launch_bounds__(256, 2) void gemm_ff(
    const unsigned short* __restrict__ A,   // [4096][2048] fp16 bits
    const unsigned short* __restrict__ Bt,  // [2048][2048]
    float* __restrict__ pr0, float* __restrict__ pi0,
    float* __restrict__ pr1, float* __restrict__ pi1) {
  __shared__ short As[256 * 64];            // 32 KB
  __shared__ short Bs[128 * 64];            // 16 KB
  const int tid = threadIdx.x;
  const int lane = tid & 63, wid = tid >> 6;
  // XCD swizzle: l in [0,256) (z adds 256 = 0 mod 8); 2 m-bands/XCD
  const int l = blockIdx.x + (blockIdx.y << 4);
  const int xcd = l & 7, j = l >> 3;        // j in [0,32)
  const int m0 = ((xcd << 1) + (j & 1)) << 8;   // 16 m-tiles of 256
  const int n0 = (j >> 1) << 7;                 // 16 n-tiles of 128
  const int z = blockIdx.z;
  const int wr = wid >> 1, wc = wid & 1;
  const int cl = lane & 15, rg = lane >> 4;

  f4x acc[8][4] = {};

  for (int kt = z * 16; kt < z * 16 + 16; ++kt) {
    const int k0 = kt * 64;
    // stage A: 2048 chunks (8/thread), B: 1024 chunks (4/thread)
    #pragma unroll
    for (int it = 0; it < 8; ++it) {
      int c = wid * 512 + it * 64 + lane;
      gload16(A + (size_t)(m0 + (c >> 3)) * 2048 + k0 + (c & 7) * 8,
              As + (wid * 512 + it * 64) * 8);
    }
    #pragma unroll
    for (int it = 0; it < 4; ++it) {
      int c = wid * 256 + it * 64 + lane;
      gload16(Bt + (size_t)(n0 + (c >> 3)) * 2048 + k0 + (c & 7) * 8,
              Bs + (wid * 256 + it * 64) * 8);
    }
    __syncthreads();
    #pragma unroll
    for (int ks = 0; ks < 2; ++ks) {
      h8 a[8], b[4];
      #pragma unroll
      for (int ms = 0; ms < 8; ++ms)
        a[ms] = *(const h8*)&As[(wr * 128 + ms * 16 + cl) * 64 + ks * 32 + rg * 8];
      #pragma unroll
      for (int ns = 0; ns < 4; ++ns)
        b[ns] = *(const h8*)&Bs[(wc * 64 + ns * 16 + cl) * 64 + ks * 32 + rg * 8];
      #pragma unroll
      for (int ms = 0; ms < 8; ++ms)
        #pragma unroll
        for (int ns = 0; ns < 4; ++ns)
          acc[ms][ns] = MFMA32F16(a[ms], b[ns], acc[ms][ns]);
    }
    __syncthreads();
  }

  const int colbase = n0 + wc * 64;
  float* o_r = z ? pr1 : pr0;
  float* o_i = z ? pi1 : pi0;
  float* dst = (colbase < 1024) ? o_r : o_i;
  const int cb = colbase & 1023;
  #pragma unroll
  for (int ms = 0; ms < 8; ++ms)
    #pragma unroll
    for (int r2 = 0; r2 < 4; ++r2) {
      const int grow = m0 + wr * 128 + ms * 16 + rg * 4 + r2;
      #pragma unroll
      for (int ns = 0; ns < 4; ++ns)
        dst[(size_t)grow * 1024 + cb + ns * 16 + cl] = acc[ms][ns][r2];
    }
}

// ---------------- RO GEMM: fp16, 128x128 tile, K=2048, K-split x4 ------------
__global__ __launch_bounds__(256, 4) void gemm_ro(
    const unsigned short* __restrict__ Z,   // [4096][2048] fp16 bits
    const unsigned short* __restrict__ Wt,  // [256][2048]
    float* __restrict__ part) {             // [4][4096][256]
  __shared__ short As[128 * 64];
  __shared__ short Bs[128 * 64];
  const int tid = threadIdx.x;
  const int lane = tid & 63, wid = tid >> 6;
  const int l = blockIdx.x + (blockIdx.y << 5);   // 0..63 (z adds 64 = 0 mod 8)
  const int xcd = l & 7, j = l >> 3;
  const int m0 = ((xcd << 2) + (j & 3)) << 7;     // 32 m-tiles
  const int n0 = (j >> 2) << 7;                   // 2 n-tiles
  const int z = blockIdx.z;
  const int wr = wid >> 1, wc = wid & 1;
  const int cl = lane & 15, rg = lane >> 4;

  f4x acc[4][4] = {};
  const int cbase = wid * 256;

  for (int kt = z * 8; kt < z * 8 + 8; ++kt) {
    const int k0 = kt * 64;
    #pragma unroll
    for (int it = 0; it < 4; ++it) {
      int c = cbase + it * 64 + lane;
      gload16(Z + (size_t)(m0 + (c >> 3)) * 2048 + k0 + (c & 7) * 8,
              As + (cbase + it * 64) * 8);
      gload16(Wt + (size_t)(n0 + (c >> 3)) * 2048 + k0 + (c & 7) * 8,
              Bs + (cbase + it * 64) * 8);
    }
    __syncthreads();
    #pragma unroll
    for (int ks = 0; ks < 2; ++ks) {
      h8 a[4], b[4];
      #pragma unroll
      for (int ms = 0; ms < 4; ++ms)
        a[ms] = *(const h8*)&As[(wr * 64 + ms * 16 + cl) * 64 + ks * 32 + rg * 8];
      #pragma unroll
      for (int ns = 0; ns < 4; ++ns)
        b[ns] = *(const h8*)&Bs[(wc * 64 + ns * 16 + cl) * 64 + ks * 32 + rg * 8];
      #pragma unroll
      for (int ms = 0; ms < 4; ++ms)
        #pragma unroll
        for (int ns = 0; ns < 4; ++ns)
          acc[ms][ns] = MFMA32F16(a[ms], b[ns], acc[ms][ns]);
    }
    __syncthreads();
  }

  float* dst = part + (size_t)z * 4096 * 256;
  const int colbase = n0 + wc * 64;
  #pragma unroll
  for (int ms = 0; ms < 4; ++ms)
    #pragma unroll
    for (int r2 = 0; r2 < 4; ++r2) {
      const int grow = m0 + wr * 64 + ms * 16 + rg * 4 + r2;
      #pragma unroll
      for (int ns = 0; ns < 4; ++ns)
        dst[(size_t)grow * 256 + colbase + ns * 16 + cl] = acc[ms][ns][r2];
    }
}

// ---------------- complex_norm over FF partial sums -> fp16 Z ----------------
__global__ __launch_bounds__(256) void norm_split_kernel(
    const float* __restrict__ pr0, const float* __restrict__ pi0,
    const float* __restrict__ pr1, const float* __restrict__ pi1,
    unsigned short* __restrict__ Z) {
  const int row = blockIdx.x, tid = threadIdx.x;
  const int base = row * E_ + tid * 4;
  float4 r0 = *(const float4*)&pr0[base];
  float4 r1 = *(const float4*)&pr1[base];
  float4 i0 = *(const float4*)&pi0[base];
  float4 i1 = *(const float4*)&pi1[base];
  float4 zr = make_float4(r0.x + r1.x, r0.y + r1.y, r0.z + r1.z, r0.w + r1.w);
  float4 zi = make_float4(i0.x + i1.x, i0.y + i1.y, i0.z + i1.z, i0.w + i1.w);
  float mg[4];
  mg[0] = sqrtf(zr.x * zr.x + zi.x * zi.x);
  mg[1] = sqrtf(zr.y * zr.y + zi.y * zi.y);
  mg[2] = sqrtf(zr.z * zr.z + zi.z * zi.z);
  mg[3] = sqrtf(zr.w * zr.w + zi.w * zi.w);
  float s1 = mg[0] + mg[1] + mg[2] + mg[3];
  float s2 = mg[0]*mg[0] + mg[1]*mg[1] + mg[2]*mg[2] + mg[3]*mg[3];
  #pragma unroll
  for (int off = 1; off < 64; off <<= 1) {
    s1 += __shfl_xor(s1, off, 64);
    s2 += __shfl_xor(s2, off, 64);
  }
  __shared__ float ws1[4], ws2[4];
  if ((tid & 63) == 0) { ws1[tid >> 6] = s1; ws2[tid >> 6] = s2; }
  __syncthreads();
  s1 = ws1[0] + ws1[1] + ws1[2] + ws1[3];
  s2 = ws2[0] + ws2[1] + ws2[2] + ws2[3];
  float mean = s1 * (1.0f / 1024.0f);
  float var = (s2 - 1024.0f * mean * mean) * (1.0f / 1023.0f);  // ddof=1
  var = fmaxf(var, 0.0f);
  float inv_sd = 1.0f / (sqrtf(var) + 1e-5f);
  float sc[4];
  #pragma unroll
  for (int t = 0; t < 4; ++t)
    sc[t] = tanhf((mg[t] - mean) * inv_sd) / (mg[t] + 1e-5f);
  h4 hr, hi;
  hr[0] = (_Float16)(zr.x * sc[0]); hr[1] = (_Float16)(zr.y * sc[1]);
  hr[2] = (_Float16)(zr.z * sc[2]); hr[3] = (_Float16)(zr.w * sc[3]);
  hi[0] = (_Float16)(zi.x * sc[0]); hi[1] = (_Float16)(zi.y * sc[1]);
  hi[2] = (_Float16)(zi.z * sc[2]); hi[3] = (_Float16)(zi.w * sc[3]);
  const size_t zb = (size_t)row * 2048 + tid * 4;
  *(h4*)&Z[zb]        = hr;
  *(h4*)&Z[zb + 1024] = hi;
}

// ---------------- reduce RO partials + biases -> out ----------------
__global__ void reduce_bias_kernel(const float* __restrict__ part,
                                   const float* __restrict__ rb,
                                   const float* __restrict__ ib,
                                   float* __restrict__ out) {
  int i4 = (blockIdx.x * 256 + threadIdx.x) * 4;   // < 4096*256
  int col = i4 & 255;
  float4 s = *(const float4*)&part[i4];
  #pragma unroll
  for (int z = 1; z < 4; ++z) {
    float4 v = *(const float4*)&part[(size_t)z * 1048576 + i4];
    s.x += v.x; s.y += v.y; s.z += v.z; s.w += v.w;
  }
  s.x += rb[col + 0] + ib[col + 0];
  s.y += rb[col + 1] + ib[col + 1];
  s.z += rb[col + 2] + ib[col + 2];
  s.w += rb[col + 3] + ib[col + 3];
  *(float4*)&out[i4] = s;
}

extern "C" void kernel_launch(void* const* d_in, const int* in_sizes, int n_in,
                              void* d_out, int out_size, void* d_ws, size_t ws_size,
                              hipStream_t stream) {
  const int*   x    = (const int*)d_in[0];
  const float* te   = (const float*)d_in[1];
  const float* pp   = (const float*)d_in[2];
  const float* qr   = (const float*)d_in[3];
  const float* kr   = (const float*)d_in[4];
  const float* vr   = (const float*)d_in[5];
  const float* ffr  = (const float*)d_in[6];
  const float* ffi  = (const float*)d_in[7];
  const float* rorw = (const float*)d_in[8];
  const float* rorb = (const float*)d_in[9];
  const float* roiw = (const float*)d_in[10];
  const float* roib = (const float*)d_in[11];
  float* out = (float*)d_out;

  char* W = (char*)d_ws;
  const size_t MiB = 1 << 20;
  // [0,16) srh(8MB used) -> pr0(f32 16MB) | [16,32) sih -> pi0
  // [32,48) Af -> Zhl
  // [48,64) Kd -> Bt[48,56) + Wt[56,57)   (after attn)
  // [64,80) Vd -> pr1 ┐
  // [80,96) pi1       ┴-> ro_part [64,80)  (after norm)
  // [96,+24K) tabs
  unsigned short* srh = (unsigned short*)W;
  unsigned short* sih = (unsigned short*)(W + 16 * MiB);
  unsigned short* Af = (unsigned short*)(W + 32 * MiB);
  unsigned short* Kd = (unsigned short*)(W + 48 * MiB);
  unsigned short* Vd = (unsigned short*)(W + 64 * MiB);
  unsigned short* Bt = (unsigned short*)(W + 48 * MiB);
  unsigned short* Wt = (unsigned short*)(W + 56 * MiB);
  float* tabs = (float*)(W + 96 * MiB);
  float* pr0 = (float*)W;
  float* pi0 = (float*)(W + 16 * MiB);
  float* pr1 = (float*)(W + 64 * MiB);
  float* pi1 = (float*)(W + 80 * MiB);
  unsigned short* Zhl = Af;
  float* ro_part = (float*)(W + 64 * MiB);   // 4 x 4 MiB

  rot_kernel<<<12, 256, 0, stream>>>(qr, kr, vr, tabs);
  embed_qkv_kernel<<<dim3(32, 64), 256, 0, stream>>>(x, te, pp, tabs, srh, sih, Kd, Vd);
  attn_mfma_kernel<<<1024, 256, 0, stream>>>(srh, sih, Kd, Vd, tabs, Af);
  split_b_kernel<<<dim3(64, 64), 256, 0, stream>>>(ffr, ffi, Bt);
  split_w_kernel<<<512, 256, 0, stream>>>(rorw, roiw, Wt);
  gemm_ff<<<dim3(16, 16, 2), 256, 0, stream>>>(Af, Bt, pr0, pi0, pr1, pi1);
  norm_split_kernel<<<B_ * S_, 256, 0, stream>>>(pr0, pi0, pr1, pi1, Zhl);
  gemm_ro<<<dim3(32, 2, 4), 256, 0, stream>>>(Zhl, Wt, ro_part);
  reduce_bias_kernel<<<1024, 256, 0, stream>>>(ro_part, rorb, roib, out);
}